// Round 6
// baseline (558.870 us; speedup 1.0000x reference)
//
#include <hip/hip_runtime.h>

#define B_   2
#define S_   2048
#define D_   512
#define H_   8
#define DK_  64
#define DFF_ 2048
#define L_   2
#define BS_  (B_*S_)   // 4096
#define NPROJ 2560     // qr|qi|kr|ki|v concatenated

typedef __attribute__((ext_vector_type(8))) short bfrag;    // 8 bf16 (4 VGPRs)
typedef __attribute__((ext_vector_type(4))) float facc;     // 4 fp32
typedef __attribute__((ext_vector_type(16))) float facc16;  // 16 fp32 (32x32 C/D)
typedef __attribute__((ext_vector_type(4))) int i4v;
typedef __attribute__((ext_vector_type(2))) float f2v;      // packed fp32 pair

__device__ __forceinline__ unsigned short f2b(float f) {
  union { float f; unsigned int u; } c; c.f = f;
  unsigned int u = c.u;
  u += 0x7fffu + ((u >> 16) & 1);    // RNE
  return (unsigned short)(u >> 16);
}

__device__ __forceinline__ float b2f(unsigned short u) {
  union { unsigned u; float f; } c; c.u = (unsigned)u << 16; return c.f;
}

__device__ __forceinline__ bfrag asb(i4v x) { union { i4v a; bfrag b; } u; u.a = x; return u.b; }

__device__ __forceinline__ bfrag bneg(bfrag x) {
  union { bfrag b; i4v a; } u; u.b = x;
  u.a.x ^= 0x80008000; u.a.y ^= 0x80008000; u.a.z ^= 0x80008000; u.a.w ^= 0x80008000;
  return u.b;
}

__device__ __forceinline__ void async_copy16(const void* g, void* l) {
  __builtin_amdgcn_global_load_lds((const __attribute__((address_space(1))) void*)g,
                                   (__attribute__((address_space(3))) void*)l,
                                   16, 0, 0);
}

// ---------------- fused embedding gather + positional zi ----------------
__global__ __launch_bounds__(128) void embed_zi_kernel(const int* __restrict__ tokens,
                                                       const float* __restrict__ embed,
                                                       float* __restrict__ zr,
                                                       unsigned short* __restrict__ acat) {
  int row = blockIdx.x;
  int tok = tokens[row];
  float4 v = ((const float4*)(embed + (size_t)tok * D_))[threadIdx.x];
  ((float4*)(zr + (size_t)row * D_))[threadIdx.x] = v;
  ushort4 o; o.x = f2b(v.x); o.y = f2b(v.y); o.z = f2b(v.z); o.w = f2b(v.w);
  *(ushort4*)(acat + (size_t)row * 1024 + threadIdx.x * 4) = o;

  int s = row & (S_ - 1);
  int d0 = threadIdx.x * 4;
  const double LN1E4 = 9.210340371976184;
  #pragma unroll
  for (int t = 0; t < 4; ++t) {
    int d = d0 + t;
    int jj = d >> 1;
    double freq = exp(-((double)jj / 256.0) * LN1E4);
    float val = (float)sin((double)s * freq);
    acat[(size_t)row * 1024 + 512 + d] = f2b(val);
  }
}

// ---------------- batched weight concat+transpose (both layers) ----------------
__global__ __launch_bounds__(256) void wcat_all(const float* __restrict__ Wqr,
                                                const float* __restrict__ Wqi,
                                                const float* __restrict__ Wkr,
                                                const float* __restrict__ Wki,
                                                const float* __restrict__ Wv,
                                                unsigned short* __restrict__ dst0,
                                                unsigned short* __restrict__ dst1) {
  __shared__ float tile[64][68];
  const int l = blockIdx.z;
  const int KA = l ? 512 : 1024;
  const int k0 = blockIdx.y * 64;
  if (k0 >= KA) return;
  unsigned short* dst = l ? dst1 : dst0;
  const size_t woff = (size_t)l * D_ * D_;
  const float* wqr = Wqr + woff;
  const float* wqi = Wqi + woff;
  const float* wkr = Wkr + woff;
  const float* wki = Wki + woff;
  const float* wv  = Wv  + woff;

  const int tid = threadIdx.x;
  const int n0 = blockIdx.x * 64;
  const int p = n0 >> 9, nn0 = n0 & 511;
  const float* src;
  float sign = 1.f;
  bool zero = false;
  if (k0 < 512) {
    const float* tops[5] = {wqr, wqi, wkr, wki, wv};
    src = tops[p];
  } else {
    const float* bots[5] = {wqi, wqr, wki, wkr, nullptr};
    const float sg[5] = {-1.f, 1.f, -1.f, 1.f, 0.f};
    src = bots[p]; sign = sg[p]; zero = (p == 4);
  }
  const int kk0 = k0 & 511;
  #pragma unroll
  for (int i = 0; i < 4; ++i) {
    int lin = tid + i * 256;
    int row = lin >> 4, c4 = (lin & 15) * 4;
    float4 v = make_float4(0.f, 0.f, 0.f, 0.f);
    if (!zero) v = *(const float4*)(src + (size_t)(kk0 + row) * 512 + nn0 + c4);
    *(float4*)&tile[row][c4] = v;
  }
  __syncthreads();
  #pragma unroll
  for (int i = 0; i < 4; ++i) {
    int lin = tid + i * 256;
    int n = lin >> 4, kc4 = (lin & 15) * 4;
    ushort4 o;
    o.x = f2b(sign * tile[kc4 + 0][n]);
    o.y = f2b(sign * tile[kc4 + 1][n]);
    o.z = f2b(sign * tile[kc4 + 2][n]);
    o.w = f2b(sign * tile[kc4 + 3][n]);
    *(ushort4*)(dst + (size_t)(n0 + n) * KA + k0 + kc4) = o;
  }
}

// ---------------- batched weight transpose: wo/w1/w2 x both layers ----------------
__global__ __launch_bounds__(256) void wtr_all(const float* __restrict__ Wo,
                                               const float* __restrict__ W1,
                                               const float* __restrict__ W2,
                                               unsigned short* __restrict__ pwo,
                                               unsigned short* __restrict__ pw1,
                                               unsigned short* __restrict__ pw2) {
  __shared__ float tile[64][68];
  const int j = blockIdx.z, l = j & 1;
  const float* src; unsigned short* dst; int K, N;
  if (j < 2)      { src = Wo + (size_t)l * 512 * 512;  dst = pwo + (size_t)l * 512 * 512;  K = 512;  N = 512; }
  else if (j < 4) { src = W1 + (size_t)l * 512 * 2048; dst = pw1 + (size_t)l * 2048 * 512; K = 512;  N = 2048; }
  else            { src = W2 + (size_t)l * 2048 * 512; dst = pw2 + (size_t)l * 512 * 2048; K = 2048; N = 512; }
  const int n0 = blockIdx.x * 64, k0 = blockIdx.y * 64;
  if (n0 >= N || k0 >= K) return;
  const int tid = threadIdx.x;
  #pragma unroll
  for (int i = 0; i < 4; ++i) {
    int lin = tid + i * 256;
    int row = lin >> 4, c4 = (lin & 15) * 4;
    *(float4*)&tile[row][c4] = *(const float4*)(src + (size_t)(k0 + row) * N + n0 + c4);
  }
  __syncthreads();
  #pragma unroll
  for (int i = 0; i < 4; ++i) {
    int lin = tid + i * 256;
    int n = lin >> 4, kc4 = (lin & 15) * 4;
    ushort4 o;
    o.x = f2b(tile[kc4 + 0][n]);
    o.y = f2b(tile[kc4 + 1][n]);
    o.z = f2b(tile[kc4 + 2][n]);
    o.w = f2b(tile[kc4 + 3][n]);
    *(ushort4*)(dst + (size_t)(n0 + n) * K + k0 + kc4) = o;
  }
}

// ---------------- bf16 MFMA GEMM (m97 pattern) ----------------
template<int TM>
__global__ __launch_bounds__(256) void gemm_bf16(const unsigned short* __restrict__ A,
                                                 const unsigned short* __restrict__ Bt,
                                                 const float* __restrict__ bias,
                                                 float* __restrict__ outF,
                                                 unsigned short* __restrict__ outB,
                                                 int M, int N, int K, int lda, int relu) {
  constexpr int MT = TM / 32;
  __shared__ short smem[(TM + 128) * 32];
  short* A_s = smem;
  short* B_s = smem + TM * 32;

  const int tid = threadIdx.x;
  const int w = tid >> 6, lane = tid & 63;
  const int col = lane & 15, quad = lane >> 4;
  const int m0 = blockIdx.y * TM, n0 = blockIdx.x * 128;
  const int wrow = (w >> 1) * (TM / 2);
  const int wcol = (w & 1) * 64;

  const int srow = lane >> 2;
  const int skk  = (lane & 3) * 8;

  facc acc[MT][4];
  #pragma unroll
  for (int i = 0; i < MT; ++i)
    #pragma unroll
    for (int j = 0; j < 4; ++j) acc[i][j] = (facc){0.f, 0.f, 0.f, 0.f};

  for (int k0 = 0; k0 < K; k0 += 32) {
    __syncthreads();
    #pragma unroll
    for (int rd = 0; rd < TM / 64; ++rd) {
      int row = rd * 64 + w * 16 + srow;
      async_copy16(A + (size_t)(m0 + row) * lda + k0 + skk, &A_s[row * 32 + skk]);
    }
    #pragma unroll
    for (int rd = 0; rd < 2; ++rd) {
      int row = rd * 64 + w * 16 + srow;
      async_copy16(Bt + (size_t)(n0 + row) * K + k0 + skk, &B_s[row * 32 + skk]);
    }
    __syncthreads();

    bfrag af[MT], bf[4];
    #pragma unroll
    for (int i = 0; i < MT; ++i)
      af[i] = *(const bfrag*)&A_s[(wrow + i * 16 + col) * 32 + quad * 8];
    #pragma unroll
    for (int j = 0; j < 4; ++j)
      bf[j] = *(const bfrag*)&B_s[(wcol + j * 16 + col) * 32 + quad * 8];
    #pragma unroll
    for (int i = 0; i < MT; ++i)
      #pragma unroll
      for (int j = 0; j < 4; ++j)
        acc[i][j] = __builtin_amdgcn_mfma_f32_16x16x32_bf16(af[i], bf[j], acc[i][j], 0, 0, 0);
  }

  #pragma unroll
  for (int i = 0; i < MT; ++i) {
    #pragma unroll
    for (int j = 0; j < 4; ++j) {
      int colIdx = n0 + wcol + j * 16 + col;
      float b = bias ? bias[colIdx] : 0.f;
      #pragma unroll
      for (int r = 0; r < 4; ++r) {
        int rowIdx = m0 + wrow + i * 16 + quad * 4 + r;
        float v = acc[i][j][r] + b;
        if (relu) v = fmaxf(v, 0.f);
        if (outF) outF[(size_t)rowIdx * N + colIdx] = v;
        if (outB) outB[(size_t)rowIdx * N + colIdx] = f2b(v);
      }
    }
  }
}

// ---------------- V transpose: Q4 cols [2048,2560) -> bf16 [b,h,dk,s] ----------------
__global__ __launch_bounds__(256) void vt_kernel(const unsigned short* __restrict__ Q4,
                                                 unsigned short* __restrict__ vt) {
  __shared__ short tile[64][80];
  const int bh = blockIdx.x;
  const int b = bh >> 3, hd = bh & 7;
  const int s0 = blockIdx.y * 64;
  const int tid = threadIdx.x;
  #pragma unroll
  for (int i = 0; i < 2; ++i) {
    int lin = tid + i * 256;
    int row = lin >> 3;
    int c8 = (lin & 7) * 8;
    *(int4*)&tile[row][c8] =
      *(const int4*)(Q4 + (size_t)(b * S_ + s0 + row) * NPROJ + 2048 + hd * DK_ + c8);
  }
  __syncthreads();
  #pragma unroll
  for (int i = 0; i < 2; ++i) {
    int lin = tid + i * 256;
    int d = lin >> 3;
    int s8 = (lin & 7) * 8;
    short tmp[8];
    #pragma unroll
    for (int t = 0; t < 8; ++t) tmp[t] = tile[s8 + t][d];
    *(int4*)(vt + ((size_t)bh * DK_ + d) * S_ + s0 + s8) = *(const int4*)tmp;
  }
}

// ---------------- MFMA complex-hybrid attention, v12 ----------------
// v11 post-mortem: 68.7us; MFMA side fully modeled (25% util = instruction
// floor at 2 blk/CU), VALUBusy 46.7% is now the longest pipe (~32us busy vs
// 17us matrix) and the softmax chain is entirely SCALAR fp32.  gfx950's
// 157TF fp32 is PACKED fp32 (v_pk_fma_f32: 2 floats/lane/instr) -- unused.
// v12:
//  1. Packed-fp32 softmax: all fma/mul/add chains on f2v (float2) pairs ->
//     clang emits v_pk_* at -O3; only rsqrt stays scalar (no packed trans).
//     Pair (2i,2i+1) layout feeds v_cvt_pk_bf16_f32 directly.
//  2. s_setprio(1) around QK and PV MFMA clusters: v11's barrier-free spans
//     are the drift regime where m191 measured +4-7% (v7's lockstep was not).
//  3. Keep: phase-staged 64KB LDS (2 barriers/256 keys), V direct-global,
//     cvt_pk+permlane exchange, persistent Q frags.
__global__ __launch_bounds__(512, 2) void attn_mfma(const unsigned short* __restrict__ Q4,
                                                    const unsigned short* __restrict__ VT,
                                                    unsigned short* __restrict__ po,
                                                    float* __restrict__ pl) {
  __shared__ __align__(16) short smem[32768];   // 64KB: kr[256][128B] | ki[256][128B]

  const int bh = blockIdx.y;
  const int b = bh >> 3, hd = bh & 7;
  const int hoff = hd * DK_;
  const int ks = blockIdx.z;
  const int tid = threadIdx.x;
  const int w = tid >> 6;
  const int lane = tid & 63;
  const int m = lane & 31;       // C col = q index / A m index
  const int h = lane >> 5;       // half-wave
  const int x7 = m & 7;
  const int q0 = blockIdx.x * 256 + w * 32;
  const int kb = ks * 512;

  const size_t bS = (size_t)b * S_;
  const size_t vtbase = (size_t)bh * DK_ * S_;

  // staging indices: 512 threads, 8 segs/key row; swizzle on SOURCE, linear dest
  const int skey = tid >> 3, sseg = tid & 7;
  const int sls = sseg ^ (skey & 7);            // XOR bank swizzle (K rows = 128B)

  // Q B-frags (persistent): B[kdim = t*16 + h*8 + j][n=q=m]
  bfrag qrf[4], qif[4], nqrf[4];
  {
    const size_t qrow = (bS + q0 + m) * (size_t)NPROJ + hoff;
    #pragma unroll
    for (int t = 0; t < 4; ++t) {
      qrf[t] = *(const bfrag*)(Q4 + qrow + t * 16 + h * 8);
      qif[t] = *(const bfrag*)(Q4 + qrow + 512 + t * 16 + h * 8);
      nqrf[t] = bneg(qrf[t]);
    }
  }

  facc16 o0 = {}, o1 = {};
  f2v lacc = {0.f, 0.f};
  const f2v c1v = {0.015625f, 0.015625f};   // 1/64
  const f2v c2v = {0.0375f, 0.0375f};       // 0.3/8
  const f2v epsv = {1e-30f, 1e-30f};
  const f2v halfv = {0.5f, 0.5f};
  const f2v onev = {1.f, 1.f};

  // V base pointers (per d-tile): row = tile*32 + m
  const unsigned short* vb0 = VT + vtbase + (size_t)m * S_ + kb + h * 8;
  const unsigned short* vb1 = vb0 + (size_t)32 * S_;

  char* kr_sb = (char*)smem;            // kr: 32KB
  char* ki_sb = (char*)smem + 32768;    // ki: 32KB

  for (int ph = 0; ph < 2; ++ph) {
    // all waves finished reading the previous phase's LDS (ds_reads complete
    // before their consuming MFMAs, which precede this barrier)
    __builtin_amdgcn_s_barrier();
    // stage 256 keys: 4 rounds x 64 keys, kr+ki, coalesced 16B, linear dest
    #pragma unroll
    for (int r = 0; r < 4; ++r) {
      const unsigned short* gk = Q4 + (bS + kb + ph * 256 + r * 64 + skey) * (size_t)NPROJ
                               + 1024 + hoff + sls * 8;
      async_copy16(gk,       kr_sb + r * 8192 + tid * 16);
      async_copy16(gk + 512, ki_sb + r * 8192 + tid * 16);
    }
    asm volatile("s_waitcnt vmcnt(0)" ::: "memory");
    __builtin_amdgcn_s_barrier();
    asm volatile("" ::: "memory");

    for (int c = 0; c < 4; ++c) {      // 64-key chunk, NO sync inside phase
      // ---- V frags direct from global ----
      bfrag vtf[2][4];
      #pragma unroll
      for (int kt = 0; kt < 4; ++kt) {
        vtf[0][kt] = *(const bfrag*)(vb0 + kt * 16);
        vtf[1][kt] = *(const bfrag*)(vb1 + kt * 16);
      }
      vb0 += 64; vb1 += 64;

      // ---- K frags both halves from LDS: row = c*64 + hs*32 + m ----
      bfrag kr0[4], ki0[4], kr1[4], ki1[4];
      #pragma unroll
      for (int t = 0; t < 4; ++t) {
        int off0 = (c * 64 + m) * 128 + (((2 * t + h) ^ x7) << 4);
        int off1 = (c * 64 + 32 + m) * 128 + (((2 * t + h) ^ x7) << 4);
        kr0[t] = *(const bfrag*)(kr_sb + off0);
        ki0[t] = *(const bfrag*)(ki_sb + off0);
        kr1[t] = *(const bfrag*)(kr_sb + off1);
        ki1[t] = *(const bfrag*)(ki_sb + off1);
      }

      // ---- QK both halves ----
      facc16 sr0 = {}, si0 = {}, sr1 = {}, si1 = {};
      __builtin_amdgcn_s_setprio(1);
      #pragma unroll
      for (int t = 0; t < 4; ++t) {
        sr0 = __builtin_amdgcn_mfma_f32_32x32x16_bf16(kr0[t], qrf[t], sr0, 0, 0, 0);
        si0 = __builtin_amdgcn_mfma_f32_32x32x16_bf16(kr0[t], qif[t], si0, 0, 0, 0);
        sr0 = __builtin_amdgcn_mfma_f32_32x32x16_bf16(ki0[t], qif[t], sr0, 0, 0, 0);
        si0 = __builtin_amdgcn_mfma_f32_32x32x16_bf16(ki0[t], nqrf[t], si0, 0, 0, 0);
      }
      #pragma unroll
      for (int t = 0; t < 4; ++t) {
        sr1 = __builtin_amdgcn_mfma_f32_32x32x16_bf16(kr1[t], qrf[t], sr1, 0, 0, 0);
        si1 = __builtin_amdgcn_mfma_f32_32x32x16_bf16(kr1[t], qif[t], si1, 0, 0, 0);
        sr1 = __builtin_amdgcn_mfma_f32_32x32x16_bf16(ki1[t], qif[t], sr1, 0, 0, 0);
        si1 = __builtin_amdgcn_mfma_f32_32x32x16_bf16(ki1[t], nqrf[t], si1, 0, 0, 0);
      }
      __builtin_amdgcn_s_setprio(0);

      #pragma unroll
      for (int hs = 0; hs < 2; ++hs) {
        const facc16& sr = hs ? sr1 : sr0;
        const facc16& si = hs ? si1 : si0;

        // ---- hybrid score -> p = exp(x) ~ 1 + x + x^2/2, PACKED fp32 ----
        // per pair: 2x pk_fma (d2), 2 scalar rsqrt, pk_mul+pk_fma (u),
        // pk_mul (x), 2x pk_fma (p), pk_add (sum) -> ~8 pk ops vs 16 scalar
        f2v pk[8];
        f2v psum = {0.f, 0.f};
        #pragma unroll
        for (int i = 0; i < 8; ++i) {
          f2v a  = { sr[2 * i], sr[2 * i + 1] };
          f2v bb = { si[2 * i], si[2 * i + 1] };
          f2v d2 = a * a + (bb * bb + epsv);
          f2v rs = { rsqrtf(d2.x), rsqrtf(d2.y) };
          f2v u  = c1v * d2 + c2v * a;
          f2v x  = rs * u;
          f2v p2 = x * (halfv * x + onev) + onev;
          pk[i] = p2;
          psum += p2;
        }
        lacc += psum;

        // ---- pack P (cvt_pk RNE) + permlane32_swap cross-half exchange ----
        unsigned dw[8];
        #pragma unroll
        for (int i = 0; i < 8; ++i)
          asm("v_cvt_pk_bf16_f32 %0, %1, %2" : "=v"(dw[i]) : "v"(pk[i].x), "v"(pk[i].y));
        unsigned s0a = dw[0], s0b = dw[2];
        unsigned s1a = dw[1], s1b = dw[3];
        unsigned s2a = dw[4], s2b = dw[6];
        unsigned s3a = dw[5], s3b = dw[7];
        asm("v_permlane32_swap_b32 %0, %1" : "+v"(s0a), "+v"(s0b));
        asm("v_permlane32_swap_b32 %0, %1" : "+v"(s1a), "+v"(s1b));
        asm("v_permlane32_swap_b32 %0, %1" : "+v"(s2a), "+v"(s2b));
        asm("v_permlane32_swap_b32 %0, %1" : "+v"(s3a), "+v"(s3b));
        i4v f0 = { (int)s0a, (int)s1a, (int)s0b, (int)s1b };
        i4v f1 = { (int)s2a, (int)s3a, (int)s2b, (int)s3b };
        bfrag pf0 = asb(f0), pf1 = asb(f1);

        // ---- PV: o^T[d][q] += V^T x P^T (k-slots 2*hs, 2*hs+1) ----
        __builtin_amdgcn_s_setprio(1);
        o0 = __builtin_amdgcn_mfma_f32_32x32x16_bf16(vtf[0][2 * hs + 0], pf0, o0, 0, 0, 0);
        o0 = __builtin_amdgcn_mfma_f32_32x32x16_bf16(vtf[0][2 * hs + 1], pf1, o0, 0, 0, 0);
        o1 = __builtin_amdgcn_mfma_f32_32x32x16_bf16(vtf[1][2 * hs + 0], pf0, o1, 0, 0, 0);
        o1 = __builtin_amdgcn_mfma_f32_32x32x16_bf16(vtf[1][2 * hs + 1], pf1, o1, 0, 0, 0);
        __builtin_amdgcn_s_setprio(0);
      }
    }
  }

  // ---- epilogue: write per-split partials (bf16 o, fp32 l) ----
  float l = lacc.x + lacc.y;
  float l_tot = l + __shfl_xor(l, 32);
  const size_t prow = ((size_t)(bh * 4 + ks)) * S_ + q0 + m;
  #pragma unroll
  for (int tile = 0; tile < 2; ++tile) {
    const facc16& oo = tile ? o1 : o0;
    #pragma unroll
    for (int rg = 0; rg < 4; ++rg) {
      int d0 = tile * 32 + rg * 8 + h * 4;        // d = (reg&3)+8*(reg>>2)+4h
      ushort4 ob;
      ob.x = f2b(oo[4 * rg + 0]);
      ob.y = f2b(oo[4 * rg + 1]);
      ob.z = f2b(oo[4 * rg + 2]);
      ob.w = f2b(oo[4 * rg + 3]);
      *(ushort4*)(po + prow * 64 + d0) = ob;
    }
  }
  if (lane < 32) pl[prow] = l_tot;
}

// ---------------- combine the 4 key-split partials -> ctxb ----------------
__global__ __launch_bounds__(256) void attn_combine(const unsigned short* __restrict__ po,
                                                    const float* __restrict__ pl,
                                                    unsigned short* __restrict__ ctxb) {
  int t = blockIdx.x * 256 + threadIdx.x;      // 262144 threads
  int row = t >> 3;                            // bh*S + q
  int dg = t & 7;
  int bh = row >> 11, q = row & (S_ - 1);
  int b = bh >> 3, hd = bh & 7;
  float acc[8];
  #pragma unroll
  for (int e = 0; e < 8; ++e) acc[e] = 0.f;
  float ls = 0.f;
  #pragma unroll
  for (int ks = 0; ks < 4; ++ks) {
    size_t prow = (((size_t)(bh * 4 + ks)) << 11) + q;
    ls += pl[prow];
    const unsigned short* src = po + prow * 64 + dg * 8;
    ushort4 v0 = *(const ushort4*)src;
    ushort4 v1 = *(const ushort4*)(src + 4);
    acc[0] += b2f(v0.x); acc[1] += b2f(v0.y); acc[2] += b2f(v0.z); acc[3] += b2f(v0.w);
    acc[4] += b2f(v1.x); acc[5] += b2f(v1.y); acc[6] += b2f(v1.z); acc[7] += b2f(v1.w);
  }
  float inv = 1.f / ls;
  unsigned short ob[8];
  #pragma unroll
  for (int e = 0; e < 8; ++e) ob[e] = f2b(acc[e] * inv);
  *(int4*)(ctxb + ((size_t)(b * S_ + q)) * D_ + hd * DK_ + dg * 8) = *(const int4*)ob;
}

// ---------------- layernorm ----------------
__global__ __launch_bounds__(256) void ln_kernel(const float* __restrict__ X,
                                                 const float* __restrict__ R,
                                                 const float* __restrict__ g,
                                                 const float* __restrict__ be,
                                                 float* __restrict__ OutF,
                                                 unsigned short* __restrict__ OutB) {
  const int lane = threadIdx.x & 63;
  const int wv = threadIdx.x >> 6;
  const int row = blockIdx.x * 4 + wv;
  const float* xp = X + (size_t)row * D_;
  const float* rp = R + (size_t)row * D_;
  float x[8];
  float s = 0.f;
  #pragma unroll
  for (int i = 0; i < 8; ++i) {
    int d = i * 64 + lane;
    x[i] = xp[d] + rp[d];
    s += x[i];
  }
  s += __shfl_xor(s, 32); s += __shfl_xor(s, 16); s += __shfl_xor(s, 8);
  s += __shfl_xor(s, 4);  s += __shfl_xor(s, 2);  s += __shfl_xor(s, 1);
  float mu = s * (1.f / 512.f);
  float vs = 0.f;
  #pragma unroll
  for (int i = 0; i < 8; ++i) { float d = x[i] - mu; vs += d * d; }
  vs += __shfl_xor(vs, 32); vs += __shfl_xor(vs, 16); vs += __shfl_xor(vs, 8);
  vs += __shfl_xor(vs, 4);  vs += __shfl_xor(vs, 2);  vs += __shfl_xor(vs, 1);
  float rstd = rsqrtf(vs * (1.f / 512.f) + 1e-5f);
  #pragma unroll
  for (int i = 0; i < 8; ++i) {
    int d = i * 64 + lane;
    float v = (x[i] - mu) * rstd * g[d] + be[d];
    if (OutF) OutF[(size_t)row * D_ + d] = v;
    if (OutB) OutB[(size_t)row * D_ + d] = f2b(v);
  }
}

// ---------------- classifier head ----------------
__global__ __launch_bounds__(256) void head_kernel(const float* __restrict__ Z,
                                                   const float* __restrict__ hw,
                                                   const float* __restrict__ hb,
                                                   float* __restrict__ out) {
  const int lane = threadIdx.x & 63;
  const int wv = threadIdx.x >> 6;
  const int row = blockIdx.x * 4 + wv;
  const float* zp = Z + (size_t)row * D_;
  float a0 = 0.f, a1 = 0.f;
  #pragma unroll
  for (int i = 0; i < 8; ++i) {
    int d = i * 64 + lane;
    float z = zp[d];
    a0 += z * hw[d * 2];
    a1 += z * hw[d * 2 + 1];
  }
  a0 += __shfl_xor(a0, 32); a0 += __shfl_xor(a0, 16); a0 += __shfl_xor(a0, 8);
  a0 += __shfl_xor(a0, 4);  a0 += __shfl_xor(a0, 2);  a0 += __shfl_xor(a0, 1);
  a1 += __shfl_xor(a1, 32); a1 += __shfl_xor(a1, 16); a1 += __shfl_xor(a1, 8);
  a1 += __shfl_xor(a1, 4);  a1 += __shfl_xor(a1, 2);  a1 += __shfl_xor(a1, 1);
  if (lane == 0) {
    out[row * 2]     = a0 + hb[0];
    out[row * 2 + 1] = a1 + hb[1];
  }
}

extern "C" void kernel_launch(void* const* d_in, const int* in_sizes, int n_in,
                              void* d_out, int out_size, void* d_ws, size_t ws_size,
                              hipStream_t stream) {
  const int*   tokens = (const int*)  d_in[0];
  const float* embed  = (const float*)d_in[1];
  const float* Wqr = (const float*)d_in[2];
  const float* Wqi = (const float*)d_in[3];
  const float* Wkr = (const float*)d_in[4];
  const float* Wki = (const float*)d_in[5];
  const float* Wv  = (const float*)d_in[6];
  const float* Wo  = (const float*)d_in[7];
  const float* bo  = (const float*)d_in[8];
  const float* W1  = (const float*)d_in[9];
  const float* b1  = (const float*)d_in[10];
  const float* W2  = (const float*)d_in[11];
  const float* b2  = (const float*)d_in[12];
  const float* g1  = (const float*)d_in[13];
  const float* be1 = (const float*)d_in[14];
  const float* g2  = (const float*)d_in[15];
  const float* be2 = (const float*)d_in[16];
  const float* hw  = (const float*)d_in[17];
  const float* hb  = (const float*)d_in[18];
  float* out = (float*)d_out;

  char* p = (char*)d_ws;
  float* zr = (float*)p;             p += (size_t)BS_ * D_ * 4;           // 8 MB
  unsigned short* acat = (unsigned short*)p;
  unsigned short* zrb  = acat;       p += (size_t)BS_ * 1024 * 2;         // 8 MB
  unsigned short* Q4   = (unsigned short*)p;
  unsigned short* ffb  = Q4;         p += (size_t)BS_ * NPROJ * 2;        // 20 MB
  unsigned short* VT   = (unsigned short*)p; p += (size_t)B_*H_*DK_*S_*2; // 4 MB
  unsigned short* ctxb = (unsigned short*)p; p += (size_t)BS_ * D_ * 2;   // 4 MB
  float* hbuf = (float*)p;           p += (size_t)BS_ * D_ * 4;           // 8 MB
  float* z1   = (float*)p;           p += (size_t)BS_ * D_ * 4;           // 8 MB  (contiguous after hbuf)
  unsigned short* z1b = (unsigned short*)p;  p += (size_t)BS_ * D_ * 2;   // 4 MB  (contiguous after z1)
  unsigned short* pw_proj0 = (unsigned short*)p; p += (size_t)NPROJ * 1024 * 2; // 5 MB
  unsigned short* pw_proj1 = (unsigned short*)p; p += (size_t)NPROJ * 512 * 2;  // 2.5 MB
  unsigned short* pw_wo = (unsigned short*)p;    p += (size_t)2 * 512 * 512 * 2;   // 1 MB
  unsigned short* pw_w1 = (unsigned short*)p;    p += (size_t)2 * 2048 * 512 * 2;  // 4 MB
  unsigned short* pw_w2 = (unsigned short*)p;    p += (size_t)2 * 512 * 2048 * 2;  // 4 MB
  float* pl = (float*)p;             p += (size_t)16 * 4 * S_ * 4;        // 0.5 MB

  // po bf16 [16 bh][4 ks][2048 q][64 d] = 16.78 MB -> aliases hbuf+z1+start of z1b
  // (all dead during attention; combine reads po before the Wo GEMM rewrites hbuf)
  unsigned short* po = (unsigned short*)hbuf;

  embed_zi_kernel<<<BS_, 128, 0, stream>>>(tokens, embed, zr, acat);
  wcat_all<<<dim3(NPROJ / 64, 16, 2), 256, 0, stream>>>(Wqr, Wqi, Wkr, Wki, Wv,
                                                        pw_proj0, pw_proj1);
  wtr_all<<<dim3(32, 32, 6), 256, 0, stream>>>(Wo, W1, W2, pw_wo, pw_w1, pw_w2);

  for (int l = 0; l < L_; ++l) {
    const int KA = (l == 0) ? 1024 : 512;
    const unsigned short* Aproj = (l == 0) ? acat : zrb;
    const unsigned short* Wproj = (l == 0) ? pw_proj0 : pw_proj1;

    gemm_bf16<128><<<dim3(NPROJ / 128, BS_ / 128), 256, 0, stream>>>(
        Aproj, Wproj, nullptr, nullptr, Q4, BS_, NPROJ, KA, KA, 0);

    vt_kernel<<<dim3(B_ * H_, S_ / 64), 256, 0, stream>>>(Q4, VT);
    attn_mfma<<<dim3(S_ / 256, B_ * H_, 4), 512, 0, stream>>>(Q4, VT, po, pl);
    attn_combine<<<1024, 256, 0, stream>>>(po, pl, ctxb);

    gemm_bf16<64><<<dim3(D_ / 128, BS_ / 64), 256, 0, stream>>>(
        ctxb, pw_wo + (size_t)l * 512 * 512, bo + l * D_, hbuf, nullptr,
        BS_, D_, D_, D_, 0);
    ln_kernel<<<BS_ / 4, 256, 0, stream>>>(zr, hbuf, g1 + l * D_, be1 + l * D_, z1, z1b);

    gemm_bf16<128><<<dim3(DFF_ / 128, BS_ / 128), 256, 0, stream>>>(
        z1b, pw_w1 + (size_t)l * 2048 * 512, b1 + l * DFF_, nullptr, ffb,
        BS_, DFF_, D_, D_, 1);
    gemm_bf16<64><<<dim3(D_ / 128, BS_ / 64), 256, 0, stream>>>(
        ffb, pw_w2 + (size_t)l * 512 * 2048, b2 + l * D_, hbuf, nullptr,
        BS_, D_, DFF_, DFF_, 0);
    ln_kernel<<<BS_ / 4, 256, 0, stream>>>(z1, hbuf, g2 + l * D_, be2 + l * D_, zr, zrb);
  }

  head_kernel<<<BS_ / 4, 256, 0, stream>>>(zr, hw, hb, out);
}

// Round 7
// 546.051 us; speedup vs baseline: 1.0235x; 1.0235x over previous
//
#include <hip/hip_runtime.h>

#define B_   2
#define S_   2048
#define D_   512
#define H_   8
#define DK_  64
#define DFF_ 2048
#define L_   2
#define BS_  (B_*S_)   // 4096
#define NPROJ 2560     // qr|qi|kr|ki|v concatenated

typedef __attribute__((ext_vector_type(8))) short bfrag;    // 8 bf16 (4 VGPRs)
typedef __attribute__((ext_vector_type(4))) float facc;     // 4 fp32
typedef __attribute__((ext_vector_type(16))) float facc16;  // 16 fp32 (32x32 C/D)
typedef __attribute__((ext_vector_type(4))) int i4v;
typedef __attribute__((ext_vector_type(2))) float f2v;      // packed fp32 pair

__device__ __forceinline__ unsigned short f2b(float f) {
  union { float f; unsigned int u; } c; c.f = f;
  unsigned int u = c.u;
  u += 0x7fffu + ((u >> 16) & 1);    // RNE
  return (unsigned short)(u >> 16);
}

__device__ __forceinline__ float b2f(unsigned short u) {
  union { unsigned u; float f; } c; c.u = (unsigned)u << 16; return c.f;
}

__device__ __forceinline__ bfrag asb(i4v x) { union { i4v a; bfrag b; } u; u.a = x; return u.b; }

__device__ __forceinline__ bfrag bneg(bfrag x) {
  union { bfrag b; i4v a; } u; u.b = x;
  u.a.x ^= 0x80008000; u.a.y ^= 0x80008000; u.a.z ^= 0x80008000; u.a.w ^= 0x80008000;
  return u.b;
}

__device__ __forceinline__ void async_copy16(const void* g, void* l) {
  __builtin_amdgcn_global_load_lds((const __attribute__((address_space(1))) void*)g,
                                   (__attribute__((address_space(3))) void*)l,
                                   16, 0, 0);
}

// ---------------- fused embedding gather + positional zi ----------------
__global__ __launch_bounds__(128) void embed_zi_kernel(const int* __restrict__ tokens,
                                                       const float* __restrict__ embed,
                                                       float* __restrict__ zr,
                                                       unsigned short* __restrict__ acat) {
  int row = blockIdx.x;
  int tok = tokens[row];
  float4 v = ((const float4*)(embed + (size_t)tok * D_))[threadIdx.x];
  ((float4*)(zr + (size_t)row * D_))[threadIdx.x] = v;
  ushort4 o; o.x = f2b(v.x); o.y = f2b(v.y); o.z = f2b(v.z); o.w = f2b(v.w);
  *(ushort4*)(acat + (size_t)row * 1024 + threadIdx.x * 4) = o;

  int s = row & (S_ - 1);
  int d0 = threadIdx.x * 4;
  const double LN1E4 = 9.210340371976184;
  #pragma unroll
  for (int t = 0; t < 4; ++t) {
    int d = d0 + t;
    int jj = d >> 1;
    double freq = exp(-((double)jj / 256.0) * LN1E4);
    float val = (float)sin((double)s * freq);
    acat[(size_t)row * 1024 + 512 + d] = f2b(val);
  }
}

// ---------------- batched weight concat+transpose (both layers) ----------------
__global__ __launch_bounds__(256) void wcat_all(const float* __restrict__ Wqr,
                                                const float* __restrict__ Wqi,
                                                const float* __restrict__ Wkr,
                                                const float* __restrict__ Wki,
                                                const float* __restrict__ Wv,
                                                unsigned short* __restrict__ dst0,
                                                unsigned short* __restrict__ dst1) {
  __shared__ float tile[64][68];
  const int l = blockIdx.z;
  const int KA = l ? 512 : 1024;
  const int k0 = blockIdx.y * 64;
  if (k0 >= KA) return;
  unsigned short* dst = l ? dst1 : dst0;
  const size_t woff = (size_t)l * D_ * D_;
  const float* wqr = Wqr + woff;
  const float* wqi = Wqi + woff;
  const float* wkr = Wkr + woff;
  const float* wki = Wki + woff;
  const float* wv  = Wv  + woff;

  const int tid = threadIdx.x;
  const int n0 = blockIdx.x * 64;
  const int p = n0 >> 9, nn0 = n0 & 511;
  const float* src;
  float sign = 1.f;
  bool zero = false;
  if (k0 < 512) {
    const float* tops[5] = {wqr, wqi, wkr, wki, wv};
    src = tops[p];
  } else {
    const float* bots[5] = {wqi, wqr, wki, wkr, nullptr};
    const float sg[5] = {-1.f, 1.f, -1.f, 1.f, 0.f};
    src = bots[p]; sign = sg[p]; zero = (p == 4);
  }
  const int kk0 = k0 & 511;
  #pragma unroll
  for (int i = 0; i < 4; ++i) {
    int lin = tid + i * 256;
    int row = lin >> 4, c4 = (lin & 15) * 4;
    float4 v = make_float4(0.f, 0.f, 0.f, 0.f);
    if (!zero) v = *(const float4*)(src + (size_t)(kk0 + row) * 512 + nn0 + c4);
    *(float4*)&tile[row][c4] = v;
  }
  __syncthreads();
  #pragma unroll
  for (int i = 0; i < 4; ++i) {
    int lin = tid + i * 256;
    int n = lin >> 4, kc4 = (lin & 15) * 4;
    ushort4 o;
    o.x = f2b(sign * tile[kc4 + 0][n]);
    o.y = f2b(sign * tile[kc4 + 1][n]);
    o.z = f2b(sign * tile[kc4 + 2][n]);
    o.w = f2b(sign * tile[kc4 + 3][n]);
    *(ushort4*)(dst + (size_t)(n0 + n) * KA + k0 + kc4) = o;
  }
}

// ---------------- batched weight transpose: wo/w1/w2 x both layers ----------------
__global__ __launch_bounds__(256) void wtr_all(const float* __restrict__ Wo,
                                               const float* __restrict__ W1,
                                               const float* __restrict__ W2,
                                               unsigned short* __restrict__ pwo,
                                               unsigned short* __restrict__ pw1,
                                               unsigned short* __restrict__ pw2) {
  __shared__ float tile[64][68];
  const int j = blockIdx.z, l = j & 1;
  const float* src; unsigned short* dst; int K, N;
  if (j < 2)      { src = Wo + (size_t)l * 512 * 512;  dst = pwo + (size_t)l * 512 * 512;  K = 512;  N = 512; }
  else if (j < 4) { src = W1 + (size_t)l * 512 * 2048; dst = pw1 + (size_t)l * 2048 * 512; K = 512;  N = 2048; }
  else            { src = W2 + (size_t)l * 2048 * 512; dst = pw2 + (size_t)l * 512 * 2048; K = 2048; N = 512; }
  const int n0 = blockIdx.x * 64, k0 = blockIdx.y * 64;
  if (n0 >= N || k0 >= K) return;
  const int tid = threadIdx.x;
  #pragma unroll
  for (int i = 0; i < 4; ++i) {
    int lin = tid + i * 256;
    int row = lin >> 4, c4 = (lin & 15) * 4;
    *(float4*)&tile[row][c4] = *(const float4*)(src + (size_t)(k0 + row) * N + n0 + c4);
  }
  __syncthreads();
  #pragma unroll
  for (int i = 0; i < 4; ++i) {
    int lin = tid + i * 256;
    int n = lin >> 4, kc4 = (lin & 15) * 4;
    ushort4 o;
    o.x = f2b(tile[kc4 + 0][n]);
    o.y = f2b(tile[kc4 + 1][n]);
    o.z = f2b(tile[kc4 + 2][n]);
    o.w = f2b(tile[kc4 + 3][n]);
    *(ushort4*)(dst + (size_t)(n0 + n) * K + k0 + kc4) = o;
  }
}

// ---------------- bf16 MFMA GEMM (m97 pattern) ----------------
template<int TM>
__global__ __launch_bounds__(256) void gemm_bf16(const unsigned short* __restrict__ A,
                                                 const unsigned short* __restrict__ Bt,
                                                 const float* __restrict__ bias,
                                                 float* __restrict__ outF,
                                                 unsigned short* __restrict__ outB,
                                                 int M, int N, int K, int lda, int relu) {
  constexpr int MT = TM / 32;
  __shared__ short smem[(TM + 128) * 32];
  short* A_s = smem;
  short* B_s = smem + TM * 32;

  const int tid = threadIdx.x;
  const int w = tid >> 6, lane = tid & 63;
  const int col = lane & 15, quad = lane >> 4;
  const int m0 = blockIdx.y * TM, n0 = blockIdx.x * 128;
  const int wrow = (w >> 1) * (TM / 2);
  const int wcol = (w & 1) * 64;

  const int srow = lane >> 2;
  const int skk  = (lane & 3) * 8;

  facc acc[MT][4];
  #pragma unroll
  for (int i = 0; i < MT; ++i)
    #pragma unroll
    for (int j = 0; j < 4; ++j) acc[i][j] = (facc){0.f, 0.f, 0.f, 0.f};

  for (int k0 = 0; k0 < K; k0 += 32) {
    __syncthreads();
    #pragma unroll
    for (int rd = 0; rd < TM / 64; ++rd) {
      int row = rd * 64 + w * 16 + srow;
      async_copy16(A + (size_t)(m0 + row) * lda + k0 + skk, &A_s[row * 32 + skk]);
    }
    #pragma unroll
    for (int rd = 0; rd < 2; ++rd) {
      int row = rd * 64 + w * 16 + srow;
      async_copy16(Bt + (size_t)(n0 + row) * K + k0 + skk, &B_s[row * 32 + skk]);
    }
    __syncthreads();

    bfrag af[MT], bf[4];
    #pragma unroll
    for (int i = 0; i < MT; ++i)
      af[i] = *(const bfrag*)&A_s[(wrow + i * 16 + col) * 32 + quad * 8];
    #pragma unroll
    for (int j = 0; j < 4; ++j)
      bf[j] = *(const bfrag*)&B_s[(wcol + j * 16 + col) * 32 + quad * 8];
    #pragma unroll
    for (int i = 0; i < MT; ++i)
      #pragma unroll
      for (int j = 0; j < 4; ++j)
        acc[i][j] = __builtin_amdgcn_mfma_f32_16x16x32_bf16(af[i], bf[j], acc[i][j], 0, 0, 0);
  }

  #pragma unroll
  for (int i = 0; i < MT; ++i) {
    #pragma unroll
    for (int j = 0; j < 4; ++j) {
      int colIdx = n0 + wcol + j * 16 + col;
      float b = bias ? bias[colIdx] : 0.f;
      #pragma unroll
      for (int r = 0; r < 4; ++r) {
        int rowIdx = m0 + wrow + i * 16 + quad * 4 + r;
        float v = acc[i][j][r] + b;
        if (relu) v = fmaxf(v, 0.f);
        if (outF) outF[(size_t)rowIdx * N + colIdx] = v;
        if (outB) outB[(size_t)rowIdx * N + colIdx] = f2b(v);
      }
    }
  }
}

// ---------------- V transpose: Q4 cols [2048,2560) -> bf16 [b,h,dk,s] ----------------
__global__ __launch_bounds__(256) void vt_kernel(const unsigned short* __restrict__ Q4,
                                                 unsigned short* __restrict__ vt) {
  __shared__ short tile[64][80];
  const int bh = blockIdx.x;
  const int b = bh >> 3, hd = bh & 7;
  const int s0 = blockIdx.y * 64;
  const int tid = threadIdx.x;
  #pragma unroll
  for (int i = 0; i < 2; ++i) {
    int lin = tid + i * 256;
    int row = lin >> 3;
    int c8 = (lin & 7) * 8;
    *(int4*)&tile[row][c8] =
      *(const int4*)(Q4 + (size_t)(b * S_ + s0 + row) * NPROJ + 2048 + hd * DK_ + c8);
  }
  __syncthreads();
  #pragma unroll
  for (int i = 0; i < 2; ++i) {
    int lin = tid + i * 256;
    int d = lin >> 3;
    int s8 = (lin & 7) * 8;
    short tmp[8];
    #pragma unroll
    for (int t = 0; t < 8; ++t) tmp[t] = tile[s8 + t][d];
    *(int4*)(vt + ((size_t)bh * DK_ + d) * S_ + s0 + s8) = *(const int4*)tmp;
  }
}

// ---------------- MFMA complex-hybrid attention, v13 ----------------
// v12 post-mortem (clean counter split of the bundle):
//  - packed softmax WORKED: VALU busy-time 32.1us -> 25.7us (-6us real work)
//  - setprio HURT: MfmaUtil 25.2 -> 22.3, total 68.7 -> 79.1us.  With all 8
//    waves raising prio around the same MFMA clusters, arbitration convoys
//    instead of interleaving -- same failure as v7; the phase barriers every
//    256 keys keep waves correlated enough that the "drift regime" never
//    materializes.  setprio is now twice-refuted on this kernel: retired.
// v13 = v12 minus setprio (single-variable step).
//  Keep: packed-fp32 softmax (f2v -> v_pk_fma_f32), phase-staged 64KB LDS
//  (2 barriers/256 keys), V direct-global, cvt_pk+permlane, persistent Q.
__global__ __launch_bounds__(512, 2) void attn_mfma(const unsigned short* __restrict__ Q4,
                                                    const unsigned short* __restrict__ VT,
                                                    unsigned short* __restrict__ po,
                                                    float* __restrict__ pl) {
  __shared__ __align__(16) short smem[32768];   // 64KB: kr[256][128B] | ki[256][128B]

  const int bh = blockIdx.y;
  const int b = bh >> 3, hd = bh & 7;
  const int hoff = hd * DK_;
  const int ks = blockIdx.z;
  const int tid = threadIdx.x;
  const int w = tid >> 6;
  const int lane = tid & 63;
  const int m = lane & 31;       // C col = q index / A m index
  const int h = lane >> 5;       // half-wave
  const int x7 = m & 7;
  const int q0 = blockIdx.x * 256 + w * 32;
  const int kb = ks * 512;

  const size_t bS = (size_t)b * S_;
  const size_t vtbase = (size_t)bh * DK_ * S_;

  // staging indices: 512 threads, 8 segs/key row; swizzle on SOURCE, linear dest
  const int skey = tid >> 3, sseg = tid & 7;
  const int sls = sseg ^ (skey & 7);            // XOR bank swizzle (K rows = 128B)

  // Q B-frags (persistent): B[kdim = t*16 + h*8 + j][n=q=m]
  bfrag qrf[4], qif[4], nqrf[4];
  {
    const size_t qrow = (bS + q0 + m) * (size_t)NPROJ + hoff;
    #pragma unroll
    for (int t = 0; t < 4; ++t) {
      qrf[t] = *(const bfrag*)(Q4 + qrow + t * 16 + h * 8);
      qif[t] = *(const bfrag*)(Q4 + qrow + 512 + t * 16 + h * 8);
      nqrf[t] = bneg(qrf[t]);
    }
  }

  facc16 o0 = {}, o1 = {};
  f2v lacc = {0.f, 0.f};
  const f2v c1v = {0.015625f, 0.015625f};   // 1/64
  const f2v c2v = {0.0375f, 0.0375f};       // 0.3/8
  const f2v epsv = {1e-30f, 1e-30f};
  const f2v halfv = {0.5f, 0.5f};
  const f2v onev = {1.f, 1.f};

  // V base pointers (per d-tile): row = tile*32 + m
  const unsigned short* vb0 = VT + vtbase + (size_t)m * S_ + kb + h * 8;
  const unsigned short* vb1 = vb0 + (size_t)32 * S_;

  char* kr_sb = (char*)smem;            // kr: 32KB
  char* ki_sb = (char*)smem + 32768;    // ki: 32KB

  for (int ph = 0; ph < 2; ++ph) {
    // all waves finished reading the previous phase's LDS (ds_reads complete
    // before their consuming MFMAs, which precede this barrier)
    __builtin_amdgcn_s_barrier();
    // stage 256 keys: 4 rounds x 64 keys, kr+ki, coalesced 16B, linear dest
    #pragma unroll
    for (int r = 0; r < 4; ++r) {
      const unsigned short* gk = Q4 + (bS + kb + ph * 256 + r * 64 + skey) * (size_t)NPROJ
                               + 1024 + hoff + sls * 8;
      async_copy16(gk,       kr_sb + r * 8192 + tid * 16);
      async_copy16(gk + 512, ki_sb + r * 8192 + tid * 16);
    }
    asm volatile("s_waitcnt vmcnt(0)" ::: "memory");
    __builtin_amdgcn_s_barrier();
    asm volatile("" ::: "memory");

    for (int c = 0; c < 4; ++c) {      // 64-key chunk, NO sync inside phase
      // ---- V frags direct from global ----
      bfrag vtf[2][4];
      #pragma unroll
      for (int kt = 0; kt < 4; ++kt) {
        vtf[0][kt] = *(const bfrag*)(vb0 + kt * 16);
        vtf[1][kt] = *(const bfrag*)(vb1 + kt * 16);
      }
      vb0 += 64; vb1 += 64;

      // ---- K frags both halves from LDS: row = c*64 + hs*32 + m ----
      bfrag kr0[4], ki0[4], kr1[4], ki1[4];
      #pragma unroll
      for (int t = 0; t < 4; ++t) {
        int off0 = (c * 64 + m) * 128 + (((2 * t + h) ^ x7) << 4);
        int off1 = (c * 64 + 32 + m) * 128 + (((2 * t + h) ^ x7) << 4);
        kr0[t] = *(const bfrag*)(kr_sb + off0);
        ki0[t] = *(const bfrag*)(ki_sb + off0);
        kr1[t] = *(const bfrag*)(kr_sb + off1);
        ki1[t] = *(const bfrag*)(ki_sb + off1);
      }

      // ---- QK both halves ----
      facc16 sr0 = {}, si0 = {}, sr1 = {}, si1 = {};
      #pragma unroll
      for (int t = 0; t < 4; ++t) {
        sr0 = __builtin_amdgcn_mfma_f32_32x32x16_bf16(kr0[t], qrf[t], sr0, 0, 0, 0);
        si0 = __builtin_amdgcn_mfma_f32_32x32x16_bf16(kr0[t], qif[t], si0, 0, 0, 0);
        sr0 = __builtin_amdgcn_mfma_f32_32x32x16_bf16(ki0[t], qif[t], sr0, 0, 0, 0);
        si0 = __builtin_amdgcn_mfma_f32_32x32x16_bf16(ki0[t], nqrf[t], si0, 0, 0, 0);
      }
      #pragma unroll
      for (int t = 0; t < 4; ++t) {
        sr1 = __builtin_amdgcn_mfma_f32_32x32x16_bf16(kr1[t], qrf[t], sr1, 0, 0, 0);
        si1 = __builtin_amdgcn_mfma_f32_32x32x16_bf16(kr1[t], qif[t], si1, 0, 0, 0);
        sr1 = __builtin_amdgcn_mfma_f32_32x32x16_bf16(ki1[t], qif[t], sr1, 0, 0, 0);
        si1 = __builtin_amdgcn_mfma_f32_32x32x16_bf16(ki1[t], nqrf[t], si1, 0, 0, 0);
      }

      #pragma unroll
      for (int hs = 0; hs < 2; ++hs) {
        const facc16& sr = hs ? sr1 : sr0;
        const facc16& si = hs ? si1 : si0;

        // ---- hybrid score -> p = exp(x) ~ 1 + x + x^2/2, PACKED fp32 ----
        f2v pk[8];
        f2v psum = {0.f, 0.f};
        #pragma unroll
        for (int i = 0; i < 8; ++i) {
          f2v a  = { sr[2 * i], sr[2 * i + 1] };
          f2v bb = { si[2 * i], si[2 * i + 1] };
          f2v d2 = a * a + (bb * bb + epsv);
          f2v rs = { rsqrtf(d2.x), rsqrtf(d2.y) };
          f2v u  = c1v * d2 + c2v * a;
          f2v x  = rs * u;
          f2v p2 = x * (halfv * x + onev) + onev;
          pk[i] = p2;
          psum += p2;
        }
        lacc += psum;

        // ---- pack P (cvt_pk RNE) + permlane32_swap cross-half exchange ----
        unsigned dw[8];
        #pragma unroll
        for (int i = 0; i < 8; ++i)
          asm("v_cvt_pk_bf16_f32 %0, %1, %2" : "=v"(dw[i]) : "v"(pk[i].x), "v"(pk[i].y));
        unsigned s0a = dw[0], s0b = dw[2];
        unsigned s1a = dw[1], s1b = dw[3];
        unsigned s2a = dw[4], s2b = dw[6];
        unsigned s3a = dw[5], s3b = dw[7];
        asm("v_permlane32_swap_b32 %0, %1" : "+v"(s0a), "+v"(s0b));
        asm("v_permlane32_swap_b32 %0, %1" : "+v"(s1a), "+v"(s1b));
        asm("v_permlane32_swap_b32 %0, %1" : "+v"(s2a), "+v"(s2b));
        asm("v_permlane32_swap_b32 %0, %1" : "+v"(s3a), "+v"(s3b));
        i4v f0 = { (int)s0a, (int)s1a, (int)s0b, (int)s1b };
        i4v f1 = { (int)s2a, (int)s3a, (int)s2b, (int)s3b };
        bfrag pf0 = asb(f0), pf1 = asb(f1);

        // ---- PV: o^T[d][q] += V^T x P^T (k-slots 2*hs, 2*hs+1) ----
        o0 = __builtin_amdgcn_mfma_f32_32x32x16_bf16(vtf[0][2 * hs + 0], pf0, o0, 0, 0, 0);
        o0 = __builtin_amdgcn_mfma_f32_32x32x16_bf16(vtf[0][2 * hs + 1], pf1, o0, 0, 0, 0);
        o1 = __builtin_amdgcn_mfma_f32_32x32x16_bf16(vtf[1][2 * hs + 0], pf0, o1, 0, 0, 0);
        o1 = __builtin_amdgcn_mfma_f32_32x32x16_bf16(vtf[1][2 * hs + 1], pf1, o1, 0, 0, 0);
      }
    }
  }

  // ---- epilogue: write per-split partials (bf16 o, fp32 l) ----
  float l = lacc.x + lacc.y;
  float l_tot = l + __shfl_xor(l, 32);
  const size_t prow = ((size_t)(bh * 4 + ks)) * S_ + q0 + m;
  #pragma unroll
  for (int tile = 0; tile < 2; ++tile) {
    const facc16& oo = tile ? o1 : o0;
    #pragma unroll
    for (int rg = 0; rg < 4; ++rg) {
      int d0 = tile * 32 + rg * 8 + h * 4;        // d = (reg&3)+8*(reg>>2)+4h
      ushort4 ob;
      ob.x = f2b(oo[4 * rg + 0]);
      ob.y = f2b(oo[4 * rg + 1]);
      ob.z = f2b(oo[4 * rg + 2]);
      ob.w = f2b(oo[4 * rg + 3]);
      *(ushort4*)(po + prow * 64 + d0) = ob;
    }
  }
  if (lane < 32) pl[prow] = l_tot;
}

// ---------------- combine the 4 key-split partials -> ctxb ----------------
__global__ __launch_bounds__(256) void attn_combine(const unsigned short* __restrict__ po,
                                                    const float* __restrict__ pl,
                                                    unsigned short* __restrict__ ctxb) {
  int t = blockIdx.x * 256 + threadIdx.x;      // 262144 threads
  int row = t >> 3;                            // bh*S + q
  int dg = t & 7;
  int bh = row >> 11, q = row & (S_ - 1);
  int b = bh >> 3, hd = bh & 7;
  float acc[8];
  #pragma unroll
  for (int e = 0; e < 8; ++e) acc[e] = 0.f;
  float ls = 0.f;
  #pragma unroll
  for (int ks = 0; ks < 4; ++ks) {
    size_t prow = (((size_t)(bh * 4 + ks)) << 11) + q;
    ls += pl[prow];
    const unsigned short* src = po + prow * 64 + dg * 8;
    ushort4 v0 = *(const ushort4*)src;
    ushort4 v1 = *(const ushort4*)(src + 4);
    acc[0] += b2f(v0.x); acc[1] += b2f(v0.y); acc[2] += b2f(v0.z); acc[3] += b2f(v0.w);
    acc[4] += b2f(v1.x); acc[5] += b2f(v1.y); acc[6] += b2f(v1.z); acc[7] += b2f(v1.w);
  }
  float inv = 1.f / ls;
  unsigned short ob[8];
  #pragma unroll
  for (int e = 0; e < 8; ++e) ob[e] = f2b(acc[e] * inv);
  *(int4*)(ctxb + ((size_t)(b * S_ + q)) * D_ + hd * DK_ + dg * 8) = *(const int4*)ob;
}

// ---------------- layernorm ----------------
__global__ __launch_bounds__(256) void ln_kernel(const float* __restrict__ X,
                                                 const float* __restrict__ R,
                                                 const float* __restrict__ g,
                                                 const float* __restrict__ be,
                                                 float* __restrict__ OutF,
                                                 unsigned short* __restrict__ OutB) {
  const int lane = threadIdx.x & 63;
  const int wv = threadIdx.x >> 6;
  const int row = blockIdx.x * 4 + wv;
  const float* xp = X + (size_t)row * D_;
  const float* rp = R + (size_t)row * D_;
  float x[8];
  float s = 0.f;
  #pragma unroll
  for (int i = 0; i < 8; ++i) {
    int d = i * 64 + lane;
    x[i] = xp[d] + rp[d];
    s += x[i];
  }
  s += __shfl_xor(s, 32); s += __shfl_xor(s, 16); s += __shfl_xor(s, 8);
  s += __shfl_xor(s, 4);  s += __shfl_xor(s, 2);  s += __shfl_xor(s, 1);
  float mu = s * (1.f / 512.f);
  float vs = 0.f;
  #pragma unroll
  for (int i = 0; i < 8; ++i) { float d = x[i] - mu; vs += d * d; }
  vs += __shfl_xor(vs, 32); vs += __shfl_xor(vs, 16); vs += __shfl_xor(vs, 8);
  vs += __shfl_xor(vs, 4);  vs += __shfl_xor(vs, 2);  vs += __shfl_xor(vs, 1);
  float rstd = rsqrtf(vs * (1.f / 512.f) + 1e-5f);
  #pragma unroll
  for (int i = 0; i < 8; ++i) {
    int d = i * 64 + lane;
    float v = (x[i] - mu) * rstd * g[d] + be[d];
    if (OutF) OutF[(size_t)row * D_ + d] = v;
    if (OutB) OutB[(size_t)row * D_ + d] = f2b(v);
  }
}

// ---------------- classifier head ----------------
__global__ __launch_bounds__(256) void head_kernel(const float* __restrict__ Z,
                                                   const float* __restrict__ hw,
                                                   const float* __restrict__ hb,
                                                   float* __restrict__ out) {
  const int lane = threadIdx.x & 63;
  const int wv = threadIdx.x >> 6;
  const int row = blockIdx.x * 4 + wv;
  const float* zp = Z + (size_t)row * D_;
  float a0 = 0.f, a1 = 0.f;
  #pragma unroll
  for (int i = 0; i < 8; ++i) {
    int d = i * 64 + lane;
    float z = zp[d];
    a0 += z * hw[d * 2];
    a1 += z * hw[d * 2 + 1];
  }
  a0 += __shfl_xor(a0, 32); a0 += __shfl_xor(a0, 16); a0 += __shfl_xor(a0, 8);
  a0 += __shfl_xor(a0, 4);  a0 += __shfl_xor(a0, 2);  a0 += __shfl_xor(a0, 1);
  a1 += __shfl_xor(a1, 32); a1 += __shfl_xor(a1, 16); a1 += __shfl_xor(a1, 8);
  a1 += __shfl_xor(a1, 4);  a1 += __shfl_xor(a1, 2);  a1 += __shfl_xor(a1, 1);
  if (lane == 0) {
    out[row * 2]     = a0 + hb[0];
    out[row * 2 + 1] = a1 + hb[1];
  }
}

extern "C" void kernel_launch(void* const* d_in, const int* in_sizes, int n_in,
                              void* d_out, int out_size, void* d_ws, size_t ws_size,
                              hipStream_t stream) {
  const int*   tokens = (const int*)  d_in[0];
  const float* embed  = (const float*)d_in[1];
  const float* Wqr = (const float*)d_in[2];
  const float* Wqi = (const float*)d_in[3];
  const float* Wkr = (const float*)d_in[4];
  const float* Wki = (const float*)d_in[5];
  const float* Wv  = (const float*)d_in[6];
  const float* Wo  = (const float*)d_in[7];
  const float* bo  = (const float*)d_in[8];
  const float* W1  = (const float*)d_in[9];
  const float* b1  = (const float*)d_in[10];
  const float* W2  = (const float*)d_in[11];
  const float* b2  = (const float*)d_in[12];
  const float* g1  = (const float*)d_in[13];
  const float* be1 = (const float*)d_in[14];
  const float* g2  = (const float*)d_in[15];
  const float* be2 = (const float*)d_in[16];
  const float* hw  = (const float*)d_in[17];
  const float* hb  = (const float*)d_in[18];
  float* out = (float*)d_out;

  char* p = (char*)d_ws;
  float* zr = (float*)p;             p += (size_t)BS_ * D_ * 4;           // 8 MB
  unsigned short* acat = (unsigned short*)p;
  unsigned short* zrb  = acat;       p += (size_t)BS_ * 1024 * 2;         // 8 MB
  unsigned short* Q4   = (unsigned short*)p;
  unsigned short* ffb  = Q4;         p += (size_t)BS_ * NPROJ * 2;        // 20 MB
  unsigned short* VT   = (unsigned short*)p; p += (size_t)B_*H_*DK_*S_*2; // 4 MB
  unsigned short* ctxb = (unsigned short*)p; p += (size_t)BS_ * D_ * 2;   // 4 MB
  float* hbuf = (float*)p;           p += (size_t)BS_ * D_ * 4;           // 8 MB
  float* z1   = (float*)p;           p += (size_t)BS_ * D_ * 4;           // 8 MB  (contiguous after hbuf)
  unsigned short* z1b = (unsigned short*)p;  p += (size_t)BS_ * D_ * 2;   // 4 MB  (contiguous after z1)
  unsigned short* pw_proj0 = (unsigned short*)p; p += (size_t)NPROJ * 1024 * 2; // 5 MB
  unsigned short* pw_proj1 = (unsigned short*)p; p += (size_t)NPROJ * 512 * 2;  // 2.5 MB
  unsigned short* pw_wo = (unsigned short*)p;    p += (size_t)2 * 512 * 512 * 2;   // 1 MB
  unsigned short* pw_w1 = (unsigned short*)p;    p += (size_t)2 * 2048 * 512 * 2;  // 4 MB
  unsigned short* pw_w2 = (unsigned short*)p;    p += (size_t)2 * 512 * 2048 * 2;  // 4 MB
  float* pl = (float*)p;             p += (size_t)16 * 4 * S_ * 4;        // 0.5 MB

  // po bf16 [16 bh][4 ks][2048 q][64 d] = 16.78 MB -> aliases hbuf+z1+start of z1b
  // (all dead during attention; combine reads po before the Wo GEMM rewrites hbuf)
  unsigned short* po = (unsigned short*)hbuf;

  embed_zi_kernel<<<BS_, 128, 0, stream>>>(tokens, embed, zr, acat);
  wcat_all<<<dim3(NPROJ / 64, 16, 2), 256, 0, stream>>>(Wqr, Wqi, Wkr, Wki, Wv,
                                                        pw_proj0, pw_proj1);
  wtr_all<<<dim3(32, 32, 6), 256, 0, stream>>>(Wo, W1, W2, pw_wo, pw_w1, pw_w2);

  for (int l = 0; l < L_; ++l) {
    const int KA = (l == 0) ? 1024 : 512;
    const unsigned short* Aproj = (l == 0) ? acat : zrb;
    const unsigned short* Wproj = (l == 0) ? pw_proj0 : pw_proj1;

    gemm_bf16<128><<<dim3(NPROJ / 128, BS_ / 128), 256, 0, stream>>>(
        Aproj, Wproj, nullptr, nullptr, Q4, BS_, NPROJ, KA, KA, 0);

    vt_kernel<<<dim3(B_ * H_, S_ / 64), 256, 0, stream>>>(Q4, VT);
    attn_mfma<<<dim3(S_ / 256, B_ * H_, 4), 512, 0, stream>>>(Q4, VT, po, pl);
    attn_combine<<<1024, 256, 0, stream>>>(po, pl, ctxb);

    gemm_bf16<64><<<dim3(D_ / 128, BS_ / 64), 256, 0, stream>>>(
        ctxb, pw_wo + (size_t)l * 512 * 512, bo + l * D_, hbuf, nullptr,
        BS_, D_, D_, D_, 0);
    ln_kernel<<<BS_ / 4, 256, 0, stream>>>(zr, hbuf, g1 + l * D_, be1 + l * D_, z1, z1b);

    gemm_bf16<128><<<dim3(DFF_ / 128, BS_ / 128), 256, 0, stream>>>(
        z1b, pw_w1 + (size_t)l * 2048 * 512, b1 + l * DFF_, nullptr, ffb,
        BS_, DFF_, D_, D_, 1);
    gemm_bf16<64><<<dim3(D_ / 128, BS_ / 64), 256, 0, stream>>>(
        ffb, pw_w2 + (size_t)l * 512 * 2048, b2 + l * D_, hbuf, nullptr,
        BS_, D_, DFF_, DFF_, 0);
    ln_kernel<<<BS_ / 4, 256, 0, stream>>>(z1, hbuf, g2 + l * D_, be2 + l * D_, zr, zrb);
  }

  head_kernel<<<BS_ / 4, 256, 0, stream>>>(zr, hw, hb, out);
}

// Round 8
// 509.728 us; speedup vs baseline: 1.0964x; 1.0713x over previous
//
#include <hip/hip_runtime.h>

#define B_   2
#define S_   2048
#define D_   512
#define H_   8
#define DK_  64
#define DFF_ 2048
#define L_   2
#define BS_  (B_*S_)   // 4096
#define NPROJ 2560     // qr|qi|kr|ki|v concatenated

typedef __attribute__((ext_vector_type(8))) short bfrag;    // 8 bf16 (4 VGPRs)
typedef __attribute__((ext_vector_type(4))) float facc;     // 4 fp32
typedef __attribute__((ext_vector_type(16))) float facc16;  // 16 fp32 (32x32 C/D)
typedef __attribute__((ext_vector_type(4))) int i4v;

__device__ __forceinline__ unsigned short f2b(float f) {
  union { float f; unsigned int u; } c; c.f = f;
  unsigned int u = c.u;
  u += 0x7fffu + ((u >> 16) & 1);    // RNE
  return (unsigned short)(u >> 16);
}

__device__ __forceinline__ float b2f(unsigned short u) {
  union { unsigned u; float f; } c; c.u = (unsigned)u << 16; return c.f;
}

__device__ __forceinline__ bfrag asb(i4v x) { union { i4v a; bfrag b; } u; u.a = x; return u.b; }

__device__ __forceinline__ bfrag bneg(bfrag x) {
  union { bfrag b; i4v a; } u; u.b = x;
  u.a.x ^= 0x80008000; u.a.y ^= 0x80008000; u.a.z ^= 0x80008000; u.a.w ^= 0x80008000;
  return u.b;
}

__device__ __forceinline__ void async_copy16(const void* g, void* l) {
  __builtin_amdgcn_global_load_lds((const __attribute__((address_space(1))) void*)g,
                                   (__attribute__((address_space(3))) void*)l,
                                   16, 0, 0);
}

// ---------------- fused embedding gather + positional zi ----------------
__global__ __launch_bounds__(128) void embed_zi_kernel(const int* __restrict__ tokens,
                                                       const float* __restrict__ embed,
                                                       float* __restrict__ zr,
                                                       unsigned short* __restrict__ acat) {
  int row = blockIdx.x;
  int tok = tokens[row];
  float4 v = ((const float4*)(embed + (size_t)tok * D_))[threadIdx.x];
  ((float4*)(zr + (size_t)row * D_))[threadIdx.x] = v;
  ushort4 o; o.x = f2b(v.x); o.y = f2b(v.y); o.z = f2b(v.z); o.w = f2b(v.w);
  *(ushort4*)(acat + (size_t)row * 1024 + threadIdx.x * 4) = o;

  int s = row & (S_ - 1);
  int d0 = threadIdx.x * 4;
  const double LN1E4 = 9.210340371976184;
  #pragma unroll
  for (int t = 0; t < 4; ++t) {
    int d = d0 + t;
    int jj = d >> 1;
    double freq = exp(-((double)jj / 256.0) * LN1E4);
    float val = (float)sin((double)s * freq);
    acat[(size_t)row * 1024 + 512 + d] = f2b(val);
  }
}

// ---------------- batched weight concat+transpose (both layers) ----------------
__global__ __launch_bounds__(256) void wcat_all(const float* __restrict__ Wqr,
                                                const float* __restrict__ Wqi,
                                                const float* __restrict__ Wkr,
                                                const float* __restrict__ Wki,
                                                const float* __restrict__ Wv,
                                                unsigned short* __restrict__ dst0,
                                                unsigned short* __restrict__ dst1) {
  __shared__ float tile[64][68];
  const int l = blockIdx.z;
  const int KA = l ? 512 : 1024;
  const int k0 = blockIdx.y * 64;
  if (k0 >= KA) return;
  unsigned short* dst = l ? dst1 : dst0;
  const size_t woff = (size_t)l * D_ * D_;
  const float* wqr = Wqr + woff;
  const float* wqi = Wqi + woff;
  const float* wkr = Wkr + woff;
  const float* wki = Wki + woff;
  const float* wv  = Wv  + woff;

  const int tid = threadIdx.x;
  const int n0 = blockIdx.x * 64;
  const int p = n0 >> 9, nn0 = n0 & 511;
  const float* src;
  float sign = 1.f;
  bool zero = false;
  if (k0 < 512) {
    const float* tops[5] = {wqr, wqi, wkr, wki, wv};
    src = tops[p];
  } else {
    const float* bots[5] = {wqi, wqr, wki, wkr, nullptr};
    const float sg[5] = {-1.f, 1.f, -1.f, 1.f, 0.f};
    src = bots[p]; sign = sg[p]; zero = (p == 4);
  }
  const int kk0 = k0 & 511;
  #pragma unroll
  for (int i = 0; i < 4; ++i) {
    int lin = tid + i * 256;
    int row = lin >> 4, c4 = (lin & 15) * 4;
    float4 v = make_float4(0.f, 0.f, 0.f, 0.f);
    if (!zero) v = *(const float4*)(src + (size_t)(kk0 + row) * 512 + nn0 + c4);
    *(float4*)&tile[row][c4] = v;
  }
  __syncthreads();
  #pragma unroll
  for (int i = 0; i < 4; ++i) {
    int lin = tid + i * 256;
    int n = lin >> 4, kc4 = (lin & 15) * 4;
    ushort4 o;
    o.x = f2b(sign * tile[kc4 + 0][n]);
    o.y = f2b(sign * tile[kc4 + 1][n]);
    o.z = f2b(sign * tile[kc4 + 2][n]);
    o.w = f2b(sign * tile[kc4 + 3][n]);
    *(ushort4*)(dst + (size_t)(n0 + n) * KA + k0 + kc4) = o;
  }
}

// ---------------- batched weight transpose: wo/w1/w2 x both layers ----------------
__global__ __launch_bounds__(256) void wtr_all(const float* __restrict__ Wo,
                                               const float* __restrict__ W1,
                                               const float* __restrict__ W2,
                                               unsigned short* __restrict__ pwo,
                                               unsigned short* __restrict__ pw1,
                                               unsigned short* __restrict__ pw2) {
  __shared__ float tile[64][68];
  const int j = blockIdx.z, l = j & 1;
  const float* src; unsigned short* dst; int K, N;
  if (j < 2)      { src = Wo + (size_t)l * 512 * 512;  dst = pwo + (size_t)l * 512 * 512;  K = 512;  N = 512; }
  else if (j < 4) { src = W1 + (size_t)l * 512 * 2048; dst = pw1 + (size_t)l * 2048 * 512; K = 512;  N = 2048; }
  else            { src = W2 + (size_t)l * 2048 * 512; dst = pw2 + (size_t)l * 512 * 2048; K = 2048; N = 512; }
  const int n0 = blockIdx.x * 64, k0 = blockIdx.y * 64;
  if (n0 >= N || k0 >= K) return;
  const int tid = threadIdx.x;
  #pragma unroll
  for (int i = 0; i < 4; ++i) {
    int lin = tid + i * 256;
    int row = lin >> 4, c4 = (lin & 15) * 4;
    *(float4*)&tile[row][c4] = *(const float4*)(src + (size_t)(k0 + row) * N + n0 + c4);
  }
  __syncthreads();
  #pragma unroll
  for (int i = 0; i < 4; ++i) {
    int lin = tid + i * 256;
    int n = lin >> 4, kc4 = (lin & 15) * 4;
    ushort4 o;
    o.x = f2b(tile[kc4 + 0][n]);
    o.y = f2b(tile[kc4 + 1][n]);
    o.z = f2b(tile[kc4 + 2][n]);
    o.w = f2b(tile[kc4 + 3][n]);
    *(ushort4*)(dst + (size_t)(n0 + n) * K + k0 + kc4) = o;
  }
}

// ---------------- bf16 MFMA GEMM (m97 pattern, TM x TN tiles) ----------------
// v14: TN template param.  wo/w2 (N=512) at TN=128 had grid = 256 blocks =
// 1 block/CU -- zero cross-block overlap for the per-K-step load drain, ~90%
// stall on w2 (K=2048).  <64,64> doubles the grid to 512 = 2 blocks/CU.
template<int TM, int TN>
__global__ __launch_bounds__(256) void gemm_bf16(const unsigned short* __restrict__ A,
                                                 const unsigned short* __restrict__ Bt,
                                                 const float* __restrict__ bias,
                                                 float* __restrict__ outF,
                                                 unsigned short* __restrict__ outB,
                                                 int M, int N, int K, int lda, int relu) {
  constexpr int MT = TM / 32;
  constexpr int NT = TN / 32;
  __shared__ short smem[(TM + TN) * 32];
  short* A_s = smem;
  short* B_s = smem + TM * 32;

  const int tid = threadIdx.x;
  const int w = tid >> 6, lane = tid & 63;
  const int col = lane & 15, quad = lane >> 4;
  const int m0 = blockIdx.y * TM, n0 = blockIdx.x * TN;
  const int wrow = (w >> 1) * (TM / 2);
  const int wcol = (w & 1) * (TN / 2);

  const int srow = lane >> 2;
  const int skk  = (lane & 3) * 8;

  facc acc[MT][NT];
  #pragma unroll
  for (int i = 0; i < MT; ++i)
    #pragma unroll
    for (int j = 0; j < NT; ++j) acc[i][j] = (facc){0.f, 0.f, 0.f, 0.f};

  for (int k0 = 0; k0 < K; k0 += 32) {
    __syncthreads();
    #pragma unroll
    for (int rd = 0; rd < TM / 64; ++rd) {
      int row = rd * 64 + w * 16 + srow;
      async_copy16(A + (size_t)(m0 + row) * lda + k0 + skk, &A_s[row * 32 + skk]);
    }
    #pragma unroll
    for (int rd = 0; rd < TN / 64; ++rd) {
      int row = rd * 64 + w * 16 + srow;
      async_copy16(Bt + (size_t)(n0 + row) * K + k0 + skk, &B_s[row * 32 + skk]);
    }
    __syncthreads();

    bfrag af[MT], bf[NT];
    #pragma unroll
    for (int i = 0; i < MT; ++i)
      af[i] = *(const bfrag*)&A_s[(wrow + i * 16 + col) * 32 + quad * 8];
    #pragma unroll
    for (int j = 0; j < NT; ++j)
      bf[j] = *(const bfrag*)&B_s[(wcol + j * 16 + col) * 32 + quad * 8];
    #pragma unroll
    for (int i = 0; i < MT; ++i)
      #pragma unroll
      for (int j = 0; j < NT; ++j)
        acc[i][j] = __builtin_amdgcn_mfma_f32_16x16x32_bf16(af[i], bf[j], acc[i][j], 0, 0, 0);
  }

  #pragma unroll
  for (int i = 0; i < MT; ++i) {
    #pragma unroll
    for (int j = 0; j < NT; ++j) {
      int colIdx = n0 + wcol + j * 16 + col;
      float b = bias ? bias[colIdx] : 0.f;
      #pragma unroll
      for (int r = 0; r < 4; ++r) {
        int rowIdx = m0 + wrow + i * 16 + quad * 4 + r;
        float v = acc[i][j][r] + b;
        if (relu) v = fmaxf(v, 0.f);
        if (outF) outF[(size_t)rowIdx * N + colIdx] = v;
        if (outB) outB[(size_t)rowIdx * N + colIdx] = f2b(v);
      }
    }
  }
}

// ---------------- V transpose: Q4 cols [2048,2560) -> bf16 [b,h,dk,s] ----------------
__global__ __launch_bounds__(256) void vt_kernel(const unsigned short* __restrict__ Q4,
                                                 unsigned short* __restrict__ vt) {
  __shared__ short tile[64][80];
  const int bh = blockIdx.x;
  const int b = bh >> 3, hd = bh & 7;
  const int s0 = blockIdx.y * 64;
  const int tid = threadIdx.x;
  #pragma unroll
  for (int i = 0; i < 2; ++i) {
    int lin = tid + i * 256;
    int row = lin >> 3;
    int c8 = (lin & 7) * 8;
    *(int4*)&tile[row][c8] =
      *(const int4*)(Q4 + (size_t)(b * S_ + s0 + row) * NPROJ + 2048 + hd * DK_ + c8);
  }
  __syncthreads();
  #pragma unroll
  for (int i = 0; i < 2; ++i) {
    int lin = tid + i * 256;
    int d = lin >> 3;
    int s8 = (lin & 7) * 8;
    short tmp[8];
    #pragma unroll
    for (int t = 0; t < 8; ++t) tmp[t] = tile[s8 + t][d];
    *(int4*)(vt + ((size_t)bh * DK_ + d) * S_ + s0 + s8) = *(const int4*)tmp;
  }
}

// ---------------- MFMA complex-hybrid attention, v14 (= v11, measured best) ----------------
// v13 post-mortem: packed softmax cut VALU busy 32.1->26.5us but TOTAL rose
// 68.7->72.6us -- the scalar VALU work was latency-hiding filler for the
// V-global and LDS-read chains; removing it exposed stall.  Both VALU opts
// (packing, setprio) are now refuted on this kernel.  v14 reverts attn to the
// v11 config verbatim: scalar softmax, cvt_pk+permlane, phase-staged 64KB
// LDS (2 barriers / 256 keys), V direct-global, persistent Q frags.
__global__ __launch_bounds__(512, 2) void attn_mfma(const unsigned short* __restrict__ Q4,
                                                    const unsigned short* __restrict__ VT,
                                                    unsigned short* __restrict__ po,
                                                    float* __restrict__ pl) {
  __shared__ __align__(16) short smem[32768];   // 64KB: kr[256][128B] | ki[256][128B]

  const int bh = blockIdx.y;
  const int b = bh >> 3, hd = bh & 7;
  const int hoff = hd * DK_;
  const int ks = blockIdx.z;
  const int tid = threadIdx.x;
  const int w = tid >> 6;
  const int lane = tid & 63;
  const int m = lane & 31;       // C col = q index / A m index
  const int h = lane >> 5;       // half-wave
  const int x7 = m & 7;
  const int q0 = blockIdx.x * 256 + w * 32;
  const int kb = ks * 512;

  const size_t bS = (size_t)b * S_;
  const size_t vtbase = (size_t)bh * DK_ * S_;

  // staging indices: 512 threads, 8 segs/key row; swizzle on SOURCE, linear dest
  const int skey = tid >> 3, sseg = tid & 7;
  const int sls = sseg ^ (skey & 7);            // XOR bank swizzle (K rows = 128B)

  // Q B-frags (persistent): B[kdim = t*16 + h*8 + j][n=q=m]
  bfrag qrf[4], qif[4], nqrf[4];
  {
    const size_t qrow = (bS + q0 + m) * (size_t)NPROJ + hoff;
    #pragma unroll
    for (int t = 0; t < 4; ++t) {
      qrf[t] = *(const bfrag*)(Q4 + qrow + t * 16 + h * 8);
      qif[t] = *(const bfrag*)(Q4 + qrow + 512 + t * 16 + h * 8);
      nqrf[t] = bneg(qrf[t]);
    }
  }

  facc16 o0 = {}, o1 = {};
  float l = 0.f;
  const float c1 = 0.015625f;   // 1/64
  const float c2 = 0.0375f;     // 0.3/8

  // V base pointers (per d-tile): row = tile*32 + m
  const unsigned short* vb0 = VT + vtbase + (size_t)m * S_ + kb + h * 8;
  const unsigned short* vb1 = vb0 + (size_t)32 * S_;

  char* kr_sb = (char*)smem;            // kr: 32KB
  char* ki_sb = (char*)smem + 32768;    // ki: 32KB

  for (int ph = 0; ph < 2; ++ph) {
    // all waves finished reading the previous phase's LDS (ds_reads complete
    // before their consuming MFMAs, which precede this barrier)
    __builtin_amdgcn_s_barrier();
    // stage 256 keys: 4 rounds x 64 keys, kr+ki, coalesced 16B, linear dest
    #pragma unroll
    for (int r = 0; r < 4; ++r) {
      const unsigned short* gk = Q4 + (bS + kb + ph * 256 + r * 64 + skey) * (size_t)NPROJ
                               + 1024 + hoff + sls * 8;
      async_copy16(gk,       kr_sb + r * 8192 + tid * 16);
      async_copy16(gk + 512, ki_sb + r * 8192 + tid * 16);
    }
    asm volatile("s_waitcnt vmcnt(0)" ::: "memory");
    __builtin_amdgcn_s_barrier();
    asm volatile("" ::: "memory");

    for (int c = 0; c < 4; ++c) {      // 64-key chunk, NO sync inside phase
      // ---- V frags direct from global ----
      bfrag vtf[2][4];
      #pragma unroll
      for (int kt = 0; kt < 4; ++kt) {
        vtf[0][kt] = *(const bfrag*)(vb0 + kt * 16);
        vtf[1][kt] = *(const bfrag*)(vb1 + kt * 16);
      }
      vb0 += 64; vb1 += 64;

      // ---- K frags both halves from LDS: row = c*64 + hs*32 + m ----
      bfrag kr0[4], ki0[4], kr1[4], ki1[4];
      #pragma unroll
      for (int t = 0; t < 4; ++t) {
        int off0 = (c * 64 + m) * 128 + (((2 * t + h) ^ x7) << 4);
        int off1 = (c * 64 + 32 + m) * 128 + (((2 * t + h) ^ x7) << 4);
        kr0[t] = *(const bfrag*)(kr_sb + off0);
        ki0[t] = *(const bfrag*)(ki_sb + off0);
        kr1[t] = *(const bfrag*)(kr_sb + off1);
        ki1[t] = *(const bfrag*)(ki_sb + off1);
      }

      // ---- QK both halves ----
      facc16 sr0 = {}, si0 = {}, sr1 = {}, si1 = {};
      #pragma unroll
      for (int t = 0; t < 4; ++t) {
        sr0 = __builtin_amdgcn_mfma_f32_32x32x16_bf16(kr0[t], qrf[t], sr0, 0, 0, 0);
        si0 = __builtin_amdgcn_mfma_f32_32x32x16_bf16(kr0[t], qif[t], si0, 0, 0, 0);
        sr0 = __builtin_amdgcn_mfma_f32_32x32x16_bf16(ki0[t], qif[t], sr0, 0, 0, 0);
        si0 = __builtin_amdgcn_mfma_f32_32x32x16_bf16(ki0[t], nqrf[t], si0, 0, 0, 0);
      }
      #pragma unroll
      for (int t = 0; t < 4; ++t) {
        sr1 = __builtin_amdgcn_mfma_f32_32x32x16_bf16(kr1[t], qrf[t], sr1, 0, 0, 0);
        si1 = __builtin_amdgcn_mfma_f32_32x32x16_bf16(kr1[t], qif[t], si1, 0, 0, 0);
        sr1 = __builtin_amdgcn_mfma_f32_32x32x16_bf16(ki1[t], qif[t], sr1, 0, 0, 0);
        si1 = __builtin_amdgcn_mfma_f32_32x32x16_bf16(ki1[t], nqrf[t], si1, 0, 0, 0);
      }

      #pragma unroll
      for (int hs = 0; hs < 2; ++hs) {
        const facc16& sr = hs ? sr1 : sr0;
        const facc16& si = hs ? si1 : si0;

        // ---- hybrid score -> p = exp(x) ~ 1 + x + x^2/2 (|x| <~ 0.2) ----
        float p[16], ssum = 0.f;
        #pragma unroll
        for (int i = 0; i < 16; ++i) {
          float a = sr[i], bb = si[i];
          float d2 = __builtin_fmaf(a, a, __builtin_fmaf(bb, bb, 1e-30f));
          float rs = rsqrtf(d2);
          float x = rs * __builtin_fmaf(c1, d2, c2 * a);
          p[i] = __builtin_fmaf(x, __builtin_fmaf(0.5f, x, 1.f), 1.f);
          ssum += p[i];
        }
        l += ssum;

        // ---- pack P (cvt_pk RNE) + permlane32_swap cross-half exchange ----
        unsigned dw[8];
        #pragma unroll
        for (int i = 0; i < 8; ++i)
          asm("v_cvt_pk_bf16_f32 %0, %1, %2" : "=v"(dw[i]) : "v"(p[2 * i]), "v"(p[2 * i + 1]));
        unsigned s0a = dw[0], s0b = dw[2];
        unsigned s1a = dw[1], s1b = dw[3];
        unsigned s2a = dw[4], s2b = dw[6];
        unsigned s3a = dw[5], s3b = dw[7];
        asm("v_permlane32_swap_b32 %0, %1" : "+v"(s0a), "+v"(s0b));
        asm("v_permlane32_swap_b32 %0, %1" : "+v"(s1a), "+v"(s1b));
        asm("v_permlane32_swap_b32 %0, %1" : "+v"(s2a), "+v"(s2b));
        asm("v_permlane32_swap_b32 %0, %1" : "+v"(s3a), "+v"(s3b));
        i4v f0 = { (int)s0a, (int)s1a, (int)s0b, (int)s1b };
        i4v f1 = { (int)s2a, (int)s3a, (int)s2b, (int)s3b };
        bfrag pf0 = asb(f0), pf1 = asb(f1);

        // ---- PV: o^T[d][q] += V^T x P^T (k-slots 2*hs, 2*hs+1) ----
        o0 = __builtin_amdgcn_mfma_f32_32x32x16_bf16(vtf[0][2 * hs + 0], pf0, o0, 0, 0, 0);
        o0 = __builtin_amdgcn_mfma_f32_32x32x16_bf16(vtf[0][2 * hs + 1], pf1, o0, 0, 0, 0);
        o1 = __builtin_amdgcn_mfma_f32_32x32x16_bf16(vtf[1][2 * hs + 0], pf0, o1, 0, 0, 0);
        o1 = __builtin_amdgcn_mfma_f32_32x32x16_bf16(vtf[1][2 * hs + 1], pf1, o1, 0, 0, 0);
      }
    }
  }

  // ---- epilogue: write per-split partials (bf16 o, fp32 l) ----
  float l_tot = l + __shfl_xor(l, 32);
  const size_t prow = ((size_t)(bh * 4 + ks)) * S_ + q0 + m;
  #pragma unroll
  for (int tile = 0; tile < 2; ++tile) {
    const facc16& oo = tile ? o1 : o0;
    #pragma unroll
    for (int rg = 0; rg < 4; ++rg) {
      int d0 = tile * 32 + rg * 8 + h * 4;        // d = (reg&3)+8*(reg>>2)+4h
      ushort4 ob;
      ob.x = f2b(oo[4 * rg + 0]);
      ob.y = f2b(oo[4 * rg + 1]);
      ob.z = f2b(oo[4 * rg + 2]);
      ob.w = f2b(oo[4 * rg + 3]);
      *(ushort4*)(po + prow * 64 + d0) = ob;
    }
  }
  if (lane < 32) pl[prow] = l_tot;
}

// ---------------- combine the 4 key-split partials -> ctxb ----------------
__global__ __launch_bounds__(256) void attn_combine(const unsigned short* __restrict__ po,
                                                    const float* __restrict__ pl,
                                                    unsigned short* __restrict__ ctxb) {
  int t = blockIdx.x * 256 + threadIdx.x;      // 262144 threads
  int row = t >> 3;                            // bh*S + q
  int dg = t & 7;
  int bh = row >> 11, q = row & (S_ - 1);
  int b = bh >> 3, hd = bh & 7;
  float acc[8];
  #pragma unroll
  for (int e = 0; e < 8; ++e) acc[e] = 0.f;
  float ls = 0.f;
  #pragma unroll
  for (int ks = 0; ks < 4; ++ks) {
    size_t prow = (((size_t)(bh * 4 + ks)) << 11) + q;
    ls += pl[prow];
    const unsigned short* src = po + prow * 64 + dg * 8;
    ushort4 v0 = *(const ushort4*)src;
    ushort4 v1 = *(const ushort4*)(src + 4);
    acc[0] += b2f(v0.x); acc[1] += b2f(v0.y); acc[2] += b2f(v0.z); acc[3] += b2f(v0.w);
    acc[4] += b2f(v1.x); acc[5] += b2f(v1.y); acc[6] += b2f(v1.z); acc[7] += b2f(v1.w);
  }
  float inv = 1.f / ls;
  unsigned short ob[8];
  #pragma unroll
  for (int e = 0; e < 8; ++e) ob[e] = f2b(acc[e] * inv);
  *(int4*)(ctxb + ((size_t)(b * S_ + q)) * D_ + hd * DK_ + dg * 8) = *(const int4*)ob;
}

// ---------------- layernorm ----------------
__global__ __launch_bounds__(256) void ln_kernel(const float* __restrict__ X,
                                                 const float* __restrict__ R,
                                                 const float* __restrict__ g,
                                                 const float* __restrict__ be,
                                                 float* __restrict__ OutF,
                                                 unsigned short* __restrict__ OutB) {
  const int lane = threadIdx.x & 63;
  const int wv = threadIdx.x >> 6;
  const int row = blockIdx.x * 4 + wv;
  const float* xp = X + (size_t)row * D_;
  const float* rp = R + (size_t)row * D_;
  float x[8];
  float s = 0.f;
  #pragma unroll
  for (int i = 0; i < 8; ++i) {
    int d = i * 64 + lane;
    x[i] = xp[d] + rp[d];
    s += x[i];
  }
  s += __shfl_xor(s, 32); s += __shfl_xor(s, 16); s += __shfl_xor(s, 8);
  s += __shfl_xor(s, 4);  s += __shfl_xor(s, 2);  s += __shfl_xor(s, 1);
  float mu = s * (1.f / 512.f);
  float vs = 0.f;
  #pragma unroll
  for (int i = 0; i < 8; ++i) { float d = x[i] - mu; vs += d * d; }
  vs += __shfl_xor(vs, 32); vs += __shfl_xor(vs, 16); vs += __shfl_xor(vs, 8);
  vs += __shfl_xor(vs, 4);  vs += __shfl_xor(vs, 2);  vs += __shfl_xor(vs, 1);
  float rstd = rsqrtf(vs * (1.f / 512.f) + 1e-5f);
  #pragma unroll
  for (int i = 0; i < 8; ++i) {
    int d = i * 64 + lane;
    float v = (x[i] - mu) * rstd * g[d] + be[d];
    if (OutF) OutF[(size_t)row * D_ + d] = v;
    if (OutB) OutB[(size_t)row * D_ + d] = f2b(v);
  }
}

// ---------------- classifier head ----------------
__global__ __launch_bounds__(256) void head_kernel(const float* __restrict__ Z,
                                                   const float* __restrict__ hw,
                                                   const float* __restrict__ hb,
                                                   float* __restrict__ out) {
  const int lane = threadIdx.x & 63;
  const int wv = threadIdx.x >> 6;
  const int row = blockIdx.x * 4 + wv;
  const float* zp = Z + (size_t)row * D_;
  float a0 = 0.f, a1 = 0.f;
  #pragma unroll
  for (int i = 0; i < 8; ++i) {
    int d = i * 64 + lane;
    float z = zp[d];
    a0 += z * hw[d * 2];
    a1 += z * hw[d * 2 + 1];
  }
  a0 += __shfl_xor(a0, 32); a0 += __shfl_xor(a0, 16); a0 += __shfl_xor(a0, 8);
  a0 += __shfl_xor(a0, 4);  a0 += __shfl_xor(a0, 2);  a0 += __shfl_xor(a0, 1);
  a1 += __shfl_xor(a1, 32); a1 += __shfl_xor(a1, 16); a1 += __shfl_xor(a1, 8);
  a1 += __shfl_xor(a1, 4);  a1 += __shfl_xor(a1, 2);  a1 += __shfl_xor(a1, 1);
  if (lane == 0) {
    out[row * 2]     = a0 + hb[0];
    out[row * 2 + 1] = a1 + hb[1];
  }
}

extern "C" void kernel_launch(void* const* d_in, const int* in_sizes, int n_in,
                              void* d_out, int out_size, void* d_ws, size_t ws_size,
                              hipStream_t stream) {
  const int*   tokens = (const int*)  d_in[0];
  const float* embed  = (const float*)d_in[1];
  const float* Wqr = (const float*)d_in[2];
  const float* Wqi = (const float*)d_in[3];
  const float* Wkr = (const float*)d_in[4];
  const float* Wki = (const float*)d_in[5];
  const float* Wv  = (const float*)d_in[6];
  const float* Wo  = (const float*)d_in[7];
  const float* bo  = (const float*)d_in[8];
  const float* W1  = (const float*)d_in[9];
  const float* b1  = (const float*)d_in[10];
  const float* W2  = (const float*)d_in[11];
  const float* b2  = (const float*)d_in[12];
  const float* g1  = (const float*)d_in[13];
  const float* be1 = (const float*)d_in[14];
  const float* g2  = (const float*)d_in[15];
  const float* be2 = (const float*)d_in[16];
  const float* hw  = (const float*)d_in[17];
  const float* hb  = (const float*)d_in[18];
  float* out = (float*)d_out;

  char* p = (char*)d_ws;
  float* zr = (float*)p;             p += (size_t)BS_ * D_ * 4;           // 8 MB
  unsigned short* acat = (unsigned short*)p;
  unsigned short* zrb  = acat;       p += (size_t)BS_ * 1024 * 2;         // 8 MB
  unsigned short* Q4   = (unsigned short*)p;
  unsigned short* ffb  = Q4;         p += (size_t)BS_ * NPROJ * 2;        // 20 MB
  unsigned short* VT   = (unsigned short*)p; p += (size_t)B_*H_*DK_*S_*2; // 4 MB
  unsigned short* ctxb = (unsigned short*)p; p += (size_t)BS_ * D_ * 2;   // 4 MB
  float* hbuf = (float*)p;           p += (size_t)BS_ * D_ * 4;           // 8 MB
  float* z1   = (float*)p;           p += (size_t)BS_ * D_ * 4;           // 8 MB  (contiguous after hbuf)
  unsigned short* z1b = (unsigned short*)p;  p += (size_t)BS_ * D_ * 2;   // 4 MB  (contiguous after z1)
  unsigned short* pw_proj0 = (unsigned short*)p; p += (size_t)NPROJ * 1024 * 2; // 5 MB
  unsigned short* pw_proj1 = (unsigned short*)p; p += (size_t)NPROJ * 512 * 2;  // 2.5 MB
  unsigned short* pw_wo = (unsigned short*)p;    p += (size_t)2 * 512 * 512 * 2;   // 1 MB
  unsigned short* pw_w1 = (unsigned short*)p;    p += (size_t)2 * 2048 * 512 * 2;  // 4 MB
  unsigned short* pw_w2 = (unsigned short*)p;    p += (size_t)2 * 512 * 2048 * 2;  // 4 MB
  float* pl = (float*)p;             p += (size_t)16 * 4 * S_ * 4;        // 0.5 MB

  // po bf16 [16 bh][4 ks][2048 q][64 d] = 16.78 MB -> aliases hbuf+z1+start of z1b
  // (all dead during attention; combine reads po before the Wo GEMM rewrites hbuf)
  unsigned short* po = (unsigned short*)hbuf;

  embed_zi_kernel<<<BS_, 128, 0, stream>>>(tokens, embed, zr, acat);
  wcat_all<<<dim3(NPROJ / 64, 16, 2), 256, 0, stream>>>(Wqr, Wqi, Wkr, Wki, Wv,
                                                        pw_proj0, pw_proj1);
  wtr_all<<<dim3(32, 32, 6), 256, 0, stream>>>(Wo, W1, W2, pw_wo, pw_w1, pw_w2);

  for (int l = 0; l < L_; ++l) {
    const int KA = (l == 0) ? 1024 : 512;
    const unsigned short* Aproj = (l == 0) ? acat : zrb;
    const unsigned short* Wproj = (l == 0) ? pw_proj0 : pw_proj1;

    gemm_bf16<128, 128><<<dim3(NPROJ / 128, BS_ / 128), 256, 0, stream>>>(
        Aproj, Wproj, nullptr, nullptr, Q4, BS_, NPROJ, KA, KA, 0);

    vt_kernel<<<dim3(B_ * H_, S_ / 64), 256, 0, stream>>>(Q4, VT);
    attn_mfma<<<dim3(S_ / 256, B_ * H_, 4), 512, 0, stream>>>(Q4, VT, po, pl);
    attn_combine<<<1024, 256, 0, stream>>>(po, pl, ctxb);

    gemm_bf16<64, 64><<<dim3(D_ / 64, BS_ / 64), 256, 0, stream>>>(
        ctxb, pw_wo + (size_t)l * 512 * 512, bo + l * D_, hbuf, nullptr,
        BS_, D_, D_, D_, 0);
    ln_kernel<<<BS_ / 4, 256, 0, stream>>>(zr, hbuf, g1 + l * D_, be1 + l * D_, z1, z1b);

    gemm_bf16<128, 128><<<dim3(DFF_ / 128, BS_ / 128), 256, 0, stream>>>(
        z1b, pw_w1 + (size_t)l * 2048 * 512, b1 + l * DFF_, nullptr, ffb,
        BS_, DFF_, D_, D_, 1);
    gemm_bf16<64, 64><<<dim3(D_ / 64, BS_ / 64), 256, 0, stream>>>(
        ffb, pw_w2 + (size_t)l * 512 * 2048, b2 + l * D_, hbuf, nullptr,
        BS_, D_, DFF_, DFF_, 0);
    ln_kernel<<<BS_ / 4, 256, 0, stream>>>(z1, hbuf, g2 + l * D_, be2 + l * D_, zr, zrb);
  }

  head_kernel<<<BS_ / 4, 256, 0, stream>>>(zr, hw, hb, out);
}

// Round 9
// 495.893 us; speedup vs baseline: 1.1270x; 1.0279x over previous
//
#include <hip/hip_runtime.h>

#define B_   2
#define S_   2048
#define D_   512
#define H_   8
#define DK_  64
#define DFF_ 2048
#define L_   2
#define BS_  (B_*S_)   // 4096
#define NPROJ 2560     // qr|qi|kr|ki|v concatenated

typedef __attribute__((ext_vector_type(8))) short bfrag;    // 8 bf16 (4 VGPRs)
typedef __attribute__((ext_vector_type(4))) float facc;     // 4 fp32
typedef __attribute__((ext_vector_type(16))) float facc16;  // 16 fp32 (32x32 C/D)
typedef __attribute__((ext_vector_type(4))) int i4v;

__device__ __forceinline__ unsigned short f2b(float f) {
  union { float f; unsigned int u; } c; c.f = f;
  unsigned int u = c.u;
  u += 0x7fffu + ((u >> 16) & 1);    // RNE
  return (unsigned short)(u >> 16);
}

__device__ __forceinline__ float b2f(unsigned short u) {
  union { unsigned u; float f; } c; c.u = (unsigned)u << 16; return c.f;
}

__device__ __forceinline__ bfrag asb(i4v x) { union { i4v a; bfrag b; } u; u.a = x; return u.b; }

__device__ __forceinline__ bfrag bneg(bfrag x) {
  union { bfrag b; i4v a; } u; u.b = x;
  u.a.x ^= 0x80008000; u.a.y ^= 0x80008000; u.a.z ^= 0x80008000; u.a.w ^= 0x80008000;
  return u.b;
}

__device__ __forceinline__ void async_copy16(const void* g, void* l) {
  __builtin_amdgcn_global_load_lds((const __attribute__((address_space(1))) void*)g,
                                   (__attribute__((address_space(3))) void*)l,
                                   16, 0, 0);
}

// ---------------- fused embedding gather + positional zi ----------------
__global__ __launch_bounds__(128) void embed_zi_kernel(const int* __restrict__ tokens,
                                                       const float* __restrict__ embed,
                                                       float* __restrict__ zr,
                                                       unsigned short* __restrict__ acat) {
  int row = blockIdx.x;
  int tok = tokens[row];
  float4 v = ((const float4*)(embed + (size_t)tok * D_))[threadIdx.x];
  ((float4*)(zr + (size_t)row * D_))[threadIdx.x] = v;
  ushort4 o; o.x = f2b(v.x); o.y = f2b(v.y); o.z = f2b(v.z); o.w = f2b(v.w);
  *(ushort4*)(acat + (size_t)row * 1024 + threadIdx.x * 4) = o;

  int s = row & (S_ - 1);
  int d0 = threadIdx.x * 4;
  const double LN1E4 = 9.210340371976184;
  #pragma unroll
  for (int t = 0; t < 4; ++t) {
    int d = d0 + t;
    int jj = d >> 1;
    double freq = exp(-((double)jj / 256.0) * LN1E4);
    float val = (float)sin((double)s * freq);
    acat[(size_t)row * 1024 + 512 + d] = f2b(val);
  }
}

// ---------------- batched weight concat+transpose (both layers) ----------------
__global__ __launch_bounds__(256) void wcat_all(const float* __restrict__ Wqr,
                                                const float* __restrict__ Wqi,
                                                const float* __restrict__ Wkr,
                                                const float* __restrict__ Wki,
                                                const float* __restrict__ Wv,
                                                unsigned short* __restrict__ dst0,
                                                unsigned short* __restrict__ dst1) {
  __shared__ float tile[64][68];
  const int l = blockIdx.z;
  const int KA = l ? 512 : 1024;
  const int k0 = blockIdx.y * 64;
  if (k0 >= KA) return;
  unsigned short* dst = l ? dst1 : dst0;
  const size_t woff = (size_t)l * D_ * D_;
  const float* wqr = Wqr + woff;
  const float* wqi = Wqi + woff;
  const float* wkr = Wkr + woff;
  const float* wki = Wki + woff;
  const float* wv  = Wv  + woff;

  const int tid = threadIdx.x;
  const int n0 = blockIdx.x * 64;
  const int p = n0 >> 9, nn0 = n0 & 511;
  const float* src;
  float sign = 1.f;
  bool zero = false;
  if (k0 < 512) {
    const float* tops[5] = {wqr, wqi, wkr, wki, wv};
    src = tops[p];
  } else {
    const float* bots[5] = {wqi, wqr, wki, wkr, nullptr};
    const float sg[5] = {-1.f, 1.f, -1.f, 1.f, 0.f};
    src = bots[p]; sign = sg[p]; zero = (p == 4);
  }
  const int kk0 = k0 & 511;
  #pragma unroll
  for (int i = 0; i < 4; ++i) {
    int lin = tid + i * 256;
    int row = lin >> 4, c4 = (lin & 15) * 4;
    float4 v = make_float4(0.f, 0.f, 0.f, 0.f);
    if (!zero) v = *(const float4*)(src + (size_t)(kk0 + row) * 512 + nn0 + c4);
    *(float4*)&tile[row][c4] = v;
  }
  __syncthreads();
  #pragma unroll
  for (int i = 0; i < 4; ++i) {
    int lin = tid + i * 256;
    int n = lin >> 4, kc4 = (lin & 15) * 4;
    ushort4 o;
    o.x = f2b(sign * tile[kc4 + 0][n]);
    o.y = f2b(sign * tile[kc4 + 1][n]);
    o.z = f2b(sign * tile[kc4 + 2][n]);
    o.w = f2b(sign * tile[kc4 + 3][n]);
    *(ushort4*)(dst + (size_t)(n0 + n) * KA + k0 + kc4) = o;
  }
}

// ---------------- batched weight transpose: wo/w1/w2 x both layers ----------------
__global__ __launch_bounds__(256) void wtr_all(const float* __restrict__ Wo,
                                               const float* __restrict__ W1,
                                               const float* __restrict__ W2,
                                               unsigned short* __restrict__ pwo,
                                               unsigned short* __restrict__ pw1,
                                               unsigned short* __restrict__ pw2) {
  __shared__ float tile[64][68];
  const int j = blockIdx.z, l = j & 1;
  const float* src; unsigned short* dst; int K, N;
  if (j < 2)      { src = Wo + (size_t)l * 512 * 512;  dst = pwo + (size_t)l * 512 * 512;  K = 512;  N = 512; }
  else if (j < 4) { src = W1 + (size_t)l * 512 * 2048; dst = pw1 + (size_t)l * 2048 * 512; K = 512;  N = 2048; }
  else            { src = W2 + (size_t)l * 2048 * 512; dst = pw2 + (size_t)l * 512 * 2048; K = 2048; N = 512; }
  const int n0 = blockIdx.x * 64, k0 = blockIdx.y * 64;
  if (n0 >= N || k0 >= K) return;
  const int tid = threadIdx.x;
  #pragma unroll
  for (int i = 0; i < 4; ++i) {
    int lin = tid + i * 256;
    int row = lin >> 4, c4 = (lin & 15) * 4;
    *(float4*)&tile[row][c4] = *(const float4*)(src + (size_t)(k0 + row) * N + n0 + c4);
  }
  __syncthreads();
  #pragma unroll
  for (int i = 0; i < 4; ++i) {
    int lin = tid + i * 256;
    int n = lin >> 4, kc4 = (lin & 15) * 4;
    ushort4 o;
    o.x = f2b(tile[kc4 + 0][n]);
    o.y = f2b(tile[kc4 + 1][n]);
    o.z = f2b(tile[kc4 + 2][n]);
    o.w = f2b(tile[kc4 + 3][n]);
    *(ushort4*)(dst + (size_t)(n0 + n) * K + k0 + kc4) = o;
  }
}

// ---------------- bf16 MFMA GEMM, v15: 2-phase double-buffered K-loop ----------------
// v14 K-loop was serial per step: {barrier; stage; drain vmcnt(0); barrier;
// compute} -- full stage latency exposed each step, hidden only by block TLP.
// v15 (T3 minimum 2-phase, attn-v8's race-free counted-vmcnt scheme):
//   prologue stage(buf0); per iter: stage(buf^1, k+32) FIRST, then
//   vmcnt(NL) (the NL newest outstanding loads are next-tile's -> current
//   buf complete; each wave verifies its OWN loads) + raw s_barrier, then
//   compute(buf), then barrier (protects buf^1 from overwrite next iter).
//   Next-tile stage latency hides under current compute.
template<int TM, int TN>
__global__ __launch_bounds__(256) void gemm_bf16(const unsigned short* __restrict__ A,
                                                 const unsigned short* __restrict__ Bt,
                                                 const float* __restrict__ bias,
                                                 float* __restrict__ outF,
                                                 unsigned short* __restrict__ outB,
                                                 int M, int N, int K, int lda, int relu) {
  constexpr int MT = TM / 32;
  constexpr int NT = TN / 32;
  constexpr int NL = TM / 64 + TN / 64;   // async copies per thread per stage
  __shared__ short smem[2 * (TM + TN) * 32];

  const int tid = threadIdx.x;
  const int w = tid >> 6, lane = tid & 63;
  const int col = lane & 15, quad = lane >> 4;
  const int m0 = blockIdx.y * TM, n0 = blockIdx.x * TN;
  const int wrow = (w >> 1) * (TM / 2);
  const int wcol = (w & 1) * (TN / 2);

  const int srow = lane >> 2;
  const int skk  = (lane & 3) * 8;

  facc acc[MT][NT];
  #pragma unroll
  for (int i = 0; i < MT; ++i)
    #pragma unroll
    for (int j = 0; j < NT; ++j) acc[i][j] = (facc){0.f, 0.f, 0.f, 0.f};

  auto stage = [&](int k0, int buf) {
    short* A_s = smem + buf * (TM + TN) * 32;
    short* B_s = A_s + TM * 32;
    #pragma unroll
    for (int rd = 0; rd < TM / 64; ++rd) {
      int row = rd * 64 + w * 16 + srow;
      async_copy16(A + (size_t)(m0 + row) * lda + k0 + skk, &A_s[row * 32 + skk]);
    }
    #pragma unroll
    for (int rd = 0; rd < TN / 64; ++rd) {
      int row = rd * 64 + w * 16 + srow;
      async_copy16(Bt + (size_t)(n0 + row) * K + k0 + skk, &B_s[row * 32 + skk]);
    }
  };

  stage(0, 0);
  int cur = 0;
  for (int k0 = 0; k0 < K; k0 += 32) {
    const bool has_next = (k0 + 32 < K);
    if (has_next) stage(k0 + 32, cur ^ 1);
    // newest NL outstanding loads belong to next tile -> vmcnt(NL) ensures
    // the CURRENT buffer's loads (older) have landed.  Last iter: drain.
    if (has_next) {
      if constexpr (NL == 4) asm volatile("s_waitcnt vmcnt(4)" ::: "memory");
      else                   asm volatile("s_waitcnt vmcnt(2)" ::: "memory");
    } else {
      asm volatile("s_waitcnt vmcnt(0)" ::: "memory");
    }
    __builtin_amdgcn_s_barrier();
    asm volatile("" ::: "memory");

    const short* A_s = smem + cur * (TM + TN) * 32;
    const short* B_s = A_s + TM * 32;

    bfrag af[MT], bf[NT];
    #pragma unroll
    for (int i = 0; i < MT; ++i)
      af[i] = *(const bfrag*)&A_s[(wrow + i * 16 + col) * 32 + quad * 8];
    #pragma unroll
    for (int j = 0; j < NT; ++j)
      bf[j] = *(const bfrag*)&B_s[(wcol + j * 16 + col) * 32 + quad * 8];
    #pragma unroll
    for (int i = 0; i < MT; ++i)
      #pragma unroll
      for (int j = 0; j < NT; ++j)
        acc[i][j] = __builtin_amdgcn_mfma_f32_16x16x32_bf16(af[i], bf[j], acc[i][j], 0, 0, 0);

    // all waves done reading cur before next iter's stage overwrites buf^1
    // (which is cur at iter t+1... rotation: next iter stages into cur, so
    // this barrier protects THIS buf's readers from next iter's stage).
    __builtin_amdgcn_s_barrier();
    asm volatile("" ::: "memory");
    cur ^= 1;
  }

  #pragma unroll
  for (int i = 0; i < MT; ++i) {
    #pragma unroll
    for (int j = 0; j < NT; ++j) {
      int colIdx = n0 + wcol + j * 16 + col;
      float b = bias ? bias[colIdx] : 0.f;
      #pragma unroll
      for (int r = 0; r < 4; ++r) {
        int rowIdx = m0 + wrow + i * 16 + quad * 4 + r;
        float v = acc[i][j][r] + b;
        if (relu) v = fmaxf(v, 0.f);
        if (outF) outF[(size_t)rowIdx * N + colIdx] = v;
        if (outB) outB[(size_t)rowIdx * N + colIdx] = f2b(v);
      }
    }
  }
}

// ---------------- V transpose: Q4 cols [2048,2560) -> bf16 [b,h,dk,s] ----------------
__global__ __launch_bounds__(256) void vt_kernel(const unsigned short* __restrict__ Q4,
                                                 unsigned short* __restrict__ vt) {
  __shared__ short tile[64][80];
  const int bh = blockIdx.x;
  const int b = bh >> 3, hd = bh & 7;
  const int s0 = blockIdx.y * 64;
  const int tid = threadIdx.x;
  #pragma unroll
  for (int i = 0; i < 2; ++i) {
    int lin = tid + i * 256;
    int row = lin >> 3;
    int c8 = (lin & 7) * 8;
    *(int4*)&tile[row][c8] =
      *(const int4*)(Q4 + (size_t)(b * S_ + s0 + row) * NPROJ + 2048 + hd * DK_ + c8);
  }
  __syncthreads();
  #pragma unroll
  for (int i = 0; i < 2; ++i) {
    int lin = tid + i * 256;
    int d = lin >> 3;
    int s8 = (lin & 7) * 8;
    short tmp[8];
    #pragma unroll
    for (int t = 0; t < 8; ++t) tmp[t] = tile[s8 + t][d];
    *(int4*)(vt + ((size_t)bh * DK_ + d) * S_ + s0 + s8) = *(const int4*)tmp;
  }
}

// ---------------- MFMA complex-hybrid attention (v11 config, measured best) ----------------
__global__ __launch_bounds__(512, 2) void attn_mfma(const unsigned short* __restrict__ Q4,
                                                    const unsigned short* __restrict__ VT,
                                                    unsigned short* __restrict__ po,
                                                    float* __restrict__ pl) {
  __shared__ __align__(16) short smem[32768];   // 64KB: kr[256][128B] | ki[256][128B]

  const int bh = blockIdx.y;
  const int b = bh >> 3, hd = bh & 7;
  const int hoff = hd * DK_;
  const int ks = blockIdx.z;
  const int tid = threadIdx.x;
  const int w = tid >> 6;
  const int lane = tid & 63;
  const int m = lane & 31;       // C col = q index / A m index
  const int h = lane >> 5;       // half-wave
  const int x7 = m & 7;
  const int q0 = blockIdx.x * 256 + w * 32;
  const int kb = ks * 512;

  const size_t bS = (size_t)b * S_;
  const size_t vtbase = (size_t)bh * DK_ * S_;

  // staging indices: 512 threads, 8 segs/key row; swizzle on SOURCE, linear dest
  const int skey = tid >> 3, sseg = tid & 7;
  const int sls = sseg ^ (skey & 7);            // XOR bank swizzle (K rows = 128B)

  // Q B-frags (persistent): B[kdim = t*16 + h*8 + j][n=q=m]
  bfrag qrf[4], qif[4], nqrf[4];
  {
    const size_t qrow = (bS + q0 + m) * (size_t)NPROJ + hoff;
    #pragma unroll
    for (int t = 0; t < 4; ++t) {
      qrf[t] = *(const bfrag*)(Q4 + qrow + t * 16 + h * 8);
      qif[t] = *(const bfrag*)(Q4 + qrow + 512 + t * 16 + h * 8);
      nqrf[t] = bneg(qrf[t]);
    }
  }

  facc16 o0 = {}, o1 = {};
  float l = 0.f;
  const float c1 = 0.015625f;   // 1/64
  const float c2 = 0.0375f;     // 0.3/8

  // V base pointers (per d-tile): row = tile*32 + m
  const unsigned short* vb0 = VT + vtbase + (size_t)m * S_ + kb + h * 8;
  const unsigned short* vb1 = vb0 + (size_t)32 * S_;

  char* kr_sb = (char*)smem;            // kr: 32KB
  char* ki_sb = (char*)smem + 32768;    // ki: 32KB

  for (int ph = 0; ph < 2; ++ph) {
    // all waves finished reading the previous phase's LDS (ds_reads complete
    // before their consuming MFMAs, which precede this barrier)
    __builtin_amdgcn_s_barrier();
    // stage 256 keys: 4 rounds x 64 keys, kr+ki, coalesced 16B, linear dest
    #pragma unroll
    for (int r = 0; r < 4; ++r) {
      const unsigned short* gk = Q4 + (bS + kb + ph * 256 + r * 64 + skey) * (size_t)NPROJ
                               + 1024 + hoff + sls * 8;
      async_copy16(gk,       kr_sb + r * 8192 + tid * 16);
      async_copy16(gk + 512, ki_sb + r * 8192 + tid * 16);
    }
    asm volatile("s_waitcnt vmcnt(0)" ::: "memory");
    __builtin_amdgcn_s_barrier();
    asm volatile("" ::: "memory");

    for (int c = 0; c < 4; ++c) {      // 64-key chunk, NO sync inside phase
      // ---- V frags direct from global ----
      bfrag vtf[2][4];
      #pragma unroll
      for (int kt = 0; kt < 4; ++kt) {
        vtf[0][kt] = *(const bfrag*)(vb0 + kt * 16);
        vtf[1][kt] = *(const bfrag*)(vb1 + kt * 16);
      }
      vb0 += 64; vb1 += 64;

      // ---- K frags both halves from LDS: row = c*64 + hs*32 + m ----
      bfrag kr0[4], ki0[4], kr1[4], ki1[4];
      #pragma unroll
      for (int t = 0; t < 4; ++t) {
        int off0 = (c * 64 + m) * 128 + (((2 * t + h) ^ x7) << 4);
        int off1 = (c * 64 + 32 + m) * 128 + (((2 * t + h) ^ x7) << 4);
        kr0[t] = *(const bfrag*)(kr_sb + off0);
        ki0[t] = *(const bfrag*)(ki_sb + off0);
        kr1[t] = *(const bfrag*)(kr_sb + off1);
        ki1[t] = *(const bfrag*)(ki_sb + off1);
      }

      // ---- QK both halves ----
      facc16 sr0 = {}, si0 = {}, sr1 = {}, si1 = {};
      #pragma unroll
      for (int t = 0; t < 4; ++t) {
        sr0 = __builtin_amdgcn_mfma_f32_32x32x16_bf16(kr0[t], qrf[t], sr0, 0, 0, 0);
        si0 = __builtin_amdgcn_mfma_f32_32x32x16_bf16(kr0[t], qif[t], si0, 0, 0, 0);
        sr0 = __builtin_amdgcn_mfma_f32_32x32x16_bf16(ki0[t], qif[t], sr0, 0, 0, 0);
        si0 = __builtin_amdgcn_mfma_f32_32x32x16_bf16(ki0[t], nqrf[t], si0, 0, 0, 0);
      }
      #pragma unroll
      for (int t = 0; t < 4; ++t) {
        sr1 = __builtin_amdgcn_mfma_f32_32x32x16_bf16(kr1[t], qrf[t], sr1, 0, 0, 0);
        si1 = __builtin_amdgcn_mfma_f32_32x32x16_bf16(kr1[t], qif[t], si1, 0, 0, 0);
        sr1 = __builtin_amdgcn_mfma_f32_32x32x16_bf16(ki1[t], qif[t], sr1, 0, 0, 0);
        si1 = __builtin_amdgcn_mfma_f32_32x32x16_bf16(ki1[t], nqrf[t], si1, 0, 0, 0);
      }

      #pragma unroll
      for (int hs = 0; hs < 2; ++hs) {
        const facc16& sr = hs ? sr1 : sr0;
        const facc16& si = hs ? si1 : si0;

        // ---- hybrid score -> p = exp(x) ~ 1 + x + x^2/2 (|x| <~ 0.2) ----
        float p[16], ssum = 0.f;
        #pragma unroll
        for (int i = 0; i < 16; ++i) {
          float a = sr[i], bb = si[i];
          float d2 = __builtin_fmaf(a, a, __builtin_fmaf(bb, bb, 1e-30f));
          float rs = rsqrtf(d2);
          float x = rs * __builtin_fmaf(c1, d2, c2 * a);
          p[i] = __builtin_fmaf(x, __builtin_fmaf(0.5f, x, 1.f), 1.f);
          ssum += p[i];
        }
        l += ssum;

        // ---- pack P (cvt_pk RNE) + permlane32_swap cross-half exchange ----
        unsigned dw[8];
        #pragma unroll
        for (int i = 0; i < 8; ++i)
          asm("v_cvt_pk_bf16_f32 %0, %1, %2" : "=v"(dw[i]) : "v"(p[2 * i]), "v"(p[2 * i + 1]));
        unsigned s0a = dw[0], s0b = dw[2];
        unsigned s1a = dw[1], s1b = dw[3];
        unsigned s2a = dw[4], s2b = dw[6];
        unsigned s3a = dw[5], s3b = dw[7];
        asm("v_permlane32_swap_b32 %0, %1" : "+v"(s0a), "+v"(s0b));
        asm("v_permlane32_swap_b32 %0, %1" : "+v"(s1a), "+v"(s1b));
        asm("v_permlane32_swap_b32 %0, %1" : "+v"(s2a), "+v"(s2b));
        asm("v_permlane32_swap_b32 %0, %1" : "+v"(s3a), "+v"(s3b));
        i4v f0 = { (int)s0a, (int)s1a, (int)s0b, (int)s1b };
        i4v f1 = { (int)s2a, (int)s3a, (int)s2b, (int)s3b };
        bfrag pf0 = asb(f0), pf1 = asb(f1);

        // ---- PV: o^T[d][q] += V^T x P^T (k-slots 2*hs, 2*hs+1) ----
        o0 = __builtin_amdgcn_mfma_f32_32x32x16_bf16(vtf[0][2 * hs + 0], pf0, o0, 0, 0, 0);
        o0 = __builtin_amdgcn_mfma_f32_32x32x16_bf16(vtf[0][2 * hs + 1], pf1, o0, 0, 0, 0);
        o1 = __builtin_amdgcn_mfma_f32_32x32x16_bf16(vtf[1][2 * hs + 0], pf0, o1, 0, 0, 0);
        o1 = __builtin_amdgcn_mfma_f32_32x32x16_bf16(vtf[1][2 * hs + 1], pf1, o1, 0, 0, 0);
      }
    }
  }

  // ---- epilogue: write per-split partials (bf16 o, fp32 l) ----
  float l_tot = l + __shfl_xor(l, 32);
  const size_t prow = ((size_t)(bh * 4 + ks)) * S_ + q0 + m;
  #pragma unroll
  for (int tile = 0; tile < 2; ++tile) {
    const facc16& oo = tile ? o1 : o0;
    #pragma unroll
    for (int rg = 0; rg < 4; ++rg) {
      int d0 = tile * 32 + rg * 8 + h * 4;        // d = (reg&3)+8*(reg>>2)+4h
      ushort4 ob;
      ob.x = f2b(oo[4 * rg + 0]);
      ob.y = f2b(oo[4 * rg + 1]);
      ob.z = f2b(oo[4 * rg + 2]);
      ob.w = f2b(oo[4 * rg + 3]);
      *(ushort4*)(po + prow * 64 + d0) = ob;
    }
  }
  if (lane < 32) pl[prow] = l_tot;
}

// ---------------- combine the 4 key-split partials -> ctxb ----------------
__global__ __launch_bounds__(256) void attn_combine(const unsigned short* __restrict__ po,
                                                    const float* __restrict__ pl,
                                                    unsigned short* __restrict__ ctxb) {
  int t = blockIdx.x * 256 + threadIdx.x;      // 262144 threads
  int row = t >> 3;                            // bh*S + q
  int dg = t & 7;
  int bh = row >> 11, q = row & (S_ - 1);
  int b = bh >> 3, hd = bh & 7;
  float acc[8];
  #pragma unroll
  for (int e = 0; e < 8; ++e) acc[e] = 0.f;
  float ls = 0.f;
  #pragma unroll
  for (int ks = 0; ks < 4; ++ks) {
    size_t prow = (((size_t)(bh * 4 + ks)) << 11) + q;
    ls += pl[prow];
    const unsigned short* src = po + prow * 64 + dg * 8;
    ushort4 v0 = *(const ushort4*)src;
    ushort4 v1 = *(const ushort4*)(src + 4);
    acc[0] += b2f(v0.x); acc[1] += b2f(v0.y); acc[2] += b2f(v0.z); acc[3] += b2f(v0.w);
    acc[4] += b2f(v1.x); acc[5] += b2f(v1.y); acc[6] += b2f(v1.z); acc[7] += b2f(v1.w);
  }
  float inv = 1.f / ls;
  unsigned short ob[8];
  #pragma unroll
  for (int e = 0; e < 8; ++e) ob[e] = f2b(acc[e] * inv);
  *(int4*)(ctxb + ((size_t)(b * S_ + q)) * D_ + hd * DK_ + dg * 8) = *(const int4*)ob;
}

// ---------------- layernorm ----------------
__global__ __launch_bounds__(256) void ln_kernel(const float* __restrict__ X,
                                                 const float* __restrict__ R,
                                                 const float* __restrict__ g,
                                                 const float* __restrict__ be,
                                                 float* __restrict__ OutF,
                                                 unsigned short* __restrict__ OutB) {
  const int lane = threadIdx.x & 63;
  const int wv = threadIdx.x >> 6;
  const int row = blockIdx.x * 4 + wv;
  const float* xp = X + (size_t)row * D_;
  const float* rp = R + (size_t)row * D_;
  float x[8];
  float s = 0.f;
  #pragma unroll
  for (int i = 0; i < 8; ++i) {
    int d = i * 64 + lane;
    x[i] = xp[d] + rp[d];
    s += x[i];
  }
  s += __shfl_xor(s, 32); s += __shfl_xor(s, 16); s += __shfl_xor(s, 8);
  s += __shfl_xor(s, 4);  s += __shfl_xor(s, 2);  s += __shfl_xor(s, 1);
  float mu = s * (1.f / 512.f);
  float vs = 0.f;
  #pragma unroll
  for (int i = 0; i < 8; ++i) { float d = x[i] - mu; vs += d * d; }
  vs += __shfl_xor(vs, 32); vs += __shfl_xor(vs, 16); vs += __shfl_xor(vs, 8);
  vs += __shfl_xor(vs, 4);  vs += __shfl_xor(vs, 2);  vs += __shfl_xor(vs, 1);
  float rstd = rsqrtf(vs * (1.f / 512.f) + 1e-5f);
  #pragma unroll
  for (int i = 0; i < 8; ++i) {
    int d = i * 64 + lane;
    float v = (x[i] - mu) * rstd * g[d] + be[d];
    if (OutF) OutF[(size_t)row * D_ + d] = v;
    if (OutB) OutB[(size_t)row * D_ + d] = f2b(v);
  }
}

// ---------------- classifier head ----------------
__global__ __launch_bounds__(256) void head_kernel(const float* __restrict__ Z,
                                                   const float* __restrict__ hw,
                                                   const float* __restrict__ hb,
                                                   float* __restrict__ out) {
  const int lane = threadIdx.x & 63;
  const int wv = threadIdx.x >> 6;
  const int row = blockIdx.x * 4 + wv;
  const float* zp = Z + (size_t)row * D_;
  float a0 = 0.f, a1 = 0.f;
  #pragma unroll
  for (int i = 0; i < 8; ++i) {
    int d = i * 64 + lane;
    float z = zp[d];
    a0 += z * hw[d * 2];
    a1 += z * hw[d * 2 + 1];
  }
  a0 += __shfl_xor(a0, 32); a0 += __shfl_xor(a0, 16); a0 += __shfl_xor(a0, 8);
  a0 += __shfl_xor(a0, 4);  a0 += __shfl_xor(a0, 2);  a0 += __shfl_xor(a0, 1);
  a1 += __shfl_xor(a1, 32); a1 += __shfl_xor(a1, 16); a1 += __shfl_xor(a1, 8);
  a1 += __shfl_xor(a1, 4);  a1 += __shfl_xor(a1, 2);  a1 += __shfl_xor(a1, 1);
  if (lane == 0) {
    out[row * 2]     = a0 + hb[0];
    out[row * 2 + 1] = a1 + hb[1];
  }
}

extern "C" void kernel_launch(void* const* d_in, const int* in_sizes, int n_in,
                              void* d_out, int out_size, void* d_ws, size_t ws_size,
                              hipStream_t stream) {
  const int*   tokens = (const int*)  d_in[0];
  const float* embed  = (const float*)d_in[1];
  const float* Wqr = (const float*)d_in[2];
  const float* Wqi = (const float*)d_in[3];
  const float* Wkr = (const float*)d_in[4];
  const float* Wki = (const float*)d_in[5];
  const float* Wv  = (const float*)d_in[6];
  const float* Wo  = (const float*)d_in[7];
  const float* bo  = (const float*)d_in[8];
  const float* W1  = (const float*)d_in[9];
  const float* b1  = (const float*)d_in[10];
  const float* W2  = (const float*)d_in[11];
  const float* b2  = (const float*)d_in[12];
  const float* g1  = (const float*)d_in[13];
  const float* be1 = (const float*)d_in[14];
  const float* g2  = (const float*)d_in[15];
  const float* be2 = (const float*)d_in[16];
  const float* hw  = (const float*)d_in[17];
  const float* hb  = (const float*)d_in[18];
  float* out = (float*)d_out;

  char* p = (char*)d_ws;
  float* zr = (float*)p;             p += (size_t)BS_ * D_ * 4;           // 8 MB
  unsigned short* acat = (unsigned short*)p;
  unsigned short* zrb  = acat;       p += (size_t)BS_ * 1024 * 2;         // 8 MB
  unsigned short* Q4   = (unsigned short*)p;
  unsigned short* ffb  = Q4;         p += (size_t)BS_ * NPROJ * 2;        // 20 MB
  unsigned short* VT   = (unsigned short*)p; p += (size_t)B_*H_*DK_*S_*2; // 4 MB
  unsigned short* ctxb = (unsigned short*)p; p += (size_t)BS_ * D_ * 2;   // 4 MB
  float* hbuf = (float*)p;           p += (size_t)BS_ * D_ * 4;           // 8 MB
  float* z1   = (float*)p;           p += (size_t)BS_ * D_ * 4;           // 8 MB  (contiguous after hbuf)
  unsigned short* z1b = (unsigned short*)p;  p += (size_t)BS_ * D_ * 2;   // 4 MB  (contiguous after z1)
  unsigned short* pw_proj0 = (unsigned short*)p; p += (size_t)NPROJ * 1024 * 2; // 5 MB
  unsigned short* pw_proj1 = (unsigned short*)p; p += (size_t)NPROJ * 512 * 2;  // 2.5 MB
  unsigned short* pw_wo = (unsigned short*)p;    p += (size_t)2 * 512 * 512 * 2;   // 1 MB
  unsigned short* pw_w1 = (unsigned short*)p;    p += (size_t)2 * 2048 * 512 * 2;  // 4 MB
  unsigned short* pw_w2 = (unsigned short*)p;    p += (size_t)2 * 512 * 2048 * 2;  // 4 MB
  float* pl = (float*)p;             p += (size_t)16 * 4 * S_ * 4;        // 0.5 MB

  // po bf16 [16 bh][4 ks][2048 q][64 d] = 16.78 MB -> aliases hbuf+z1+start of z1b
  // (all dead during attention; combine reads po before the Wo GEMM rewrites hbuf)
  unsigned short* po = (unsigned short*)hbuf;

  embed_zi_kernel<<<BS_, 128, 0, stream>>>(tokens, embed, zr, acat);
  wcat_all<<<dim3(NPROJ / 64, 16, 2), 256, 0, stream>>>(Wqr, Wqi, Wkr, Wki, Wv,
                                                        pw_proj0, pw_proj1);
  wtr_all<<<dim3(32, 32, 6), 256, 0, stream>>>(Wo, W1, W2, pw_wo, pw_w1, pw_w2);

  for (int l = 0; l < L_; ++l) {
    const int KA = (l == 0) ? 1024 : 512;
    const unsigned short* Aproj = (l == 0) ? acat : zrb;
    const unsigned short* Wproj = (l == 0) ? pw_proj0 : pw_proj1;

    gemm_bf16<128, 128><<<dim3(NPROJ / 128, BS_ / 128), 256, 0, stream>>>(
        Aproj, Wproj, nullptr, nullptr, Q4, BS_, NPROJ, KA, KA, 0);

    vt_kernel<<<dim3(B_ * H_, S_ / 64), 256, 0, stream>>>(Q4, VT);
    attn_mfma<<<dim3(S_ / 256, B_ * H_, 4), 512, 0, stream>>>(Q4, VT, po, pl);
    attn_combine<<<1024, 256, 0, stream>>>(po, pl, ctxb);

    gemm_bf16<64, 64><<<dim3(D_ / 64, BS_ / 64), 256, 0, stream>>>(
        ctxb, pw_wo + (size_t)l * 512 * 512, bo + l * D_, hbuf, nullptr,
        BS_, D_, D_, D_, 0);
    ln_kernel<<<BS_ / 4, 256, 0, stream>>>(zr, hbuf, g1 + l * D_, be1 + l * D_, z1, z1b);

    gemm_bf16<128, 128><<<dim3(DFF_ / 128, BS_ / 128), 256, 0, stream>>>(
        z1b, pw_w1 + (size_t)l * 2048 * 512, b1 + l * DFF_, nullptr, ffb,
        BS_, DFF_, D_, D_, 1);
    gemm_bf16<64, 64><<<dim3(D_ / 64, BS_ / 64), 256, 0, stream>>>(
        ffb, pw_w2 + (size_t)l * 512 * 2048, b2 + l * D_, hbuf, nullptr,
        BS_, D_, DFF_, DFF_, 0);
    ln_kernel<<<BS_ / 4, 256, 0, stream>>>(z1, hbuf, g2 + l * D_, be2 + l * D_, zr, zrb);
  }

  head_kernel<<<BS_ / 4, 256, 0, stream>>>(zr, hw, hb, out);
}

// Round 10
// 494.566 us; speedup vs baseline: 1.1300x; 1.0027x over previous
//
#include <hip/hip_runtime.h>

#define B_   2
#define S_   2048
#define D_   512
#define H_   8
#define DK_  64
#define DFF_ 2048
#define L_   2
#define BS_  (B_*S_)   // 4096
#define NPROJ 2560     // qr|qi|kr|ki|v concatenated

typedef __attribute__((ext_vector_type(8))) short bfrag;    // 8 bf16 (4 VGPRs)
typedef __attribute__((ext_vector_type(4))) float facc;     // 4 fp32
typedef __attribute__((ext_vector_type(16))) float facc16;  // 16 fp32 (32x32 C/D)
typedef __attribute__((ext_vector_type(4))) int i4v;

__device__ __forceinline__ unsigned short f2b(float f) {
  union { float f; unsigned int u; } c; c.f = f;
  unsigned int u = c.u;
  u += 0x7fffu + ((u >> 16) & 1);    // RNE
  return (unsigned short)(u >> 16);
}

__device__ __forceinline__ float b2f(unsigned short u) {
  union { unsigned u; float f; } c; c.u = (unsigned)u << 16; return c.f;
}

__device__ __forceinline__ bfrag asb(i4v x) { union { i4v a; bfrag b; } u; u.a = x; return u.b; }

__device__ __forceinline__ bfrag bneg(bfrag x) {
  union { bfrag b; i4v a; } u; u.b = x;
  u.a.x ^= 0x80008000; u.a.y ^= 0x80008000; u.a.z ^= 0x80008000; u.a.w ^= 0x80008000;
  return u.b;
}

__device__ __forceinline__ void async_copy16(const void* g, void* l) {
  __builtin_amdgcn_global_load_lds((const __attribute__((address_space(1))) void*)g,
                                   (__attribute__((address_space(3))) void*)l,
                                   16, 0, 0);
}

// ---------------- fused embedding gather + positional zi ----------------
__global__ __launch_bounds__(128) void embed_zi_kernel(const int* __restrict__ tokens,
                                                       const float* __restrict__ embed,
                                                       float* __restrict__ zr,
                                                       unsigned short* __restrict__ acat) {
  int row = blockIdx.x;
  int tok = tokens[row];
  float4 v = ((const float4*)(embed + (size_t)tok * D_))[threadIdx.x];
  ((float4*)(zr + (size_t)row * D_))[threadIdx.x] = v;
  ushort4 o; o.x = f2b(v.x); o.y = f2b(v.y); o.z = f2b(v.z); o.w = f2b(v.w);
  *(ushort4*)(acat + (size_t)row * 1024 + threadIdx.x * 4) = o;

  int s = row & (S_ - 1);
  int d0 = threadIdx.x * 4;
  const double LN1E4 = 9.210340371976184;
  #pragma unroll
  for (int t = 0; t < 4; ++t) {
    int d = d0 + t;
    int jj = d >> 1;
    double freq = exp(-((double)jj / 256.0) * LN1E4);
    float val = (float)sin((double)s * freq);
    acat[(size_t)row * 1024 + 512 + d] = f2b(val);
  }
}

// ---------------- batched weight concat+transpose (both layers) ----------------
__global__ __launch_bounds__(256) void wcat_all(const float* __restrict__ Wqr,
                                                const float* __restrict__ Wqi,
                                                const float* __restrict__ Wkr,
                                                const float* __restrict__ Wki,
                                                const float* __restrict__ Wv,
                                                unsigned short* __restrict__ dst0,
                                                unsigned short* __restrict__ dst1) {
  __shared__ float tile[64][68];
  const int l = blockIdx.z;
  const int KA = l ? 512 : 1024;
  const int k0 = blockIdx.y * 64;
  if (k0 >= KA) return;
  unsigned short* dst = l ? dst1 : dst0;
  const size_t woff = (size_t)l * D_ * D_;
  const float* wqr = Wqr + woff;
  const float* wqi = Wqi + woff;
  const float* wkr = Wkr + woff;
  const float* wki = Wki + woff;
  const float* wv  = Wv  + woff;

  const int tid = threadIdx.x;
  const int n0 = blockIdx.x * 64;
  const int p = n0 >> 9, nn0 = n0 & 511;
  const float* src;
  float sign = 1.f;
  bool zero = false;
  if (k0 < 512) {
    const float* tops[5] = {wqr, wqi, wkr, wki, wv};
    src = tops[p];
  } else {
    const float* bots[5] = {wqi, wqr, wki, wkr, nullptr};
    const float sg[5] = {-1.f, 1.f, -1.f, 1.f, 0.f};
    src = bots[p]; sign = sg[p]; zero = (p == 4);
  }
  const int kk0 = k0 & 511;
  #pragma unroll
  for (int i = 0; i < 4; ++i) {
    int lin = tid + i * 256;
    int row = lin >> 4, c4 = (lin & 15) * 4;
    float4 v = make_float4(0.f, 0.f, 0.f, 0.f);
    if (!zero) v = *(const float4*)(src + (size_t)(kk0 + row) * 512 + nn0 + c4);
    *(float4*)&tile[row][c4] = v;
  }
  __syncthreads();
  #pragma unroll
  for (int i = 0; i < 4; ++i) {
    int lin = tid + i * 256;
    int n = lin >> 4, kc4 = (lin & 15) * 4;
    ushort4 o;
    o.x = f2b(sign * tile[kc4 + 0][n]);
    o.y = f2b(sign * tile[kc4 + 1][n]);
    o.z = f2b(sign * tile[kc4 + 2][n]);
    o.w = f2b(sign * tile[kc4 + 3][n]);
    *(ushort4*)(dst + (size_t)(n0 + n) * KA + k0 + kc4) = o;
  }
}

// ---------------- batched weight transpose: wo/w1/w2 x both layers ----------------
__global__ __launch_bounds__(256) void wtr_all(const float* __restrict__ Wo,
                                               const float* __restrict__ W1,
                                               const float* __restrict__ W2,
                                               unsigned short* __restrict__ pwo,
                                               unsigned short* __restrict__ pw1,
                                               unsigned short* __restrict__ pw2) {
  __shared__ float tile[64][68];
  const int j = blockIdx.z, l = j & 1;
  const float* src; unsigned short* dst; int K, N;
  if (j < 2)      { src = Wo + (size_t)l * 512 * 512;  dst = pwo + (size_t)l * 512 * 512;  K = 512;  N = 512; }
  else if (j < 4) { src = W1 + (size_t)l * 512 * 2048; dst = pw1 + (size_t)l * 2048 * 512; K = 512;  N = 2048; }
  else            { src = W2 + (size_t)l * 2048 * 512; dst = pw2 + (size_t)l * 512 * 2048; K = 2048; N = 512; }
  const int n0 = blockIdx.x * 64, k0 = blockIdx.y * 64;
  if (n0 >= N || k0 >= K) return;
  const int tid = threadIdx.x;
  #pragma unroll
  for (int i = 0; i < 4; ++i) {
    int lin = tid + i * 256;
    int row = lin >> 4, c4 = (lin & 15) * 4;
    *(float4*)&tile[row][c4] = *(const float4*)(src + (size_t)(k0 + row) * N + n0 + c4);
  }
  __syncthreads();
  #pragma unroll
  for (int i = 0; i < 4; ++i) {
    int lin = tid + i * 256;
    int n = lin >> 4, kc4 = (lin & 15) * 4;
    ushort4 o;
    o.x = f2b(tile[kc4 + 0][n]);
    o.y = f2b(tile[kc4 + 1][n]);
    o.z = f2b(tile[kc4 + 2][n]);
    o.w = f2b(tile[kc4 + 3][n]);
    *(ushort4*)(dst + (size_t)(n0 + n) * K + k0 + kc4) = o;
  }
}

// ---------------- bf16 MFMA GEMM, v16: depth-2 (3-buffer) pipelined K-loop ----------------
// v15 (depth-1, 2-buffer) recovered 14us -> counted-vmcnt transfers to these
// small-K shapes.  But depth-1 hides the stage latency (~400-900cy) under ONE
// compute phase -- for <64,64> that's only ~130cy of MFMA issue.  v16: stage
// 2 tiles ahead, 3 buffers (tile t -> buf t%3), wait vmcnt(fut*NL) where
// fut = #future tiles in flight (2 steady, 1/0 at tail).  The end-of-iter
// barrier already guarantees buffer-overwrite safety (buf reused at t+1 was
// fully read at t).  LDS 48KB (128x128) / 24KB (64x64) -- occupancy unchanged.
template<int TM, int TN>
__global__ __launch_bounds__(256) void gemm_bf16(const unsigned short* __restrict__ A,
                                                 const unsigned short* __restrict__ Bt,
                                                 const float* __restrict__ bias,
                                                 float* __restrict__ outF,
                                                 unsigned short* __restrict__ outB,
                                                 int M, int N, int K, int lda, int relu) {
  constexpr int MT = TM / 32;
  constexpr int NT = TN / 32;
  constexpr int NL = TM / 64 + TN / 64;   // async copies per thread per stage
  __shared__ short smem[3 * (TM + TN) * 32];

  const int tid = threadIdx.x;
  const int w = tid >> 6, lane = tid & 63;
  const int col = lane & 15, quad = lane >> 4;
  const int m0 = blockIdx.y * TM, n0 = blockIdx.x * TN;
  const int wrow = (w >> 1) * (TM / 2);
  const int wcol = (w & 1) * (TN / 2);

  const int srow = lane >> 2;
  const int skk  = (lane & 3) * 8;

  facc acc[MT][NT];
  #pragma unroll
  for (int i = 0; i < MT; ++i)
    #pragma unroll
    for (int j = 0; j < NT; ++j) acc[i][j] = (facc){0.f, 0.f, 0.f, 0.f};

  auto stage = [&](int k0, int buf) {
    short* A_s = smem + buf * (TM + TN) * 32;
    short* B_s = A_s + TM * 32;
    #pragma unroll
    for (int rd = 0; rd < TM / 64; ++rd) {
      int row = rd * 64 + w * 16 + srow;
      async_copy16(A + (size_t)(m0 + row) * lda + k0 + skk, &A_s[row * 32 + skk]);
    }
    #pragma unroll
    for (int rd = 0; rd < TN / 64; ++rd) {
      int row = rd * 64 + w * 16 + srow;
      async_copy16(Bt + (size_t)(n0 + row) * K + k0 + skk, &B_s[row * 32 + skk]);
    }
  };

  const int nT = K >> 5;                 // K/32 tiles
  stage(0, 0);
  if (nT > 1) stage(32, 1);

  int cur = 0;                           // buffer of tile t (t%3)
  for (int t = 0; t < nT; ++t) {
    if (t + 2 < nT) {
      int nb = cur + 2; if (nb >= 3) nb -= 3;
      stage((t + 2) * 32, nb);           // overwrites buf of tile t-1: safe,
    }                                     // end-barrier of iter t-1 passed
    const int fut = (t + 1 < nT) + (t + 2 < nT);
    // loads retire in issue order: wait until only the future tiles' loads
    // (fut*NL newest) remain outstanding -> tile t's loads have landed.
    if constexpr (NL == 4) {
      if (fut == 2)      asm volatile("s_waitcnt vmcnt(8)" ::: "memory");
      else if (fut == 1) asm volatile("s_waitcnt vmcnt(4)" ::: "memory");
      else               asm volatile("s_waitcnt vmcnt(0)" ::: "memory");
    } else {
      if (fut == 2)      asm volatile("s_waitcnt vmcnt(4)" ::: "memory");
      else if (fut == 1) asm volatile("s_waitcnt vmcnt(2)" ::: "memory");
      else               asm volatile("s_waitcnt vmcnt(0)" ::: "memory");
    }
    __builtin_amdgcn_s_barrier();
    asm volatile("" ::: "memory");

    const short* A_s = smem + cur * (TM + TN) * 32;
    const short* B_s = A_s + TM * 32;

    bfrag af[MT], bf[NT];
    #pragma unroll
    for (int i = 0; i < MT; ++i)
      af[i] = *(const bfrag*)&A_s[(wrow + i * 16 + col) * 32 + quad * 8];
    #pragma unroll
    for (int j = 0; j < NT; ++j)
      bf[j] = *(const bfrag*)&B_s[(wcol + j * 16 + col) * 32 + quad * 8];
    #pragma unroll
    for (int i = 0; i < MT; ++i)
      #pragma unroll
      for (int j = 0; j < NT; ++j)
        acc[i][j] = __builtin_amdgcn_mfma_f32_16x16x32_bf16(af[i], bf[j], acc[i][j], 0, 0, 0);

    // all waves done reading buf cur before iter t+1 overwrites it (tile t+3)
    __builtin_amdgcn_s_barrier();
    asm volatile("" ::: "memory");
    cur = (cur == 2) ? 0 : cur + 1;
  }

  #pragma unroll
  for (int i = 0; i < MT; ++i) {
    #pragma unroll
    for (int j = 0; j < NT; ++j) {
      int colIdx = n0 + wcol + j * 16 + col;
      float b = bias ? bias[colIdx] : 0.f;
      #pragma unroll
      for (int r = 0; r < 4; ++r) {
        int rowIdx = m0 + wrow + i * 16 + quad * 4 + r;
        float v = acc[i][j][r] + b;
        if (relu) v = fmaxf(v, 0.f);
        if (outF) outF[(size_t)rowIdx * N + colIdx] = v;
        if (outB) outB[(size_t)rowIdx * N + colIdx] = f2b(v);
      }
    }
  }
}

// ---------------- V transpose: Q4 cols [2048,2560) -> bf16 [b,h,dk,s] ----------------
__global__ __launch_bounds__(256) void vt_kernel(const unsigned short* __restrict__ Q4,
                                                 unsigned short* __restrict__ vt) {
  __shared__ short tile[64][80];
  const int bh = blockIdx.x;
  const int b = bh >> 3, hd = bh & 7;
  const int s0 = blockIdx.y * 64;
  const int tid = threadIdx.x;
  #pragma unroll
  for (int i = 0; i < 2; ++i) {
    int lin = tid + i * 256;
    int row = lin >> 3;
    int c8 = (lin & 7) * 8;
    *(int4*)&tile[row][c8] =
      *(const int4*)(Q4 + (size_t)(b * S_ + s0 + row) * NPROJ + 2048 + hd * DK_ + c8);
  }
  __syncthreads();
  #pragma unroll
  for (int i = 0; i < 2; ++i) {
    int lin = tid + i * 256;
    int d = lin >> 3;
    int s8 = (lin & 7) * 8;
    short tmp[8];
    #pragma unroll
    for (int t = 0; t < 8; ++t) tmp[t] = tile[s8 + t][d];
    *(int4*)(vt + ((size_t)bh * DK_ + d) * S_ + s0 + s8) = *(const int4*)tmp;
  }
}

// ---------------- MFMA complex-hybrid attention (v11 config, measured best) ----------------
__global__ __launch_bounds__(512, 2) void attn_mfma(const unsigned short* __restrict__ Q4,
                                                    const unsigned short* __restrict__ VT,
                                                    unsigned short* __restrict__ po,
                                                    float* __restrict__ pl) {
  __shared__ __align__(16) short smem[32768];   // 64KB: kr[256][128B] | ki[256][128B]

  const int bh = blockIdx.y;
  const int b = bh >> 3, hd = bh & 7;
  const int hoff = hd * DK_;
  const int ks = blockIdx.z;
  const int tid = threadIdx.x;
  const int w = tid >> 6;
  const int lane = tid & 63;
  const int m = lane & 31;       // C col = q index / A m index
  const int h = lane >> 5;       // half-wave
  const int x7 = m & 7;
  const int q0 = blockIdx.x * 256 + w * 32;
  const int kb = ks * 512;

  const size_t bS = (size_t)b * S_;
  const size_t vtbase = (size_t)bh * DK_ * S_;

  // staging indices: 512 threads, 8 segs/key row; swizzle on SOURCE, linear dest
  const int skey = tid >> 3, sseg = tid & 7;
  const int sls = sseg ^ (skey & 7);            // XOR bank swizzle (K rows = 128B)

  // Q B-frags (persistent): B[kdim = t*16 + h*8 + j][n=q=m]
  bfrag qrf[4], qif[4], nqrf[4];
  {
    const size_t qrow = (bS + q0 + m) * (size_t)NPROJ + hoff;
    #pragma unroll
    for (int t = 0; t < 4; ++t) {
      qrf[t] = *(const bfrag*)(Q4 + qrow + t * 16 + h * 8);
      qif[t] = *(const bfrag*)(Q4 + qrow + 512 + t * 16 + h * 8);
      nqrf[t] = bneg(qrf[t]);
    }
  }

  facc16 o0 = {}, o1 = {};
  float l = 0.f;
  const float c1 = 0.015625f;   // 1/64
  const float c2 = 0.0375f;     // 0.3/8

  // V base pointers (per d-tile): row = tile*32 + m
  const unsigned short* vb0 = VT + vtbase + (size_t)m * S_ + kb + h * 8;
  const unsigned short* vb1 = vb0 + (size_t)32 * S_;

  char* kr_sb = (char*)smem;            // kr: 32KB
  char* ki_sb = (char*)smem + 32768;    // ki: 32KB

  for (int ph = 0; ph < 2; ++ph) {
    // all waves finished reading the previous phase's LDS (ds_reads complete
    // before their consuming MFMAs, which precede this barrier)
    __builtin_amdgcn_s_barrier();
    // stage 256 keys: 4 rounds x 64 keys, kr+ki, coalesced 16B, linear dest
    #pragma unroll
    for (int r = 0; r < 4; ++r) {
      const unsigned short* gk = Q4 + (bS + kb + ph * 256 + r * 64 + skey) * (size_t)NPROJ
                               + 1024 + hoff + sls * 8;
      async_copy16(gk,       kr_sb + r * 8192 + tid * 16);
      async_copy16(gk + 512, ki_sb + r * 8192 + tid * 16);
    }
    asm volatile("s_waitcnt vmcnt(0)" ::: "memory");
    __builtin_amdgcn_s_barrier();
    asm volatile("" ::: "memory");

    for (int c = 0; c < 4; ++c) {      // 64-key chunk, NO sync inside phase
      // ---- V frags direct from global ----
      bfrag vtf[2][4];
      #pragma unroll
      for (int kt = 0; kt < 4; ++kt) {
        vtf[0][kt] = *(const bfrag*)(vb0 + kt * 16);
        vtf[1][kt] = *(const bfrag*)(vb1 + kt * 16);
      }
      vb0 += 64; vb1 += 64;

      // ---- K frags both halves from LDS: row = c*64 + hs*32 + m ----
      bfrag kr0[4], ki0[4], kr1[4], ki1[4];
      #pragma unroll
      for (int t = 0; t < 4; ++t) {
        int off0 = (c * 64 + m) * 128 + (((2 * t + h) ^ x7) << 4);
        int off1 = (c * 64 + 32 + m) * 128 + (((2 * t + h) ^ x7) << 4);
        kr0[t] = *(const bfrag*)(kr_sb + off0);
        ki0[t] = *(const bfrag*)(ki_sb + off0);
        kr1[t] = *(const bfrag*)(kr_sb + off1);
        ki1[t] = *(const bfrag*)(ki_sb + off1);
      }

      // ---- QK both halves ----
      facc16 sr0 = {}, si0 = {}, sr1 = {}, si1 = {};
      #pragma unroll
      for (int t = 0; t < 4; ++t) {
        sr0 = __builtin_amdgcn_mfma_f32_32x32x16_bf16(kr0[t], qrf[t], sr0, 0, 0, 0);
        si0 = __builtin_amdgcn_mfma_f32_32x32x16_bf16(kr0[t], qif[t], si0, 0, 0, 0);
        sr0 = __builtin_amdgcn_mfma_f32_32x32x16_bf16(ki0[t], qif[t], sr0, 0, 0, 0);
        si0 = __builtin_amdgcn_mfma_f32_32x32x16_bf16(ki0[t], nqrf[t], si0, 0, 0, 0);
      }
      #pragma unroll
      for (int t = 0; t < 4; ++t) {
        sr1 = __builtin_amdgcn_mfma_f32_32x32x16_bf16(kr1[t], qrf[t], sr1, 0, 0, 0);
        si1 = __builtin_amdgcn_mfma_f32_32x32x16_bf16(kr1[t], qif[t], si1, 0, 0, 0);
        sr1 = __builtin_amdgcn_mfma_f32_32x32x16_bf16(ki1[t], qif[t], sr1, 0, 0, 0);
        si1 = __builtin_amdgcn_mfma_f32_32x32x16_bf16(ki1[t], nqrf[t], si1, 0, 0, 0);
      }

      #pragma unroll
      for (int hs = 0; hs < 2; ++hs) {
        const facc16& sr = hs ? sr1 : sr0;
        const facc16& si = hs ? si1 : si0;

        // ---- hybrid score -> p = exp(x) ~ 1 + x + x^2/2 (|x| <~ 0.2) ----
        float p[16], ssum = 0.f;
        #pragma unroll
        for (int i = 0; i < 16; ++i) {
          float a = sr[i], bb = si[i];
          float d2 = __builtin_fmaf(a, a, __builtin_fmaf(bb, bb, 1e-30f));
          float rs = rsqrtf(d2);
          float x = rs * __builtin_fmaf(c1, d2, c2 * a);
          p[i] = __builtin_fmaf(x, __builtin_fmaf(0.5f, x, 1.f), 1.f);
          ssum += p[i];
        }
        l += ssum;

        // ---- pack P (cvt_pk RNE) + permlane32_swap cross-half exchange ----
        unsigned dw[8];
        #pragma unroll
        for (int i = 0; i < 8; ++i)
          asm("v_cvt_pk_bf16_f32 %0, %1, %2" : "=v"(dw[i]) : "v"(p[2 * i]), "v"(p[2 * i + 1]));
        unsigned s0a = dw[0], s0b = dw[2];
        unsigned s1a = dw[1], s1b = dw[3];
        unsigned s2a = dw[4], s2b = dw[6];
        unsigned s3a = dw[5], s3b = dw[7];
        asm("v_permlane32_swap_b32 %0, %1" : "+v"(s0a), "+v"(s0b));
        asm("v_permlane32_swap_b32 %0, %1" : "+v"(s1a), "+v"(s1b));
        asm("v_permlane32_swap_b32 %0, %1" : "+v"(s2a), "+v"(s2b));
        asm("v_permlane32_swap_b32 %0, %1" : "+v"(s3a), "+v"(s3b));
        i4v f0 = { (int)s0a, (int)s1a, (int)s0b, (int)s1b };
        i4v f1 = { (int)s2a, (int)s3a, (int)s2b, (int)s3b };
        bfrag pf0 = asb(f0), pf1 = asb(f1);

        // ---- PV: o^T[d][q] += V^T x P^T (k-slots 2*hs, 2*hs+1) ----
        o0 = __builtin_amdgcn_mfma_f32_32x32x16_bf16(vtf[0][2 * hs + 0], pf0, o0, 0, 0, 0);
        o0 = __builtin_amdgcn_mfma_f32_32x32x16_bf16(vtf[0][2 * hs + 1], pf1, o0, 0, 0, 0);
        o1 = __builtin_amdgcn_mfma_f32_32x32x16_bf16(vtf[1][2 * hs + 0], pf0, o1, 0, 0, 0);
        o1 = __builtin_amdgcn_mfma_f32_32x32x16_bf16(vtf[1][2 * hs + 1], pf1, o1, 0, 0, 0);
      }
    }
  }

  // ---- epilogue: write per-split partials (bf16 o, fp32 l) ----
  float l_tot = l + __shfl_xor(l, 32);
  const size_t prow = ((size_t)(bh * 4 + ks)) * S_ + q0 + m;
  #pragma unroll
  for (int tile = 0; tile < 2; ++tile) {
    const facc16& oo = tile ? o1 : o0;
    #pragma unroll
    for (int rg = 0; rg < 4; ++rg) {
      int d0 = tile * 32 + rg * 8 + h * 4;        // d = (reg&3)+8*(reg>>2)+4h
      ushort4 ob;
      ob.x = f2b(oo[4 * rg + 0]);
      ob.y = f2b(oo[4 * rg + 1]);
      ob.z = f2b(oo[4 * rg + 2]);
      ob.w = f2b(oo[4 * rg + 3]);
      *(ushort4*)(po + prow * 64 + d0) = ob;
    }
  }
  if (lane < 32) pl[prow] = l_tot;
}

// ---------------- combine the 4 key-split partials -> ctxb ----------------
__global__ __launch_bounds__(256) void attn_combine(const unsigned short* __restrict__ po,
                                                    const float* __restrict__ pl,
                                                    unsigned short* __restrict__ ctxb) {
  int t = blockIdx.x * 256 + threadIdx.x;      // 262144 threads
  int row = t >> 3;                            // bh*S + q
  int dg = t & 7;
  int bh = row >> 11, q = row & (S_ - 1);
  int b = bh >> 3, hd = bh & 7;
  float acc[8];
  #pragma unroll
  for (int e = 0; e < 8; ++e) acc[e] = 0.f;
  float ls = 0.f;
  #pragma unroll
  for (int ks = 0; ks < 4; ++ks) {
    size_t prow = (((size_t)(bh * 4 + ks)) << 11) + q;
    ls += pl[prow];
    const unsigned short* src = po + prow * 64 + dg * 8;
    ushort4 v0 = *(const ushort4*)src;
    ushort4 v1 = *(const ushort4*)(src + 4);
    acc[0] += b2f(v0.x); acc[1] += b2f(v0.y); acc[2] += b2f(v0.z); acc[3] += b2f(v0.w);
    acc[4] += b2f(v1.x); acc[5] += b2f(v1.y); acc[6] += b2f(v1.z); acc[7] += b2f(v1.w);
  }
  float inv = 1.f / ls;
  unsigned short ob[8];
  #pragma unroll
  for (int e = 0; e < 8; ++e) ob[e] = f2b(acc[e] * inv);
  *(int4*)(ctxb + ((size_t)(b * S_ + q)) * D_ + hd * DK_ + dg * 8) = *(const int4*)ob;
}

// ---------------- layernorm ----------------
__global__ __launch_bounds__(256) void ln_kernel(const float* __restrict__ X,
                                                 const float* __restrict__ R,
                                                 const float* __restrict__ g,
                                                 const float* __restrict__ be,
                                                 float* __restrict__ OutF,
                                                 unsigned short* __restrict__ OutB) {
  const int lane = threadIdx.x & 63;
  const int wv = threadIdx.x >> 6;
  const int row = blockIdx.x * 4 + wv;
  const float* xp = X + (size_t)row * D_;
  const float* rp = R + (size_t)row * D_;
  float x[8];
  float s = 0.f;
  #pragma unroll
  for (int i = 0; i < 8; ++i) {
    int d = i * 64 + lane;
    x[i] = xp[d] + rp[d];
    s += x[i];
  }
  s += __shfl_xor(s, 32); s += __shfl_xor(s, 16); s += __shfl_xor(s, 8);
  s += __shfl_xor(s, 4);  s += __shfl_xor(s, 2);  s += __shfl_xor(s, 1);
  float mu = s * (1.f / 512.f);
  float vs = 0.f;
  #pragma unroll
  for (int i = 0; i < 8; ++i) { float d = x[i] - mu; vs += d * d; }
  vs += __shfl_xor(vs, 32); vs += __shfl_xor(vs, 16); vs += __shfl_xor(vs, 8);
  vs += __shfl_xor(vs, 4);  vs += __shfl_xor(vs, 2);  vs += __shfl_xor(vs, 1);
  float rstd = rsqrtf(vs * (1.f / 512.f) + 1e-5f);
  #pragma unroll
  for (int i = 0; i < 8; ++i) {
    int d = i * 64 + lane;
    float v = (x[i] - mu) * rstd * g[d] + be[d];
    if (OutF) OutF[(size_t)row * D_ + d] = v;
    if (OutB) OutB[(size_t)row * D_ + d] = f2b(v);
  }
}

// ---------------- classifier head ----------------
__global__ __launch_bounds__(256) void head_kernel(const float* __restrict__ Z,
                                                   const float* __restrict__ hw,
                                                   const float* __restrict__ hb,
                                                   float* __restrict__ out) {
  const int lane = threadIdx.x & 63;
  const int wv = threadIdx.x >> 6;
  const int row = blockIdx.x * 4 + wv;
  const float* zp = Z + (size_t)row * D_;
  float a0 = 0.f, a1 = 0.f;
  #pragma unroll
  for (int i = 0; i < 8; ++i) {
    int d = i * 64 + lane;
    float z = zp[d];
    a0 += z * hw[d * 2];
    a1 += z * hw[d * 2 + 1];
  }
  a0 += __shfl_xor(a0, 32); a0 += __shfl_xor(a0, 16); a0 += __shfl_xor(a0, 8);
  a0 += __shfl_xor(a0, 4);  a0 += __shfl_xor(a0, 2);  a0 += __shfl_xor(a0, 1);
  a1 += __shfl_xor(a1, 32); a1 += __shfl_xor(a1, 16); a1 += __shfl_xor(a1, 8);
  a1 += __shfl_xor(a1, 4);  a1 += __shfl_xor(a1, 2);  a1 += __shfl_xor(a1, 1);
  if (lane == 0) {
    out[row * 2]     = a0 + hb[0];
    out[row * 2 + 1] = a1 + hb[1];
  }
}

extern "C" void kernel_launch(void* const* d_in, const int* in_sizes, int n_in,
                              void* d_out, int out_size, void* d_ws, size_t ws_size,
                              hipStream_t stream) {
  const int*   tokens = (const int*)  d_in[0];
  const float* embed  = (const float*)d_in[1];
  const float* Wqr = (const float*)d_in[2];
  const float* Wqi = (const float*)d_in[3];
  const float* Wkr = (const float*)d_in[4];
  const float* Wki = (const float*)d_in[5];
  const float* Wv  = (const float*)d_in[6];
  const float* Wo  = (const float*)d_in[7];
  const float* bo  = (const float*)d_in[8];
  const float* W1  = (const float*)d_in[9];
  const float* b1  = (const float*)d_in[10];
  const float* W2  = (const float*)d_in[11];
  const float* b2  = (const float*)d_in[12];
  const float* g1  = (const float*)d_in[13];
  const float* be1 = (const float*)d_in[14];
  const float* g2  = (const float*)d_in[15];
  const float* be2 = (const float*)d_in[16];
  const float* hw  = (const float*)d_in[17];
  const float* hb  = (const float*)d_in[18];
  float* out = (float*)d_out;

  char* p = (char*)d_ws;
  float* zr = (float*)p;             p += (size_t)BS_ * D_ * 4;           // 8 MB
  unsigned short* acat = (unsigned short*)p;
  unsigned short* zrb  = acat;       p += (size_t)BS_ * 1024 * 2;         // 8 MB
  unsigned short* Q4   = (unsigned short*)p;
  unsigned short* ffb  = Q4;         p += (size_t)BS_ * NPROJ * 2;        // 20 MB
  unsigned short* VT   = (unsigned short*)p; p += (size_t)B_*H_*DK_*S_*2; // 4 MB
  unsigned short* ctxb = (unsigned short*)p; p += (size_t)BS_ * D_ * 2;   // 4 MB
  float* hbuf = (float*)p;           p += (size_t)BS_ * D_ * 4;           // 8 MB
  float* z1   = (float*)p;           p += (size_t)BS_ * D_ * 4;           // 8 MB  (contiguous after hbuf)
  unsigned short* z1b = (unsigned short*)p;  p += (size_t)BS_ * D_ * 2;   // 4 MB  (contiguous after z1)
  unsigned short* pw_proj0 = (unsigned short*)p; p += (size_t)NPROJ * 1024 * 2; // 5 MB
  unsigned short* pw_proj1 = (unsigned short*)p; p += (size_t)NPROJ * 512 * 2;  // 2.5 MB
  unsigned short* pw_wo = (unsigned short*)p;    p += (size_t)2 * 512 * 512 * 2;   // 1 MB
  unsigned short* pw_w1 = (unsigned short*)p;    p += (size_t)2 * 2048 * 512 * 2;  // 4 MB
  unsigned short* pw_w2 = (unsigned short*)p;    p += (size_t)2 * 512 * 2048 * 2;  // 4 MB
  float* pl = (float*)p;             p += (size_t)16 * 4 * S_ * 4;        // 0.5 MB

  // po bf16 [16 bh][4 ks][2048 q][64 d] = 16.78 MB -> aliases hbuf+z1+start of z1b
  // (all dead during attention; combine reads po before the Wo GEMM rewrites hbuf)
  unsigned short* po = (unsigned short*)hbuf;

  embed_zi_kernel<<<BS_, 128, 0, stream>>>(tokens, embed, zr, acat);
  wcat_all<<<dim3(NPROJ / 64, 16, 2), 256, 0, stream>>>(Wqr, Wqi, Wkr, Wki, Wv,
                                                        pw_proj0, pw_proj1);
  wtr_all<<<dim3(32, 32, 6), 256, 0, stream>>>(Wo, W1, W2, pw_wo, pw_w1, pw_w2);

  for (int l = 0; l < L_; ++l) {
    const int KA = (l == 0) ? 1024 : 512;
    const unsigned short* Aproj = (l == 0) ? acat : zrb;
    const unsigned short* Wproj = (l == 0) ? pw_proj0 : pw_proj1;

    gemm_bf16<128, 128><<<dim3(NPROJ / 128, BS_ / 128), 256, 0, stream>>>(
        Aproj, Wproj, nullptr, nullptr, Q4, BS_, NPROJ, KA, KA, 0);

    vt_kernel<<<dim3(B_ * H_, S_ / 64), 256, 0, stream>>>(Q4, VT);
    attn_mfma<<<dim3(S_ / 256, B_ * H_, 4), 512, 0, stream>>>(Q4, VT, po, pl);
    attn_combine<<<1024, 256, 0, stream>>>(po, pl, ctxb);

    gemm_bf16<64, 64><<<dim3(D_ / 64, BS_ / 64), 256, 0, stream>>>(
        ctxb, pw_wo + (size_t)l * 512 * 512, bo + l * D_, hbuf, nullptr,
        BS_, D_, D_, D_, 0);
    ln_kernel<<<BS_ / 4, 256, 0, stream>>>(zr, hbuf, g1 + l * D_, be1 + l * D_, z1, z1b);

    gemm_bf16<128, 128><<<dim3(DFF_ / 128, BS_ / 128), 256, 0, stream>>>(
        z1b, pw_w1 + (size_t)l * 2048 * 512, b1 + l * DFF_, nullptr, ffb,
        BS_, DFF_, D_, D_, 1);
    gemm_bf16<64, 64><<<dim3(D_ / 64, BS_ / 64), 256, 0, stream>>>(
        ffb, pw_w2 + (size_t)l * 512 * 2048, b2 + l * D_, hbuf, nullptr,
        BS_, D_, DFF_, DFF_, 0);
    ln_kernel<<<BS_ / 4, 256, 0, stream>>>(z1, hbuf, g2 + l * D_, be2 + l * D_, zr, zrb);
  }

  head_kernel<<<BS_ / 4, 256, 0, stream>>>(zr, hw, hb, out);
}

// Round 11
// 475.292 us; speedup vs baseline: 1.1758x; 1.0406x over previous
//
#include <hip/hip_runtime.h>

#define B_   2
#define S_   2048
#define D_   512
#define H_   8
#define DK_  64
#define DFF_ 2048
#define L_   2
#define BS_  (B_*S_)   // 4096
#define NPROJ 2560     // qr|qi|kr|ki|v concatenated

typedef __attribute__((ext_vector_type(8))) short bfrag;    // 8 bf16 (4 VGPRs)
typedef __attribute__((ext_vector_type(4))) float facc;     // 4 fp32
typedef __attribute__((ext_vector_type(16))) float facc16;  // 16 fp32 (32x32 C/D)
typedef __attribute__((ext_vector_type(4))) int i4v;

__device__ __forceinline__ unsigned short f2b(float f) {
  union { float f; unsigned int u; } c; c.f = f;
  unsigned int u = c.u;
  u += 0x7fffu + ((u >> 16) & 1);    // RNE
  return (unsigned short)(u >> 16);
}

__device__ __forceinline__ float b2f(unsigned short u) {
  union { unsigned u; float f; } c; c.u = (unsigned)u << 16; return c.f;
}

__device__ __forceinline__ bfrag asb(i4v x) { union { i4v a; bfrag b; } u; u.a = x; return u.b; }

__device__ __forceinline__ bfrag bneg(bfrag x) {
  union { bfrag b; i4v a; } u; u.b = x;
  u.a.x ^= 0x80008000; u.a.y ^= 0x80008000; u.a.z ^= 0x80008000; u.a.w ^= 0x80008000;
  return u.b;
}

__device__ __forceinline__ void async_copy16(const void* g, void* l) {
  __builtin_amdgcn_global_load_lds((const __attribute__((address_space(1))) void*)g,
                                   (__attribute__((address_space(3))) void*)l,
                                   16, 0, 0);
}

// ---------------- fused embedding gather + positional zi ----------------
__global__ __launch_bounds__(128) void embed_zi_kernel(const int* __restrict__ tokens,
                                                       const float* __restrict__ embed,
                                                       float* __restrict__ zr,
                                                       unsigned short* __restrict__ acat) {
  int row = blockIdx.x;
  int tok = tokens[row];
  float4 v = ((const float4*)(embed + (size_t)tok * D_))[threadIdx.x];
  ((float4*)(zr + (size_t)row * D_))[threadIdx.x] = v;
  ushort4 o; o.x = f2b(v.x); o.y = f2b(v.y); o.z = f2b(v.z); o.w = f2b(v.w);
  *(ushort4*)(acat + (size_t)row * 1024 + threadIdx.x * 4) = o;

  int s = row & (S_ - 1);
  int d0 = threadIdx.x * 4;
  const double LN1E4 = 9.210340371976184;
  #pragma unroll
  for (int t = 0; t < 4; ++t) {
    int d = d0 + t;
    int jj = d >> 1;
    double freq = exp(-((double)jj / 256.0) * LN1E4);
    float val = (float)sin((double)s * freq);
    acat[(size_t)row * 1024 + 512 + d] = f2b(val);
  }
}

// ---------------- batched weight concat+transpose (both layers) ----------------
__global__ __launch_bounds__(256) void wcat_all(const float* __restrict__ Wqr,
                                                const float* __restrict__ Wqi,
                                                const float* __restrict__ Wkr,
                                                const float* __restrict__ Wki,
                                                const float* __restrict__ Wv,
                                                unsigned short* __restrict__ dst0,
                                                unsigned short* __restrict__ dst1) {
  __shared__ float tile[64][68];
  const int l = blockIdx.z;
  const int KA = l ? 512 : 1024;
  const int k0 = blockIdx.y * 64;
  if (k0 >= KA) return;
  unsigned short* dst = l ? dst1 : dst0;
  const size_t woff = (size_t)l * D_ * D_;
  const float* wqr = Wqr + woff;
  const float* wqi = Wqi + woff;
  const float* wkr = Wkr + woff;
  const float* wki = Wki + woff;
  const float* wv  = Wv  + woff;

  const int tid = threadIdx.x;
  const int n0 = blockIdx.x * 64;
  const int p = n0 >> 9, nn0 = n0 & 511;
  const float* src;
  float sign = 1.f;
  bool zero = false;
  if (k0 < 512) {
    const float* tops[5] = {wqr, wqi, wkr, wki, wv};
    src = tops[p];
  } else {
    const float* bots[5] = {wqi, wqr, wki, wkr, nullptr};
    const float sg[5] = {-1.f, 1.f, -1.f, 1.f, 0.f};
    src = bots[p]; sign = sg[p]; zero = (p == 4);
  }
  const int kk0 = k0 & 511;
  #pragma unroll
  for (int i = 0; i < 4; ++i) {
    int lin = tid + i * 256;
    int row = lin >> 4, c4 = (lin & 15) * 4;
    float4 v = make_float4(0.f, 0.f, 0.f, 0.f);
    if (!zero) v = *(const float4*)(src + (size_t)(kk0 + row) * 512 + nn0 + c4);
    *(float4*)&tile[row][c4] = v;
  }
  __syncthreads();
  #pragma unroll
  for (int i = 0; i < 4; ++i) {
    int lin = tid + i * 256;
    int n = lin >> 4, kc4 = (lin & 15) * 4;
    ushort4 o;
    o.x = f2b(sign * tile[kc4 + 0][n]);
    o.y = f2b(sign * tile[kc4 + 1][n]);
    o.z = f2b(sign * tile[kc4 + 2][n]);
    o.w = f2b(sign * tile[kc4 + 3][n]);
    *(ushort4*)(dst + (size_t)(n0 + n) * KA + k0 + kc4) = o;
  }
}

// ---------------- batched weight transpose: wo/w1/w2 x both layers ----------------
__global__ __launch_bounds__(256) void wtr_all(const float* __restrict__ Wo,
                                               const float* __restrict__ W1,
                                               const float* __restrict__ W2,
                                               unsigned short* __restrict__ pwo,
                                               unsigned short* __restrict__ pw1,
                                               unsigned short* __restrict__ pw2) {
  __shared__ float tile[64][68];
  const int j = blockIdx.z, l = j & 1;
  const float* src; unsigned short* dst; int K, N;
  if (j < 2)      { src = Wo + (size_t)l * 512 * 512;  dst = pwo + (size_t)l * 512 * 512;  K = 512;  N = 512; }
  else if (j < 4) { src = W1 + (size_t)l * 512 * 2048; dst = pw1 + (size_t)l * 2048 * 512; K = 512;  N = 2048; }
  else            { src = W2 + (size_t)l * 2048 * 512; dst = pw2 + (size_t)l * 512 * 2048; K = 2048; N = 512; }
  const int n0 = blockIdx.x * 64, k0 = blockIdx.y * 64;
  if (n0 >= N || k0 >= K) return;
  const int tid = threadIdx.x;
  #pragma unroll
  for (int i = 0; i < 4; ++i) {
    int lin = tid + i * 256;
    int row = lin >> 4, c4 = (lin & 15) * 4;
    *(float4*)&tile[row][c4] = *(const float4*)(src + (size_t)(k0 + row) * N + n0 + c4);
  }
  __syncthreads();
  #pragma unroll
  for (int i = 0; i < 4; ++i) {
    int lin = tid + i * 256;
    int n = lin >> 4, kc4 = (lin & 15) * 4;
    ushort4 o;
    o.x = f2b(tile[kc4 + 0][n]);
    o.y = f2b(tile[kc4 + 1][n]);
    o.z = f2b(tile[kc4 + 2][n]);
    o.w = f2b(tile[kc4 + 3][n]);
    *(ushort4*)(dst + (size_t)(n0 + n) * K + k0 + kc4) = o;
  }
}

// ---------------- bf16 MFMA GEMM, v17 ----------------
// v16 depth-2 3-buffer pipeline kept.  v17 adds:
//  - XCD-chunked blockIdx swizzle (all grids %8==0 -> simple bijective form):
//    contiguous tile chunks per XCD -> shared A/B panels hit per-XCD L2.
//  - optional VT epilogue output (proj only): cols>=2048 are the V
//    projection; write them TRANSPOSED to VT[bh][d][s] instead of Q4 (attn
//    never reads Q4's V columns -- eliminates vt_kernel).  The 4 r-values
//    are s-consecutive -> one ushort4 store (better than the scalar Q4
//    scatter they replace).
template<int TM, int TN>
__global__ __launch_bounds__(256) void gemm_bf16(const unsigned short* __restrict__ A,
                                                 const unsigned short* __restrict__ Bt,
                                                 const float* __restrict__ bias,
                                                 float* __restrict__ outF,
                                                 unsigned short* __restrict__ outB,
                                                 unsigned short* __restrict__ vt,
                                                 int M, int N, int K, int lda, int relu) {
  constexpr int MT = TM / 32;
  constexpr int NT = TN / 32;
  constexpr int NL = TM / 64 + TN / 64;   // async copies per thread per stage
  __shared__ short smem[3 * (TM + TN) * 32];

  const int tid = threadIdx.x;
  const int w = tid >> 6, lane = tid & 63;
  const int col = lane & 15, quad = lane >> 4;

  // XCD-chunked bijective swizzle (grids here are always %8 == 0)
  const int nwg = gridDim.x * gridDim.y;
  const int bid = blockIdx.y * gridDim.x + blockIdx.x;
  const int cpx = nwg >> 3;
  const int swz = (bid & 7) * cpx + (bid >> 3);
  const int bx = swz % gridDim.x, by = swz / gridDim.x;

  const int m0 = by * TM, n0 = bx * TN;
  const int wrow = (w >> 1) * (TM / 2);
  const int wcol = (w & 1) * (TN / 2);

  const int srow = lane >> 2;
  const int skk  = (lane & 3) * 8;

  facc acc[MT][NT];
  #pragma unroll
  for (int i = 0; i < MT; ++i)
    #pragma unroll
    for (int j = 0; j < NT; ++j) acc[i][j] = (facc){0.f, 0.f, 0.f, 0.f};

  auto stage = [&](int k0, int buf) {
    short* A_s = smem + buf * (TM + TN) * 32;
    short* B_s = A_s + TM * 32;
    #pragma unroll
    for (int rd = 0; rd < TM / 64; ++rd) {
      int row = rd * 64 + w * 16 + srow;
      async_copy16(A + (size_t)(m0 + row) * lda + k0 + skk, &A_s[row * 32 + skk]);
    }
    #pragma unroll
    for (int rd = 0; rd < TN / 64; ++rd) {
      int row = rd * 64 + w * 16 + srow;
      async_copy16(Bt + (size_t)(n0 + row) * K + k0 + skk, &B_s[row * 32 + skk]);
    }
  };

  const int nT = K >> 5;                 // K/32 tiles
  stage(0, 0);
  if (nT > 1) stage(32, 1);

  int cur = 0;                           // buffer of tile t (t%3)
  for (int t = 0; t < nT; ++t) {
    if (t + 2 < nT) {
      int nb = cur + 2; if (nb >= 3) nb -= 3;
      stage((t + 2) * 32, nb);
    }
    const int fut = (t + 1 < nT) + (t + 2 < nT);
    if constexpr (NL == 4) {
      if (fut == 2)      asm volatile("s_waitcnt vmcnt(8)" ::: "memory");
      else if (fut == 1) asm volatile("s_waitcnt vmcnt(4)" ::: "memory");
      else               asm volatile("s_waitcnt vmcnt(0)" ::: "memory");
    } else {
      if (fut == 2)      asm volatile("s_waitcnt vmcnt(4)" ::: "memory");
      else if (fut == 1) asm volatile("s_waitcnt vmcnt(2)" ::: "memory");
      else               asm volatile("s_waitcnt vmcnt(0)" ::: "memory");
    }
    __builtin_amdgcn_s_barrier();
    asm volatile("" ::: "memory");

    const short* A_s = smem + cur * (TM + TN) * 32;
    const short* B_s = A_s + TM * 32;

    bfrag af[MT], bf[NT];
    #pragma unroll
    for (int i = 0; i < MT; ++i)
      af[i] = *(const bfrag*)&A_s[(wrow + i * 16 + col) * 32 + quad * 8];
    #pragma unroll
    for (int j = 0; j < NT; ++j)
      bf[j] = *(const bfrag*)&B_s[(wcol + j * 16 + col) * 32 + quad * 8];
    #pragma unroll
    for (int i = 0; i < MT; ++i)
      #pragma unroll
      for (int j = 0; j < NT; ++j)
        acc[i][j] = __builtin_amdgcn_mfma_f32_16x16x32_bf16(af[i], bf[j], acc[i][j], 0, 0, 0);

    __builtin_amdgcn_s_barrier();
    asm volatile("" ::: "memory");
    cur = (cur == 2) ? 0 : cur + 1;
  }

  #pragma unroll
  for (int i = 0; i < MT; ++i) {
    #pragma unroll
    for (int j = 0; j < NT; ++j) {
      int colIdx = n0 + wcol + j * 16 + col;
      float b = bias ? bias[colIdx] : 0.f;
      int rowBase = m0 + wrow + i * 16 + quad * 4;
      if (vt && colIdx >= 2048) {
        // V projection -> VT[bh][d][s], 4 s-consecutive values, one ushort4
        int c = colIdx - 2048;
        int bh = ((rowBase >> 11) << 3) + (c >> 6);   // b*8 + head
        int d = c & 63;
        int s = rowBase & (S_ - 1);
        ushort4 o;
        o.x = f2b(acc[i][j][0]); o.y = f2b(acc[i][j][1]);
        o.z = f2b(acc[i][j][2]); o.w = f2b(acc[i][j][3]);
        *(ushort4*)(vt + ((size_t)bh * DK_ + d) * S_ + s) = o;
      } else {
        #pragma unroll
        for (int r = 0; r < 4; ++r) {
          int rowIdx = rowBase + r;
          float v = acc[i][j][r] + b;
          if (relu) v = fmaxf(v, 0.f);
          if (outF) outF[(size_t)rowIdx * N + colIdx] = v;
          if (outB) outB[(size_t)rowIdx * N + colIdx] = f2b(v);
        }
      }
    }
  }
}

// ---------------- MFMA complex-hybrid attention (v11 config, measured best) ----------------
__global__ __launch_bounds__(512, 2) void attn_mfma(const unsigned short* __restrict__ Q4,
                                                    const unsigned short* __restrict__ VT,
                                                    unsigned short* __restrict__ po,
                                                    float* __restrict__ pl) {
  __shared__ __align__(16) short smem[32768];   // 64KB: kr[256][128B] | ki[256][128B]

  const int bh = blockIdx.y;
  const int b = bh >> 3, hd = bh & 7;
  const int hoff = hd * DK_;
  const int ks = blockIdx.z;
  const int tid = threadIdx.x;
  const int w = tid >> 6;
  const int lane = tid & 63;
  const int m = lane & 31;       // C col = q index / A m index
  const int h = lane >> 5;       // half-wave
  const int x7 = m & 7;
  const int q0 = blockIdx.x * 256 + w * 32;
  const int kb = ks * 512;

  const size_t bS = (size_t)b * S_;
  const size_t vtbase = (size_t)bh * DK_ * S_;

  // staging indices: 512 threads, 8 segs/key row; swizzle on SOURCE, linear dest
  const int skey = tid >> 3, sseg = tid & 7;
  const int sls = sseg ^ (skey & 7);            // XOR bank swizzle (K rows = 128B)

  // Q B-frags (persistent): B[kdim = t*16 + h*8 + j][n=q=m]
  bfrag qrf[4], qif[4], nqrf[4];
  {
    const size_t qrow = (bS + q0 + m) * (size_t)NPROJ + hoff;
    #pragma unroll
    for (int t = 0; t < 4; ++t) {
      qrf[t] = *(const bfrag*)(Q4 + qrow + t * 16 + h * 8);
      qif[t] = *(const bfrag*)(Q4 + qrow + 512 + t * 16 + h * 8);
      nqrf[t] = bneg(qrf[t]);
    }
  }

  facc16 o0 = {}, o1 = {};
  float l = 0.f;
  const float c1 = 0.015625f;   // 1/64
  const float c2 = 0.0375f;     // 0.3/8

  // V base pointers (per d-tile): row = tile*32 + m
  const unsigned short* vb0 = VT + vtbase + (size_t)m * S_ + kb + h * 8;
  const unsigned short* vb1 = vb0 + (size_t)32 * S_;

  char* kr_sb = (char*)smem;            // kr: 32KB
  char* ki_sb = (char*)smem + 32768;    // ki: 32KB

  for (int ph = 0; ph < 2; ++ph) {
    // all waves finished reading the previous phase's LDS (ds_reads complete
    // before their consuming MFMAs, which precede this barrier)
    __builtin_amdgcn_s_barrier();
    // stage 256 keys: 4 rounds x 64 keys, kr+ki, coalesced 16B, linear dest
    #pragma unroll
    for (int r = 0; r < 4; ++r) {
      const unsigned short* gk = Q4 + (bS + kb + ph * 256 + r * 64 + skey) * (size_t)NPROJ
                               + 1024 + hoff + sls * 8;
      async_copy16(gk,       kr_sb + r * 8192 + tid * 16);
      async_copy16(gk + 512, ki_sb + r * 8192 + tid * 16);
    }
    asm volatile("s_waitcnt vmcnt(0)" ::: "memory");
    __builtin_amdgcn_s_barrier();
    asm volatile("" ::: "memory");

    for (int c = 0; c < 4; ++c) {      // 64-key chunk, NO sync inside phase
      // ---- V frags direct from global ----
      bfrag vtf[2][4];
      #pragma unroll
      for (int kt = 0; kt < 4; ++kt) {
        vtf[0][kt] = *(const bfrag*)(vb0 + kt * 16);
        vtf[1][kt] = *(const bfrag*)(vb1 + kt * 16);
      }
      vb0 += 64; vb1 += 64;

      // ---- K frags both halves from LDS: row = c*64 + hs*32 + m ----
      bfrag kr0[4], ki0[4], kr1[4], ki1[4];
      #pragma unroll
      for (int t = 0; t < 4; ++t) {
        int off0 = (c * 64 + m) * 128 + (((2 * t + h) ^ x7) << 4);
        int off1 = (c * 64 + 32 + m) * 128 + (((2 * t + h) ^ x7) << 4);
        kr0[t] = *(const bfrag*)(kr_sb + off0);
        ki0[t] = *(const bfrag*)(ki_sb + off0);
        kr1[t] = *(const bfrag*)(kr_sb + off1);
        ki1[t] = *(const bfrag*)(ki_sb + off1);
      }

      // ---- QK both halves ----
      facc16 sr0 = {}, si0 = {}, sr1 = {}, si1 = {};
      #pragma unroll
      for (int t = 0; t < 4; ++t) {
        sr0 = __builtin_amdgcn_mfma_f32_32x32x16_bf16(kr0[t], qrf[t], sr0, 0, 0, 0);
        si0 = __builtin_amdgcn_mfma_f32_32x32x16_bf16(kr0[t], qif[t], si0, 0, 0, 0);
        sr0 = __builtin_amdgcn_mfma_f32_32x32x16_bf16(ki0[t], qif[t], sr0, 0, 0, 0);
        si0 = __builtin_amdgcn_mfma_f32_32x32x16_bf16(ki0[t], nqrf[t], si0, 0, 0, 0);
      }
      #pragma unroll
      for (int t = 0; t < 4; ++t) {
        sr1 = __builtin_amdgcn_mfma_f32_32x32x16_bf16(kr1[t], qrf[t], sr1, 0, 0, 0);
        si1 = __builtin_amdgcn_mfma_f32_32x32x16_bf16(kr1[t], qif[t], si1, 0, 0, 0);
        sr1 = __builtin_amdgcn_mfma_f32_32x32x16_bf16(ki1[t], qif[t], sr1, 0, 0, 0);
        si1 = __builtin_amdgcn_mfma_f32_32x32x16_bf16(ki1[t], nqrf[t], si1, 0, 0, 0);
      }

      #pragma unroll
      for (int hs = 0; hs < 2; ++hs) {
        const facc16& sr = hs ? sr1 : sr0;
        const facc16& si = hs ? si1 : si0;

        // ---- hybrid score -> p = exp(x) ~ 1 + x + x^2/2 (|x| <~ 0.2) ----
        float p[16], ssum = 0.f;
        #pragma unroll
        for (int i = 0; i < 16; ++i) {
          float a = sr[i], bb = si[i];
          float d2 = __builtin_fmaf(a, a, __builtin_fmaf(bb, bb, 1e-30f));
          float rs = rsqrtf(d2);
          float x = rs * __builtin_fmaf(c1, d2, c2 * a);
          p[i] = __builtin_fmaf(x, __builtin_fmaf(0.5f, x, 1.f), 1.f);
          ssum += p[i];
        }
        l += ssum;

        // ---- pack P (cvt_pk RNE) + permlane32_swap cross-half exchange ----
        unsigned dw[8];
        #pragma unroll
        for (int i = 0; i < 8; ++i)
          asm("v_cvt_pk_bf16_f32 %0, %1, %2" : "=v"(dw[i]) : "v"(p[2 * i]), "v"(p[2 * i + 1]));
        unsigned s0a = dw[0], s0b = dw[2];
        unsigned s1a = dw[1], s1b = dw[3];
        unsigned s2a = dw[4], s2b = dw[6];
        unsigned s3a = dw[5], s3b = dw[7];
        asm("v_permlane32_swap_b32 %0, %1" : "+v"(s0a), "+v"(s0b));
        asm("v_permlane32_swap_b32 %0, %1" : "+v"(s1a), "+v"(s1b));
        asm("v_permlane32_swap_b32 %0, %1" : "+v"(s2a), "+v"(s2b));
        asm("v_permlane32_swap_b32 %0, %1" : "+v"(s3a), "+v"(s3b));
        i4v f0 = { (int)s0a, (int)s1a, (int)s0b, (int)s1b };
        i4v f1 = { (int)s2a, (int)s3a, (int)s2b, (int)s3b };
        bfrag pf0 = asb(f0), pf1 = asb(f1);

        // ---- PV: o^T[d][q] += V^T x P^T (k-slots 2*hs, 2*hs+1) ----
        o0 = __builtin_amdgcn_mfma_f32_32x32x16_bf16(vtf[0][2 * hs + 0], pf0, o0, 0, 0, 0);
        o0 = __builtin_amdgcn_mfma_f32_32x32x16_bf16(vtf[0][2 * hs + 1], pf1, o0, 0, 0, 0);
        o1 = __builtin_amdgcn_mfma_f32_32x32x16_bf16(vtf[1][2 * hs + 0], pf0, o1, 0, 0, 0);
        o1 = __builtin_amdgcn_mfma_f32_32x32x16_bf16(vtf[1][2 * hs + 1], pf1, o1, 0, 0, 0);
      }
    }
  }

  // ---- epilogue: write per-split partials (bf16 o, fp32 l) ----
  float l_tot = l + __shfl_xor(l, 32);
  const size_t prow = ((size_t)(bh * 4 + ks)) * S_ + q0 + m;
  #pragma unroll
  for (int tile = 0; tile < 2; ++tile) {
    const facc16& oo = tile ? o1 : o0;
    #pragma unroll
    for (int rg = 0; rg < 4; ++rg) {
      int d0 = tile * 32 + rg * 8 + h * 4;        // d = (reg&3)+8*(reg>>2)+4h
      ushort4 ob;
      ob.x = f2b(oo[4 * rg + 0]);
      ob.y = f2b(oo[4 * rg + 1]);
      ob.z = f2b(oo[4 * rg + 2]);
      ob.w = f2b(oo[4 * rg + 3]);
      *(ushort4*)(po + prow * 64 + d0) = ob;
    }
  }
  if (lane < 32) pl[prow] = l_tot;
}

// ---------------- combine the 4 key-split partials -> ctxb ----------------
__global__ __launch_bounds__(256) void attn_combine(const unsigned short* __restrict__ po,
                                                    const float* __restrict__ pl,
                                                    unsigned short* __restrict__ ctxb) {
  int t = blockIdx.x * 256 + threadIdx.x;      // 262144 threads
  int row = t >> 3;                            // bh*S + q
  int dg = t & 7;
  int bh = row >> 11, q = row & (S_ - 1);
  int b = bh >> 3, hd = bh & 7;
  float acc[8];
  #pragma unroll
  for (int e = 0; e < 8; ++e) acc[e] = 0.f;
  float ls = 0.f;
  #pragma unroll
  for (int ks = 0; ks < 4; ++ks) {
    size_t prow = (((size_t)(bh * 4 + ks)) << 11) + q;
    ls += pl[prow];
    const unsigned short* src = po + prow * 64 + dg * 8;
    ushort4 v0 = *(const ushort4*)src;
    ushort4 v1 = *(const ushort4*)(src + 4);
    acc[0] += b2f(v0.x); acc[1] += b2f(v0.y); acc[2] += b2f(v0.z); acc[3] += b2f(v0.w);
    acc[4] += b2f(v1.x); acc[5] += b2f(v1.y); acc[6] += b2f(v1.z); acc[7] += b2f(v1.w);
  }
  float inv = 1.f / ls;
  unsigned short ob[8];
  #pragma unroll
  for (int e = 0; e < 8; ++e) ob[e] = f2b(acc[e] * inv);
  *(int4*)(ctxb + ((size_t)(b * S_ + q)) * D_ + hd * DK_ + dg * 8) = *(const int4*)ob;
}

// ---------------- layernorm (+ optional fused classifier head) ----------------
__global__ __launch_bounds__(256) void ln_kernel(const float* __restrict__ X,
                                                 const float* __restrict__ R,
                                                 const float* __restrict__ g,
                                                 const float* __restrict__ be,
                                                 float* __restrict__ OutF,
                                                 unsigned short* __restrict__ OutB,
                                                 const float* __restrict__ hw,
                                                 const float* __restrict__ hb,
                                                 float* __restrict__ hout) {
  const int lane = threadIdx.x & 63;
  const int wv = threadIdx.x >> 6;
  const int row = blockIdx.x * 4 + wv;
  const float* xp = X + (size_t)row * D_;
  const float* rp = R + (size_t)row * D_;
  float x[8];
  float s = 0.f;
  #pragma unroll
  for (int i = 0; i < 8; ++i) {
    int d = i * 64 + lane;
    x[i] = xp[d] + rp[d];
    s += x[i];
  }
  s += __shfl_xor(s, 32); s += __shfl_xor(s, 16); s += __shfl_xor(s, 8);
  s += __shfl_xor(s, 4);  s += __shfl_xor(s, 2);  s += __shfl_xor(s, 1);
  float mu = s * (1.f / 512.f);
  float vs = 0.f;
  #pragma unroll
  for (int i = 0; i < 8; ++i) { float d = x[i] - mu; vs += d * d; }
  vs += __shfl_xor(vs, 32); vs += __shfl_xor(vs, 16); vs += __shfl_xor(vs, 8);
  vs += __shfl_xor(vs, 4);  vs += __shfl_xor(vs, 2);  vs += __shfl_xor(vs, 1);
  float rstd = rsqrtf(vs * (1.f / 512.f) + 1e-5f);
  float a0 = 0.f, a1 = 0.f;
  #pragma unroll
  for (int i = 0; i < 8; ++i) {
    int d = i * 64 + lane;
    float v = (x[i] - mu) * rstd * g[d] + be[d];
    if (OutF) OutF[(size_t)row * D_ + d] = v;
    if (OutB) OutB[(size_t)row * D_ + d] = f2b(v);
    if (hout) { a0 += v * hw[d * 2]; a1 += v * hw[d * 2 + 1]; }
  }
  if (hout) {
    a0 += __shfl_xor(a0, 32); a0 += __shfl_xor(a0, 16); a0 += __shfl_xor(a0, 8);
    a0 += __shfl_xor(a0, 4);  a0 += __shfl_xor(a0, 2);  a0 += __shfl_xor(a0, 1);
    a1 += __shfl_xor(a1, 32); a1 += __shfl_xor(a1, 16); a1 += __shfl_xor(a1, 8);
    a1 += __shfl_xor(a1, 4);  a1 += __shfl_xor(a1, 2);  a1 += __shfl_xor(a1, 1);
    if (lane == 0) {
      hout[row * 2]     = a0 + hb[0];
      hout[row * 2 + 1] = a1 + hb[1];
    }
  }
}

extern "C" void kernel_launch(void* const* d_in, const int* in_sizes, int n_in,
                              void* d_out, int out_size, void* d_ws, size_t ws_size,
                              hipStream_t stream) {
  const int*   tokens = (const int*)  d_in[0];
  const float* embed  = (const float*)d_in[1];
  const float* Wqr = (const float*)d_in[2];
  const float* Wqi = (const float*)d_in[3];
  const float* Wkr = (const float*)d_in[4];
  const float* Wki = (const float*)d_in[5];
  const float* Wv  = (const float*)d_in[6];
  const float* Wo  = (const float*)d_in[7];
  const float* bo  = (const float*)d_in[8];
  const float* W1  = (const float*)d_in[9];
  const float* b1  = (const float*)d_in[10];
  const float* W2  = (const float*)d_in[11];
  const float* b2  = (const float*)d_in[12];
  const float* g1  = (const float*)d_in[13];
  const float* be1 = (const float*)d_in[14];
  const float* g2  = (const float*)d_in[15];
  const float* be2 = (const float*)d_in[16];
  const float* hw  = (const float*)d_in[17];
  const float* hb  = (const float*)d_in[18];
  float* out = (float*)d_out;

  char* p = (char*)d_ws;
  float* zr = (float*)p;             p += (size_t)BS_ * D_ * 4;           // 8 MB
  unsigned short* acat = (unsigned short*)p;
  unsigned short* zrb  = acat;       p += (size_t)BS_ * 1024 * 2;         // 8 MB
  unsigned short* Q4   = (unsigned short*)p;
  unsigned short* ffb  = Q4;         p += (size_t)BS_ * NPROJ * 2;        // 20 MB
  unsigned short* VT   = (unsigned short*)p; p += (size_t)B_*H_*DK_*S_*2; // 4 MB
  unsigned short* ctxb = (unsigned short*)p; p += (size_t)BS_ * D_ * 2;   // 4 MB
  float* hbuf = (float*)p;           p += (size_t)BS_ * D_ * 4;           // 8 MB
  float* z1   = (float*)p;           p += (size_t)BS_ * D_ * 4;           // 8 MB  (contiguous after hbuf)
  unsigned short* z1b = (unsigned short*)p;  p += (size_t)BS_ * D_ * 2;   // 4 MB  (contiguous after z1)
  unsigned short* pw_proj0 = (unsigned short*)p; p += (size_t)NPROJ * 1024 * 2; // 5 MB
  unsigned short* pw_proj1 = (unsigned short*)p; p += (size_t)NPROJ * 512 * 2;  // 2.5 MB
  unsigned short* pw_wo = (unsigned short*)p;    p += (size_t)2 * 512 * 512 * 2;   // 1 MB
  unsigned short* pw_w1 = (unsigned short*)p;    p += (size_t)2 * 2048 * 512 * 2;  // 4 MB
  unsigned short* pw_w2 = (unsigned short*)p;    p += (size_t)2 * 512 * 2048 * 2;  // 4 MB
  float* pl = (float*)p;             p += (size_t)16 * 4 * S_ * 4;        // 0.5 MB

  // po bf16 [16 bh][4 ks][2048 q][64 d] = 16.78 MB -> aliases hbuf+z1+start of z1b
  // (all dead during attention; combine reads po before the Wo GEMM rewrites hbuf)
  unsigned short* po = (unsigned short*)hbuf;

  embed_zi_kernel<<<BS_, 128, 0, stream>>>(tokens, embed, zr, acat);
  wcat_all<<<dim3(NPROJ / 64, 16, 2), 256, 0, stream>>>(Wqr, Wqi, Wkr, Wki, Wv,
                                                        pw_proj0, pw_proj1);
  wtr_all<<<dim3(32, 32, 6), 256, 0, stream>>>(Wo, W1, W2, pw_wo, pw_w1, pw_w2);

  for (int l = 0; l < L_; ++l) {
    const int KA = (l == 0) ? 1024 : 512;
    const unsigned short* Aproj = (l == 0) ? acat : zrb;
    const unsigned short* Wproj = (l == 0) ? pw_proj0 : pw_proj1;

    // proj writes Q/K cols to Q4 and V cols TRANSPOSED to VT (vt_kernel fused)
    gemm_bf16<128, 128><<<dim3(NPROJ / 128, BS_ / 128), 256, 0, stream>>>(
        Aproj, Wproj, nullptr, nullptr, Q4, VT, BS_, NPROJ, KA, KA, 0);

    attn_mfma<<<dim3(S_ / 256, B_ * H_, 4), 512, 0, stream>>>(Q4, VT, po, pl);
    attn_combine<<<1024, 256, 0, stream>>>(po, pl, ctxb);

    gemm_bf16<64, 64><<<dim3(D_ / 64, BS_ / 64), 256, 0, stream>>>(
        ctxb, pw_wo + (size_t)l * 512 * 512, bo + l * D_, hbuf, nullptr, nullptr,
        BS_, D_, D_, D_, 0);
    ln_kernel<<<BS_ / 4, 256, 0, stream>>>(zr, hbuf, g1 + l * D_, be1 + l * D_, z1, z1b,
                                           nullptr, nullptr, nullptr);

    gemm_bf16<128, 128><<<dim3(DFF_ / 128, BS_ / 128), 256, 0, stream>>>(
        z1b, pw_w1 + (size_t)l * 2048 * 512, b1 + l * DFF_, nullptr, ffb, nullptr,
        BS_, DFF_, D_, D_, 1);
    gemm_bf16<64, 64><<<dim3(D_ / 64, BS_ / 64), 256, 0, stream>>>(
        ffb, pw_w2 + (size_t)l * 512 * 2048, b2 + l * D_, hbuf, nullptr, nullptr,
        BS_, D_, DFF_, DFF_, 0);
    // final ln fuses the classifier head (head_kernel eliminated)
    if (l == L_ - 1)
      ln_kernel<<<BS_ / 4, 256, 0, stream>>>(z1, hbuf, g2 + l * D_, be2 + l * D_,
                                             nullptr, nullptr, hw, hb, out);
    else
      ln_kernel<<<BS_ / 4, 256, 0, stream>>>(z1, hbuf, g2 + l * D_, be2 + l * D_,
                                             zr, zrb, nullptr, nullptr, nullptr);
  }
}